// Round 9
// baseline (562.036 us; speedup 1.0000x reference)
//
#include <hip/hip_runtime.h>
#include <stdint.h>

// ---------- small helpers ----------
typedef __attribute__((ext_vector_type(8))) short bf16x8;
typedef __attribute__((ext_vector_type(8))) unsigned short u16x8;
typedef __attribute__((ext_vector_type(4))) float floatx4;

__device__ __forceinline__ uint16_t f2bf(float f) {
  union { float f; uint32_t u; } v; v.f = f;
  uint32_t r = v.u + 0x7fffu + ((v.u >> 16) & 1u);
  return (uint16_t)(r >> 16);
}
__device__ __forceinline__ float bf2f(uint16_t b) {
  union { uint32_t u; float f; } v; v.u = ((uint32_t)b) << 16;
  return v.f;
}
__device__ __forceinline__ float ld_as_float(float v) { return v; }
__device__ __forceinline__ float ld_as_float(uint16_t v) { return bf2f(v); }

__device__ __forceinline__ void mfma16(floatx4& d, bf16x8 a, bf16x8 b) {
  asm("v_mfma_f32_16x16x32_bf16 %0, %1, %2, %0" : "+v"(d) : "v"(a), "v"(b));
}

#define FENCE() asm volatile("" ::: "memory")
#define SCHED() __builtin_amdgcn_sched_barrier(0)
#define SBAR()                                  \
  do {                                          \
    FENCE();                                    \
    __builtin_amdgcn_sched_barrier(0);          \
    __builtin_amdgcn_s_barrier();               \
    __builtin_amdgcn_sched_barrier(0);          \
    FENCE();                                    \
  } while (0)

// ================= v4 GEMM: 256x128, BK=32, 3-slot ring, 2 blocks/CU =================
// C(M,N) = A(M,K) @ B(N,K)^T, bf16 in, fp32 acc. Requires K % 32 == 0, K >= 64.
// 256 threads = 4 waves (2M x 2N), per-wave 128x64 output (8x4 frags) — the
// LDS:MFMA-balanced ratio (12 ds_read_b128 : 32 MFMA per wave-tile).
// LDS: 3 slots x (A 16KB + B 8KB) = 72 KB -> 2 blocks/CU: independent blocks
// fill each other's barrier/vmcnt stalls (the structural 1-block/CU loss of v3).
// Tile t in slot t%3; stage t+2 into slot (t+2)%3 (= slot t-1, WAR-safe: all
// waves' t-1 reads completed before this tile's entry barrier).
// Per tile: vmcnt(6) [own loads landed; next tile's 6 in flight] -> s_barrier ->
// 12 ds_reads + staging issue -> lgkmcnt(4) -> 16 MFMA -> lgkmcnt(0) -> 16 MFMA.
// Chunk-XOR swizzle (both sides, same involution — verified r7: conflicts=0):
//   write: source chunk = (l&3) ^ ((l>>3)&3)   [row within round = l>>2]
//   read:  chunk = (l>>4) ^ ((lr>>1)&3)
// MODE 0: fp32 C0; 1: bf16 C0; 2: routed (cols 0-511 bf16 C0 ld512 cq-pre,
//   512-1023 fp32 C1 ld512 ckv-pre, 1024-1535 bf16 C2 ld2560 aq);
// 3: bf16 C0 with fused *(1/12) scale.
template<int MODE>
__global__ void __launch_bounds__(256, 2) gemm128(
    const uint16_t* __restrict__ A, const uint16_t* __restrict__ B,
    void* __restrict__ C0v, void* __restrict__ C1v, void* __restrict__ C2v,
    int K, int lda, int ldb, int ldc,
    long sA, long sB, long sC)
{
  __shared__ __attribute__((aligned(16))) char lds[73728];  // 3 x 24576
  const int tid = threadIdx.x;
  const int w = tid >> 6, l = tid & 63;   // w in 0..3
  const int wm = w >> 1, wn = w & 1;

  // XCD-aware swizzle over the (x,y) plane (all grids here have nwg % 8 == 0)
  const int gx = gridDim.x;
  const int nwg = gx * gridDim.y;
  int id = blockIdx.y * gx + blockIdx.x;
  if ((nwg & 7) == 0) id = (id & 7) * (nwg >> 3) + (id >> 3);
  const long bm = (long)(id % gx) * 256;
  const long bn = (long)(id / gx) * 128;
  A += (long)blockIdx.z * sA;
  B += (long)blockIdx.z * sB;

  // staging: round = 64 rows x 64B (4 waves x 16 rows); source chunk pre-swizzled
  const int scol = (((l & 3) ^ ((l >> 3) & 3)) << 3);  // elements
  const uint16_t* gA = A + (bm + w * 16 + (l >> 2)) * (long)lda + scol;
  const uint16_t* gB = B + (bn + w * 16 + (l >> 2)) * (long)ldb + scol;
  const int ldsw = w * 1024;

#define STG_A4(slot, k0, r)                                                    \
  __builtin_amdgcn_global_load_lds(gA + (k0) + (long)(r) * 64 * lda,           \
      (uint16_t*)(lds + (slot) * 24576 + (r) * 4096 + ldsw), 16, 0, 0)
#define STG_B4(slot, k0, r)                                                    \
  __builtin_amdgcn_global_load_lds(gB + (k0) + (long)(r) * 64 * ldb,           \
      (uint16_t*)(lds + (slot) * 24576 + 16384 + (r) * 4096 + ldsw), 16, 0, 0)

  // fragment read geometry: row stride 64B; lane reads 16B at swizzled chunk
  const int lr = l & 15;
  const int chunkx = (((l >> 4) ^ ((lr >> 1) & 3)) << 4);  // bytes
  const int aoff = (wm * 128 + lr) * 64 + chunkx;
  const int boff = 16384 + (wn * 64 + lr) * 64 + chunkx;

  floatx4 acc[8][4];
#pragma unroll
  for (int i = 0; i < 8; i++)
#pragma unroll
    for (int j = 0; j < 4; j++) acc[i][j] = (floatx4){0.f, 0.f, 0.f, 0.f};

  const int nt = K >> 5;  // nt >= 2
  // prologue: stage tiles 0,1 (FIFO order matches in-loop order A0..A3,B0,B1)
#pragma unroll
  for (int tt = 0; tt < 2; tt++) {
    STG_A4(tt, tt * 32, 0); STG_A4(tt, tt * 32, 1);
    STG_A4(tt, tt * 32, 2); STG_A4(tt, tt * 32, 3);
    STG_B4(tt, tt * 32, 0); STG_B4(tt, tt * 32, 1);
  }

  for (int t = 0; t < nt; t++) {
    const char* Ls = lds + (t % 3) * 24576;
    // retire own tile's loads; next tile's 6 stay in flight
    if (t < nt - 1) asm volatile("s_waitcnt vmcnt(6)" ::: "memory");
    else            asm volatile("s_waitcnt vmcnt(0)" ::: "memory");
    SBAR();

    bf16x8 Bf[4], Af0[4], Af1[4];
#pragma unroll
    for (int j = 0; j < 4; j++) Bf[j] = *(const bf16x8*)(Ls + boff + j * 1024);
#pragma unroll
    for (int i = 0; i < 4; i++) Af0[i] = *(const bf16x8*)(Ls + aoff + i * 1024);
    SCHED();  // pin DS issue: first 8 = Bf + Af0

    const long pk0 = (long)(t + 2) << 5;
    const int pslot = (t + 2) % 3;
    const bool pf = (t + 2 < nt);
    if (pf) { STG_A4(pslot, pk0, 0); STG_A4(pslot, pk0, 1); }

#pragma unroll
    for (int i = 0; i < 4; i++) Af1[i] = *(const bf16x8*)(Ls + aoff + (4 + i) * 1024);
    SCHED();
    if (pf) { STG_A4(pslot, pk0, 2); STG_A4(pslot, pk0, 3); }

    asm volatile("s_waitcnt lgkmcnt(4)" ::: "memory");  // Bf+Af0 landed
    SCHED();
    __builtin_amdgcn_s_setprio(1);
#pragma unroll
    for (int i = 0; i < 4; i++)
#pragma unroll
      for (int j = 0; j < 4; j++) mfma16(acc[i][j], Af0[i], Bf[j]);
    __builtin_amdgcn_s_setprio(0);
    SCHED();

    if (pf) { STG_B4(pslot, pk0, 0); STG_B4(pslot, pk0, 1); }

    asm volatile("s_waitcnt lgkmcnt(0)" ::: "memory");
    SCHED();
    __builtin_amdgcn_s_setprio(1);
#pragma unroll
    for (int i = 0; i < 4; i++)
#pragma unroll
      for (int j = 0; j < 4; j++) mfma16(acc[4 + i][j], Af1[i], Bf[j]);
    __builtin_amdgcn_s_setprio(0);
    SCHED();
  }
#undef STG_A4
#undef STG_B4

  const long crow = bm + wm * 128 + ((l >> 4) * 4);
  const long ccol = bn + wn * 64 + (l & 15);
  if constexpr (MODE == 0) {
    float* C = (float*)C0v + (long)blockIdx.z * sC;
#pragma unroll
    for (int i = 0; i < 8; i++)
#pragma unroll
      for (int r = 0; r < 4; r++) {
        long row = crow + i * 16 + r;
#pragma unroll
        for (int j = 0; j < 4; j++) C[row * (long)ldc + ccol + j * 16] = acc[i][j][r];
      }
  } else if constexpr (MODE == 1) {
    uint16_t* C = (uint16_t*)C0v + (long)blockIdx.z * sC;
#pragma unroll
    for (int i = 0; i < 8; i++)
#pragma unroll
      for (int r = 0; r < 4; r++) {
        long row = crow + i * 16 + r;
#pragma unroll
        for (int j = 0; j < 4; j++) C[row * (long)ldc + ccol + j * 16] = f2bf(acc[i][j][r]);
      }
  } else if constexpr (MODE == 3) {
    const float s = 1.0f / 12.0f;
    uint16_t* C = (uint16_t*)C0v + (long)blockIdx.z * sC;
#pragma unroll
    for (int i = 0; i < 8; i++)
#pragma unroll
      for (int r = 0; r < 4; r++) {
        long row = crow + i * 16 + r;
#pragma unroll
        for (int j = 0; j < 4; j++) C[row * (long)ldc + ccol + j * 16] = f2bf(acc[i][j][r] * s);
      }
  } else {
    if (bn < 512) {
      uint16_t* C = (uint16_t*)C0v;
#pragma unroll
      for (int i = 0; i < 8; i++)
#pragma unroll
        for (int r = 0; r < 4; r++) {
          long row = crow + i * 16 + r;
#pragma unroll
          for (int j = 0; j < 4; j++) C[row * 512 + ccol + j * 16] = f2bf(acc[i][j][r]);
        }
    } else if (bn < 1024) {
      float* C = (float*)C1v;
      const long cc = ccol - 512;
#pragma unroll
      for (int i = 0; i < 8; i++)
#pragma unroll
        for (int r = 0; r < 4; r++) {
          long row = crow + i * 16 + r;
#pragma unroll
          for (int j = 0; j < 4; j++) C[row * 512 + cc + j * 16] = acc[i][j][r];
        }
    } else {
      uint16_t* C = (uint16_t*)C2v;
      const long cc = ccol - 1024;
#pragma unroll
      for (int i = 0; i < 8; i++)
#pragma unroll
        for (int r = 0; r < 4; r++) {
          long row = crow + i * 16 + r;
#pragma unroll
          for (int j = 0; j < 4; j++) C[row * 2560 + cc + j * 16] = f2bf(acc[i][j][r]);
        }
    }
  }
}

// ================= legacy 128x128 GEMM (small weight-prep matmuls, split-K via z) =================
template<int OUTB>
__global__ void __launch_bounds__(256) gemm_bt(
    const uint16_t* __restrict__ A, const uint16_t* __restrict__ B,
    void* __restrict__ Cv, int K, int lda, int ldb, int ldc,
    long sA, long sB, long sC)
{
  __shared__ alignas(16) uint16_t As[4096];
  __shared__ alignas(16) uint16_t Bs[4096];
  const int tid = threadIdx.x;
  const int w = tid >> 6, l = tid & 63;
  const int wr = w >> 1, wc = w & 1;
  const long bm = (long)blockIdx.x * 128, bn = (long)blockIdx.y * 128;
  A += (long)blockIdx.z * sA;
  B += (long)blockIdx.z * sB;

  const uint16_t* ga0 = A + (bm + w * 16 + (l >> 2)) * (long)lda + (l & 3) * 8;
  const uint16_t* ga1 = ga0 + 64L * lda;
  const uint16_t* gb0 = B + (bn + w * 16 + (l >> 2)) * (long)ldb + (l & 3) * 8;
  const uint16_t* gb1 = gb0 + 64L * ldb;
  uint16_t* la0 = &As[w * 512];
  uint16_t* la1 = &As[2048 + w * 512];
  uint16_t* lb0 = &Bs[w * 512];
  uint16_t* lb1 = &Bs[2048 + w * 512];

  floatx4 acc[4][4];
#pragma unroll
  for (int i = 0; i < 4; i++)
#pragma unroll
    for (int j = 0; j < 4; j++) acc[i][j] = (floatx4){0.f, 0.f, 0.f, 0.f};

  const int rA = (wr * 64 + (l & 15)) * 32 + (l >> 4) * 8;
  const int rB = (wc * 64 + (l & 15)) * 32 + (l >> 4) * 8;

  for (int k0 = 0; k0 < K; k0 += 32) {
    __builtin_amdgcn_global_load_lds(ga0, la0, 16, 0, 0);
    __builtin_amdgcn_global_load_lds(ga1, la1, 16, 0, 0);
    __builtin_amdgcn_global_load_lds(gb0, lb0, 16, 0, 0);
    __builtin_amdgcn_global_load_lds(gb1, lb1, 16, 0, 0);
    ga0 += 32; ga1 += 32; gb0 += 32; gb1 += 32;
    __syncthreads();
    bf16x8 af[4], bfr[4];
#pragma unroll
    for (int i = 0; i < 4; i++) af[i] = *(const bf16x8*)&As[rA + i * 512];
#pragma unroll
    for (int j = 0; j < 4; j++) bfr[j] = *(const bf16x8*)&Bs[rB + j * 512];
#pragma unroll
    for (int i = 0; i < 4; i++)
#pragma unroll
      for (int j = 0; j < 4; j++) mfma16(acc[i][j], af[i], bfr[j]);
    __syncthreads();
  }

  const long crow = bm + wr * 64 + ((l >> 4) * 4);
  const long ccol = bn + wc * 64 + (l & 15);
  if constexpr (OUTB == 0) {
    float* C = (float*)Cv + (long)blockIdx.z * sC;
#pragma unroll
    for (int i = 0; i < 4; i++)
#pragma unroll
      for (int r = 0; r < 4; r++) {
        long row = crow + i * 16 + r;
#pragma unroll
        for (int j = 0; j < 4; j++) C[row * (long)ldc + ccol + j * 16] = acc[i][j][r];
      }
  } else {
    uint16_t* C = (uint16_t*)Cv + (long)blockIdx.z * sC;
#pragma unroll
    for (int i = 0; i < 4; i++)
#pragma unroll
      for (int r = 0; r < 4; r++) {
        long row = crow + i * 16 + r;
#pragma unroll
        for (int j = 0; j < 4; j++) C[row * (long)ldc + ccol + j * 16] = f2bf(acc[i][j][r]);
      }
  }
}

// ---------- split-K reduce: out_bf16[i] = sum_s in[s*stride + i] ----------
__global__ void __launch_bounds__(256) reduceK(const float* __restrict__ in,
                                               uint16_t* __restrict__ out,
                                               long n, int S, long stride) {
  long i = ((long)blockIdx.x * 256 + threadIdx.x) * 4;
  if (i >= n) return;
  float4 s = *(const float4*)(in + i);
  for (int k = 1; k < S; k++) {
    float4 t = *(const float4*)(in + k * stride + i);
    s.x += t.x; s.y += t.y; s.z += t.z; s.w += t.w;
  }
  ushort4 o; o.x = f2bf(s.x); o.y = f2bf(s.y); o.z = f2bf(s.z); o.w = f2bf(s.w);
  *(ushort4*)(out + i) = o;
}

// ---------- fp32 -> bf16 convert (h) ----------
__global__ void __launch_bounds__(256) cvt_k(const float* __restrict__ in,
                                             uint16_t* __restrict__ out, long n) {
  long i = ((long)blockIdx.x * 256 + threadIdx.x) * 4;
  if (i >= n) return;
  float4 v = *(const float4*)(in + i);
  ushort4 o; o.x = f2bf(v.x); o.y = f2bf(v.y); o.z = f2bf(v.z); o.w = f2bf(v.w);
  *(ushort4*)(out + i) = o;
}

// ---------- fused small-weight converts + rope table (one launch) ----------
__global__ void __launch_bounds__(256) prep_small(
    const float* __restrict__ wdq, const float* __restrict__ wdkv,
    const float* __restrict__ wqr, const float* __restrict__ wkr,
    const float* __restrict__ wo,
    uint16_t* __restrict__ wdq_b, uint16_t* __restrict__ wdkv_b,
    uint16_t* __restrict__ wqr_b, uint16_t* __restrict__ wkr_b,
    uint16_t* __restrict__ wo_b, float2* __restrict__ rtab)
{
  const int b = blockIdx.x;
  if (b < 11264) {
    const float* src; uint16_t* dst; long off;
    if (b < 1024)      { src = wdq;  dst = wdq_b;  off = b; }
    else if (b < 2048) { src = wdkv; dst = wdkv_b; off = b - 1024; }
    else if (b < 3072) { src = wqr;  dst = wqr_b;  off = b - 2048; }
    else if (b < 7168) { src = wkr;  dst = wkr_b;  off = b - 3072; }
    else               { src = wo;   dst = wo_b;   off = b - 7168; }
    long i = (off * 256 + threadIdx.x) * 4;
    float4 v = *(const float4*)(src + i);
    ushort4 o; o.x = f2bf(v.x); o.y = f2bf(v.y); o.z = f2bf(v.z); o.w = f2bf(v.w);
    *(ushort4*)(dst + i) = o;
  } else {
    int idx = (b - 11264) * 256 + threadIdx.x;  // 2048*64
    int s = idx >> 6, fi = idx & 63;
    float f = powf(10000.0f, -(float)fi * (1.0f / 64.0f));
    float ang = (float)s * f;
    rtab[idx] = make_float2(cosf(ang), sinf(ang));
  }
}

// ---------- transpose (R,Cc) -> (Cc,R), bf16 out ----------
template<typename TIN>
__global__ void __launch_bounds__(256) transpose_to_bf16(
    const TIN* __restrict__ in, uint16_t* __restrict__ out,
    int ld_in, int ld_out, long sIn, long sOut)
{
  __shared__ float tile[32][33];
  in += (long)blockIdx.z * sIn;
  out += (long)blockIdx.z * sOut;
  const int rb = blockIdx.y * 32, cb = blockIdx.x * 32;
#pragma unroll
  for (int i = 0; i < 32; i += 8)
    tile[threadIdx.y + i][threadIdx.x] =
        ld_as_float(in[(long)(rb + threadIdx.y + i) * ld_in + cb + threadIdx.x]);
  __syncthreads();
#pragma unroll
  for (int i = 0; i < 32; i += 8)
    out[(long)(cb + threadIdx.y + i) * ld_out + rb + threadIdx.x] =
        f2bf(tile[threadIdx.x][threadIdx.y + i]);
}

// ---------- rmsnorm: one block per row; DIM = PT*256 ----------
template<int PT, typename TIN>
__global__ void __launch_bounds__(256) rmsnorm_k(
    const TIN* __restrict__ in, const float* __restrict__ g,
    float* __restrict__ out_f, uint16_t* __restrict__ out_b, int ld_b)
{
  constexpr int DIM = PT * 256;
  __shared__ float sm[9];
  const TIN* x = in + (long)blockIdx.x * DIM;
  const int base = threadIdx.x * PT;
  float v[PT];
  if constexpr (sizeof(TIN) == 2) {
    if constexpr (PT >= 8) {
#pragma unroll
      for (int i = 0; i < PT; i += 8) {
        u16x8 t = *(const u16x8*)&x[base + i];
#pragma unroll
        for (int q = 0; q < 8; q++) v[i + q] = bf2f(t[q]);
      }
    } else {
#pragma unroll
      for (int i = 0; i < PT; i += 2) {
        ushort2 t = *(const ushort2*)&x[base + i];
        v[i] = bf2f(t.x); v[i + 1] = bf2f(t.y);
      }
    }
  } else if constexpr (PT == 2) {
    float2 t = *(const float2*)&x[base]; v[0] = t.x; v[1] = t.y;
  } else {
#pragma unroll
    for (int i = 0; i < PT; i += 4) {
      float4 t = *(const float4*)&x[base + i];
      v[i] = t.x; v[i + 1] = t.y; v[i + 2] = t.z; v[i + 3] = t.w;
    }
  }
  float ss = 0.f;
#pragma unroll
  for (int i = 0; i < PT; i++) ss += v[i] * v[i];
#pragma unroll
  for (int o = 32; o; o >>= 1) ss += __shfl_down(ss, o);
  if ((threadIdx.x & 63) == 0) sm[threadIdx.x >> 6] = ss;
  __syncthreads();
  if (threadIdx.x == 0)
    sm[8] = rsqrtf((sm[0] + sm[1] + sm[2] + sm[3]) * (1.0f / DIM) + 1.1920929e-7f);
  __syncthreads();
  const float sc = sm[8];
#pragma unroll
  for (int i = 0; i < PT; i++) {
    float y = v[i] * sc * g[base + i];
    if (out_f) out_f[(long)blockIdx.x * DIM + base + i] = y;
    if (out_b) out_b[(long)blockIdx.x * ld_b + base + i] = f2bf(y);
  }
}

// ---------- rope apply: in bf16 (8192,2048); bf16 out -> cat[:,512:]; optional fp32 out ----------
template<bool WF32>
__global__ void __launch_bounds__(256) rope_k(
    const uint16_t* __restrict__ in, uint16_t* __restrict__ outb,
    float* __restrict__ outf, const float2* __restrict__ tab)
{
  long idx = (long)blockIdx.x * 256 + threadIdx.x;  // 8192*1024 pairs
  int r = (int)(idx >> 10);
  int pp = (int)idx & 1023;
  int s = r & 2047;
  int fi = pp & 63;
  ushort2 xv = *(const ushort2*)(in + ((long)r << 11) + 2 * pp);
  float x0 = bf2f(xv.x), x1 = bf2f(xv.y);
  float2 cs = tab[(s << 6) + fi];
  float y0 = x0 * cs.x - x1 * cs.y;
  float y1 = x0 * cs.y + x1 * cs.x;
  ushort2 ov; ov.x = f2bf(y0); ov.y = f2bf(y1);
  *(ushort2*)(outb + (long)r * 2560 + 512 + 2 * pp) = ov;
  if (WF32) *(float2*)(outf + ((long)r << 11) + 2 * pp) = make_float2(y0, y1);
}

// ---------- softmax over rows of 2048, bf16 in (pre-scaled), bf16 out ----------
__global__ void __launch_bounds__(256) softmax_k(const uint16_t* __restrict__ sc,
                                                 uint16_t* __restrict__ attn) {
  __shared__ float sm[9];
  const uint16_t* x = sc + ((long)blockIdx.x << 11);
  const int base = threadIdx.x * 8;
  float v[8];
  u16x8 t = *(const u16x8*)&x[base];
#pragma unroll
  for (int i = 0; i < 8; i++) v[i] = bf2f(t[i]);
  float m = -1e30f;
#pragma unroll
  for (int i = 0; i < 8; i++) m = fmaxf(m, v[i]);
#pragma unroll
  for (int o = 32; o; o >>= 1) m = fmaxf(m, __shfl_down(m, o));
  if ((threadIdx.x & 63) == 0) sm[threadIdx.x >> 6] = m;
  __syncthreads();
  if (threadIdx.x == 0)
    sm[8] = fmaxf(fmaxf(sm[0], sm[1]), fmaxf(sm[2], sm[3]));
  __syncthreads();
  m = sm[8];
  __syncthreads();
  float ss = 0.f;
#pragma unroll
  for (int i = 0; i < 8; i++) { v[i] = __expf(v[i] - m); ss += v[i]; }
#pragma unroll
  for (int o = 32; o; o >>= 1) ss += __shfl_down(ss, o);
  if ((threadIdx.x & 63) == 0) sm[threadIdx.x >> 6] = ss;
  __syncthreads();
  if (threadIdx.x == 0) sm[8] = 1.0f / (sm[0] + sm[1] + sm[2] + sm[3]);
  __syncthreads();
  const float r = sm[8];
  ushort4 o1, o2;
  o1.x = f2bf(v[0] * r); o1.y = f2bf(v[1] * r); o1.z = f2bf(v[2] * r); o1.w = f2bf(v[3] * r);
  o2.x = f2bf(v[4] * r); o2.y = f2bf(v[5] * r); o2.z = f2bf(v[6] * r); o2.w = f2bf(v[7] * r);
  uint16_t* dst = attn + ((long)blockIdx.x << 11) + base;
  *(ushort4*)dst = o1;
  *(ushort4*)(dst + 4) = o2;
}

// ---------- orchestration ----------
extern "C" void kernel_launch(void* const* d_in, const int* in_sizes, int n_in,
                              void* d_out, int out_size, void* d_ws, size_t ws_size,
                              hipStream_t stream) {
  (void)in_sizes; (void)n_in; (void)out_size; (void)ws_size;
  const float* h    = (const float*)d_in[0];
  const float* wdkv = (const float*)d_in[1];
  const float* wuk  = (const float*)d_in[2];
  const float* wuv  = (const float*)d_in[3];
  const float* wdq  = (const float*)d_in[4];
  const float* wuq  = (const float*)d_in[5];
  const float* wkr  = (const float*)d_in[6];
  const float* wqr  = (const float*)d_in[7];
  const float* wo   = (const float*)d_in[8];
  const float* g1   = (const float*)d_in[9];
  const float* g2   = (const float*)d_in[10];
  const float* g3   = (const float*)d_in[11];

  float* u_out   = (float*)d_out;                 // (4,2048,2048)
  float* ckv_out = u_out + 16777216L;             // (4,2048,512)
  float* kr_out  = ckv_out + 4194304L;            // (4,2048,2048)

  char* p = (char*)d_ws;
  auto alloc = [&](size_t bytes) -> void* {
    void* q = (void*)p; p += (bytes + 255) & ~(size_t)255; return q;
  };
  uint16_t* hb     = (uint16_t*)alloc(16777216ULL * 2);  // h bf16
  uint16_t* wcat   = (uint16_t*)alloc(3145728ULL * 2);   // (1536,2048) [wdq;wdkv;Bqt]
  uint16_t* wqr_b  = (uint16_t*)alloc(1048576ULL * 2);
  uint16_t* wkr_b  = (uint16_t*)alloc(4194304ULL * 2);
  uint16_t* wo_b   = (uint16_t*)alloc(4194304ULL * 2);
  uint16_t* wukT   = (uint16_t*)alloc(1048576ULL * 2);   // (512,2048)
  uint16_t* wuqT   = (uint16_t*)alloc(1048576ULL * 2);
  uint16_t* wuvT   = (uint16_t*)alloc(1048576ULL * 2);
  uint16_t* wdqT   = (uint16_t*)alloc(1048576ULL * 2);   // (2048,512)
  uint16_t* T1t    = (uint16_t*)alloc(262144ULL * 2);    // (512,512)
  uint16_t* awoT   = (uint16_t*)alloc(1048576ULL * 2);   // absorbed_w_o^T (2048,512)
  uint16_t* cqpre  = (uint16_t*)alloc(4194304ULL * 2);   // (8192,512) bf16 cq-pre
  uint16_t* cq_b   = (uint16_t*)alloc(4194304ULL * 2);   // (8192,512)
  uint16_t* catq   = (uint16_t*)alloc(20971520ULL * 2);  // (8192,2560) [aq|qr]
  uint16_t* catk   = (uint16_t*)alloc(20971520ULL * 2);  // (8192,2560) [ckv|kr]
  uint16_t* ckvT   = (uint16_t*)alloc(4194304ULL * 2);   // 4 x (512,2048)
  uint16_t* o_b    = (uint16_t*)alloc(4194304ULL * 2);   // (8192,512)
  float2*   rtab   = (float2*)alloc(131072ULL * 8);      // 2048x64 (cos,sin)
  float*    tmpS2  = (float*)alloc(4194304ULL * 4);      // (8192,512) fp32 ckv-pre
  float*    tmpB   = (float*)alloc(16777216ULL * 4);     // (8192,2048) scratch
  float*    redT   = (float*)alloc(1048576ULL * 4);      // 4 x (512,512) partials
  float*    redW   = (float*)alloc(4194304ULL * 4);      // 4 x (2048,512) partials
  uint16_t* tmpBb  = (uint16_t*)tmpB;                    // alias: (8192,2048) bf16
  uint16_t* attn   = catq;  // alias: catq dead after scores GEMM

  uint16_t* wdq_b  = wcat;                  // rows 0-511
  uint16_t* wdkv_b = wcat + 1048576;        // rows 512-1023
  uint16_t* Bqt    = wcat + 2097152;        // rows 1024-1535 (absorbed_w_q^T)

  const dim3 b256(256);
  const dim3 tb(32, 8);

  // h convert + fused small-weight converts + rope table
  cvt_k<<<dim3(16384), b256, 0, stream>>>(h, hb, 16777216L);
  prep_small<<<dim3(11776), b256, 0, stream>>>(
      wdq, wdkv, wqr, wkr, wo, wdq_b, wdkv_b, wqr_b, wkr_b, wo_b, rtab);
  // weight transposes (fp32 -> bf16)
  transpose_to_bf16<float><<<dim3(16, 64, 1), tb, 0, stream>>>(wuk, wukT, 512, 2048, 0, 0);
  transpose_to_bf16<float><<<dim3(16, 64, 1), tb, 0, stream>>>(wuq, wuqT, 512, 2048, 0, 0);
  transpose_to_bf16<float><<<dim3(16, 64, 1), tb, 0, stream>>>(wuv, wuvT, 512, 2048, 0, 0);
  transpose_to_bf16<float><<<dim3(64, 16, 1), tb, 0, stream>>>(wdq, wdqT, 2048, 512, 0, 0);

  // absorbed weights — split-K (z=4, Kc=512) + deterministic reduce
  // T1t partials: (512,512) x4
  gemm_bt<0><<<dim3(4, 4, 4), b256, 0, stream>>>(
      wukT, wuqT, redT, 512, 2048, 2048, 512, 512L, 512L, 262144L);
  reduceK<<<dim3(256), b256, 0, stream>>>(redT, T1t, 262144L, 4, 262144L);
  // awoT partials: (2048,512) x4  [awoT = wo @ wuv]
  gemm_bt<0><<<dim3(16, 4, 4), b256, 0, stream>>>(
      wo_b, wuvT, redW, 512, 2048, 2048, 512, 512L, 512L, 1048576L);
  reduceK<<<dim3(1024), b256, 0, stream>>>(redW, awoT, 1048576L, 4, 1048576L);
  // Bqt = T1t @ wdqT^T (K=512)
  gemm_bt<1><<<dim3(4, 16, 1), b256, 0, stream>>>(T1t, wdqT, Bqt, 512, 512, 512, 2048, 0, 0, 0);

  // fused: [cq-pre(bf16) | ckv-pre(fp32) | aq(bf16)] = h @ [wdq; wdkv; Bqt]^T
  gemm128<2><<<dim3(32, 12, 1), b256, 0, stream>>>(
      hb, wcat, cqpre, tmpS2, catq, 2048, 2048, 2048, 0, 0, 0, 0);
  // cq = rmsnorm(cq-pre, g1)
  rmsnorm_k<2, uint16_t><<<dim3(8192), b256, 0, stream>>>(cqpre, g1, nullptr, cq_b, 512);
  // qr = rope(cq @ wqr^T) -> catq[:,512:]
  gemm128<1><<<dim3(32, 16, 1), b256, 0, stream>>>(
      cq_b, wqr_b, tmpBb, nullptr, nullptr, 512, 512, 512, 2048, 0, 0, 0);
  rope_k<false><<<dim3(32768), b256, 0, stream>>>(tmpBb, catq, nullptr, rtab);
  // ckv = rmsnorm(ckv-pre, g2) -> ckv_out (fp32) + catk[:,0:512] (bf16)
  rmsnorm_k<2, float><<<dim3(8192), b256, 0, stream>>>(tmpS2, g2, ckv_out, catk, 2560);
  // ckvT: 4 x (512,2048) from catk cols 0..511
  transpose_to_bf16<uint16_t><<<dim3(16, 64, 4), tb, 0, stream>>>(
      catk, ckvT, 2560, 2048, 2048L * 2560, 512L * 2048);
  // kr = rope(h @ wkr^T) -> kr_out (fp32) + catk[:,512:]
  gemm128<1><<<dim3(32, 16, 1), b256, 0, stream>>>(
      hb, wkr_b, tmpBb, nullptr, nullptr, 2048, 2048, 2048, 2048, 0, 0, 0);
  rope_k<true><<<dim3(32768), b256, 0, stream>>>(tmpBb, catk, kr_out, rtab);
  // scores[b]/12 = (catq_b @ catk_b^T)/12 -> tmpBb bf16 (K=2560)
  gemm128<3><<<dim3(8, 16, 4), b256, 0, stream>>>(
      catq, catk, tmpBb, nullptr, nullptr, 2560, 2560, 2560, 2048,
      5242880L, 5242880L, 4194304L);
  // softmax -> attn bf16 (aliases catq)
  softmax_k<<<dim3(8192), b256, 0, stream>>>(tmpBb, attn);
  // o[b] = attn_b @ ckv_b (via ckvT) -> o_b bf16
  gemm128<1><<<dim3(8, 4, 4), b256, 0, stream>>>(
      attn, ckvT, o_b, nullptr, nullptr, 2048, 2048, 2048, 512,
      4194304L, 1048576L, 1048576L);
  // u = rmsnorm(o @ absorbed_w_o, g3) -> u_out
  gemm128<1><<<dim3(32, 16, 1), b256, 0, stream>>>(
      o_b, awoT, tmpBb, nullptr, nullptr, 512, 512, 512, 2048, 0, 0, 0);
  rmsnorm_k<8, uint16_t><<<dim3(8192), b256, 0, stream>>>(tmpBb, g3, u_out, nullptr, 0);
}

// Round 10
// 502.428 us; speedup vs baseline: 1.1186x; 1.1186x over previous
//
#include <hip/hip_runtime.h>
#include <stdint.h>

// ---------- small helpers ----------
typedef __attribute__((ext_vector_type(8))) short bf16x8;
typedef __attribute__((ext_vector_type(8))) unsigned short u16x8;
typedef __attribute__((ext_vector_type(4))) float floatx4;

__device__ __forceinline__ uint16_t f2bf(float f) {
  union { float f; uint32_t u; } v; v.f = f;
  uint32_t r = v.u + 0x7fffu + ((v.u >> 16) & 1u);
  return (uint16_t)(r >> 16);
}
__device__ __forceinline__ float bf2f(uint16_t b) {
  union { uint32_t u; float f; } v; v.u = ((uint32_t)b) << 16;
  return v.f;
}
__device__ __forceinline__ float ld_as_float(float v) { return v; }
__device__ __forceinline__ float ld_as_float(uint16_t v) { return bf2f(v); }

__device__ __forceinline__ void mfma16(floatx4& d, bf16x8 a, bf16x8 b) {
  asm("v_mfma_f32_16x16x32_bf16 %0, %1, %2, %0" : "+v"(d) : "v"(a), "v"(b));
}

#define FENCE() asm volatile("" ::: "memory")
#define SCHED() __builtin_amdgcn_sched_barrier(0)
#define SBAR()                                  \
  do {                                          \
    FENCE();                                    \
    __builtin_amdgcn_sched_barrier(0);          \
    __builtin_amdgcn_s_barrier();               \
    __builtin_amdgcn_sched_barrier(0);          \
    FENCE();                                    \
  } while (0)

// ================= v3 GEMM: 256x256, BK=32, 4-slot ring, 1 barrier/tile =================
// (r7-verified schedule: bank conflicts = 0, scores 88 us.)
// C(M,N) = A(M,K) @ B(N,K)^T, bf16 in, fp32 acc. Requires K % 32 == 0, K >= 96.
// 512 threads = 8 waves (2M x 4N), per-wave 128x64 output (8x4 frags).
// LDS: 4 slots x (A 16KB + B 16KB) = 128 KB. Tile t in slot t%4, prefetch depth 3.
// Per tile: vmcnt(8) -> s_barrier -> 12 ds_reads + staging issue, lgkmcnt(4),
// 16 MFMA, lgkmcnt(0), 16 MFMA.
// Chunk-XOR swizzle (both sides, same involution):
//   write: source chunk = (l&3) ^ ((l>>3)&3);  read: chunk = (l>>4) ^ ((lr>>1)&3)
// XCD mapping: 1D swizzle gives each XCD nwg/8 consecutive logical ids; swzG
// then shapes that chunk into a ~square (gx-major within groups of G bn-columns)
// region so each XCD's L2 working set is (cpx/G) A-panels + G B-panels instead
// of all-A + 1-B (the r7 column mapping = swzG 1). Bijective iff gridDim.y % G == 0.
// MODE 0: fp32 C0; 1: bf16 C0; 2: routed (cols 0-511 bf16 C0 ld512 cq-pre,
//   512-1023 fp32 C1 ld512 ckv-pre, 1024-1535 bf16 C2 ld2560 aq);
// 3: bf16 C0 with fused *(1/12) scale.
template<int MODE>
__global__ void __launch_bounds__(512, 1) gemm256v3(
    const uint16_t* __restrict__ A, const uint16_t* __restrict__ B,
    void* __restrict__ C0v, void* __restrict__ C1v, void* __restrict__ C2v,
    int K, int lda, int ldb, int ldc,
    long sA, long sB, long sC, int swzG)
{
  __shared__ __attribute__((aligned(16))) char lds[131072];
  const int tid = threadIdx.x;
  const int w = tid >> 6, l = tid & 63;
  const int wm = w >> 2, wn = w & 3;

  // XCD-aware swizzle + 2D supertile shaping
  const int gx = gridDim.x;
  const int nwg = gx * gridDim.y;
  int id = blockIdx.y * gx + blockIdx.x;
  if ((nwg & 7) == 0) id = (id & 7) * (nwg >> 3) + (id >> 3);
  const int grp = gx * swzG;
  const int ing = id % grp;
  const long bm = (long)(ing / swzG) * 256;
  const long bn = ((long)(id / grp) * swzG + (ing % swzG)) * 256;
  A += (long)blockIdx.z * sA;
  B += (long)blockIdx.z * sB;

  // staging: one global_load_lds covers 128 rows x 64B (8 waves x 16 rows).
  const int scol = (((l & 3) ^ ((l >> 3) & 3)) << 3);  // pre-swizzled source chunk
  const uint16_t* gA = A + (bm + w * 16 + (l >> 2)) * (long)lda + scol;
  const uint16_t* gB = B + (bn + w * 16 + (l >> 2)) * (long)ldb + scol;
  const int ldsw = w * 1024;

#define STG_A3(slot, k0, r)                                                    \
  __builtin_amdgcn_global_load_lds(gA + (k0) + (long)(r) * 128 * lda,          \
      (uint16_t*)(lds + (slot) * 32768 + (r) * 8192 + ldsw), 16, 0, 0)
#define STG_B3(slot, k0, r)                                                    \
  __builtin_amdgcn_global_load_lds(gB + (k0) + (long)(r) * 128 * ldb,          \
      (uint16_t*)(lds + (slot) * 32768 + 16384 + (r) * 8192 + ldsw), 16, 0, 0)

  // fragment read geometry: row stride 64B; lane reads 16B at swizzled chunk
  const int lr = l & 15;
  const int chunkx = (((l >> 4) ^ ((lr >> 1) & 3)) << 4);  // bytes
  const int aoff = (wm * 128 + lr) * 64 + chunkx;
  const int boff = 16384 + (wn * 64 + lr) * 64 + chunkx;

  floatx4 acc[8][4];
#pragma unroll
  for (int i = 0; i < 8; i++)
#pragma unroll
    for (int j = 0; j < 4; j++) acc[i][j] = (floatx4){0.f, 0.f, 0.f, 0.f};

  const int nt = K >> 5;  // assumes nt >= 3
#pragma unroll
  for (int tt = 0; tt < 3; tt++) {
    STG_A3(tt, tt * 32, 0); STG_A3(tt, tt * 32, 1);
    STG_B3(tt, tt * 32, 0); STG_B3(tt, tt * 32, 1);
  }

  for (int t = 0; t < nt; t++) {
    const char* Ls = lds + (t & 3) * 32768;
    if (t + 2 < nt) asm volatile("s_waitcnt vmcnt(8)" ::: "memory");
    else            asm volatile("s_waitcnt vmcnt(0)" ::: "memory");
    SBAR();

    bf16x8 Bf[4], Af0[4], Af1[4];
#pragma unroll
    for (int j = 0; j < 4; j++) Bf[j] = *(const bf16x8*)(Ls + boff + j * 1024);
#pragma unroll
    for (int i = 0; i < 4; i++) Af0[i] = *(const bf16x8*)(Ls + aoff + i * 1024);
    SCHED();  // pin DS issue count: first 8 = Bf + Af0

    const long pk0 = (long)(t + 3) << 5;
    const int pslot = (t + 3) & 3;
    const bool pf = (t + 3 < nt);
    if (pf) { STG_A3(pslot, pk0, 0); STG_A3(pslot, pk0, 1); }

#pragma unroll
    for (int i = 0; i < 4; i++) Af1[i] = *(const bf16x8*)(Ls + aoff + (4 + i) * 1024);
    SCHED();

    asm volatile("s_waitcnt lgkmcnt(4)" ::: "memory");  // Bf+Af0 landed
    SCHED();
    __builtin_amdgcn_s_setprio(1);
#pragma unroll
    for (int i = 0; i < 4; i++)
#pragma unroll
      for (int j = 0; j < 4; j++) mfma16(acc[i][j], Af0[i], Bf[j]);
    __builtin_amdgcn_s_setprio(0);
    SCHED();

    if (pf) { STG_B3(pslot, pk0, 0); STG_B3(pslot, pk0, 1); }

    asm volatile("s_waitcnt lgkmcnt(0)" ::: "memory");
    SCHED();
    __builtin_amdgcn_s_setprio(1);
#pragma unroll
    for (int i = 0; i < 4; i++)
#pragma unroll
      for (int j = 0; j < 4; j++) mfma16(acc[4 + i][j], Af1[i], Bf[j]);
    __builtin_amdgcn_s_setprio(0);
    SCHED();
  }
#undef STG_A3
#undef STG_B3

  const long crow = bm + wm * 128 + ((l >> 4) * 4);
  const long ccol = bn + wn * 64 + (l & 15);
  if constexpr (MODE == 0) {
    float* C = (float*)C0v + (long)blockIdx.z * sC;
#pragma unroll
    for (int i = 0; i < 8; i++)
#pragma unroll
      for (int r = 0; r < 4; r++) {
        long row = crow + i * 16 + r;
#pragma unroll
        for (int j = 0; j < 4; j++) C[row * (long)ldc + ccol + j * 16] = acc[i][j][r];
      }
  } else if constexpr (MODE == 1) {
    uint16_t* C = (uint16_t*)C0v + (long)blockIdx.z * sC;
#pragma unroll
    for (int i = 0; i < 8; i++)
#pragma unroll
      for (int r = 0; r < 4; r++) {
        long row = crow + i * 16 + r;
#pragma unroll
        for (int j = 0; j < 4; j++) C[row * (long)ldc + ccol + j * 16] = f2bf(acc[i][j][r]);
      }
  } else if constexpr (MODE == 3) {
    const float s = 1.0f / 12.0f;
    uint16_t* C = (uint16_t*)C0v + (long)blockIdx.z * sC;
#pragma unroll
    for (int i = 0; i < 8; i++)
#pragma unroll
      for (int r = 0; r < 4; r++) {
        long row = crow + i * 16 + r;
#pragma unroll
        for (int j = 0; j < 4; j++) C[row * (long)ldc + ccol + j * 16] = f2bf(acc[i][j][r] * s);
      }
  } else {
    if (bn < 512) {
      uint16_t* C = (uint16_t*)C0v;
#pragma unroll
      for (int i = 0; i < 8; i++)
#pragma unroll
        for (int r = 0; r < 4; r++) {
          long row = crow + i * 16 + r;
#pragma unroll
          for (int j = 0; j < 4; j++) C[row * 512 + ccol + j * 16] = f2bf(acc[i][j][r]);
        }
    } else if (bn < 1024) {
      float* C = (float*)C1v;
      const long cc = ccol - 512;
#pragma unroll
      for (int i = 0; i < 8; i++)
#pragma unroll
        for (int r = 0; r < 4; r++) {
          long row = crow + i * 16 + r;
#pragma unroll
          for (int j = 0; j < 4; j++) C[row * 512 + cc + j * 16] = acc[i][j][r];
        }
    } else {
      uint16_t* C = (uint16_t*)C2v;
      const long cc = ccol - 1024;
#pragma unroll
      for (int i = 0; i < 8; i++)
#pragma unroll
        for (int r = 0; r < 4; r++) {
          long row = crow + i * 16 + r;
#pragma unroll
          for (int j = 0; j < 4; j++) C[row * 2560 + cc + j * 16] = f2bf(acc[i][j][r]);
        }
    }
  }
}

// ================= 256x128 pipelined GEMM (for the small-N o GEMM) =================
template<int OUTB>
__global__ void __launch_bounds__(512, 2) gemm256(
    const uint16_t* __restrict__ A, const uint16_t* __restrict__ B,
    void* __restrict__ Cv, int K, int lda, int ldb, int ldc,
    long sA, long sB, long sC)
{
  __shared__ __attribute__((aligned(16))) char lds[147456];
  const int tid = threadIdx.x;
  const int w = tid >> 6, l = tid & 63;
  const int wm = w >> 1, wn = w & 1;

  const int gx = gridDim.x;
  const int nwg = gx * gridDim.y;
  int id = blockIdx.y * gx + blockIdx.x;
  if ((nwg & 7) == 0) id = (id & 7) * (nwg >> 3) + (id >> 3);
  const long bm = (long)(id % gx) * 256;
  const long bn = (long)(id / gx) * 128;
  A += (long)blockIdx.z * sA;
  B += (long)blockIdx.z * sB;

  const int sr = l >> 3;
  const int sc = l & 7;
  const int scol = ((sc ^ sr) << 3);
  const uint16_t* gA = A + (bm + w * 8 + sr) * (long)lda + scol;
  const uint16_t* gB = B + (bn + w * 8 + sr) * (long)ldb + scol;
  const int ldsw = w * 1024;

#define STAGE_A(bufi, k0, r)                                                     \
  __builtin_amdgcn_global_load_lds(gA + (k0) + (long)(r) * 64 * lda,             \
      (uint16_t*)(lds + (bufi) * 49152 + (r) * 8192 + ldsw), 16, 0, 0)
#define STAGE_B(bufi, k0, r)                                                     \
  __builtin_amdgcn_global_load_lds(gB + (k0) + (long)(r) * 64 * ldb,             \
      (uint16_t*)(lds + (bufi) * 49152 + 32768 + (r) * 8192 + ldsw), 16, 0, 0)

  const int lr = l & 15;
  const int kk = (l >> 4) << 4;
  const int msk = (l & 7) << 4;
  const int ko0 = kk ^ msk;
  const int ko1 = (64 + kk) ^ msk;
  const int arow = (wm * 64 + lr) * 128;
  const int brow = (wn * 64 + lr) * 128;

  floatx4 acc[4][4];
#pragma unroll
  for (int i = 0; i < 4; i++)
#pragma unroll
    for (int j = 0; j < 4; j++) acc[i][j] = (floatx4){0.f, 0.f, 0.f, 0.f};

  const int nt = K >> 6;
#pragma unroll
  for (int r = 0; r < 4; r++) STAGE_A(0, 0, r);
#pragma unroll
  for (int r = 0; r < 2; r++) STAGE_B(0, 0, r);
#pragma unroll
  for (int r = 0; r < 4; r++) STAGE_A(1, 64, r);
#pragma unroll
  for (int r = 0; r < 2; r++) STAGE_B(1, 64, r);
  asm volatile("s_waitcnt vmcnt(6)" ::: "memory");
  SBAR();

  bf16x8 af0[4], bf0[4], af1[4], bf1[4];
  {
    const char* LA = lds + arow;
    const char* LB = lds + 32768 + brow;
#pragma unroll
    for (int i = 0; i < 4; i++) af0[i] = *(const bf16x8*)(LA + i * 2048 + ko0);
#pragma unroll
    for (int j = 0; j < 4; j++) bf0[j] = *(const bf16x8*)(LB + j * 2048 + ko0);
  }

  for (int t = 0; t < nt; t++) {
    const int buf = t % 3;
    const int pbuf = (t + 2) % 3;
    const long pk0 = (long)(t + 2) << 6;
    const char* LA = lds + buf * 49152 + arow;
    const char* LB = lds + buf * 49152 + 32768 + brow;
    const bool pf = (t + 2 < nt);

    if (pf) { STAGE_A(pbuf, pk0, 0); STAGE_A(pbuf, pk0, 1); STAGE_B(pbuf, pk0, 0); }
#pragma unroll
    for (int i = 0; i < 4; i++) af1[i] = *(const bf16x8*)(LA + i * 2048 + ko1);
#pragma unroll
    for (int j = 0; j < 4; j++) bf1[j] = *(const bf16x8*)(LB + j * 2048 + ko1);
    SCHED();
    __builtin_amdgcn_s_setprio(1);
#pragma unroll
    for (int i = 0; i < 4; i++)
#pragma unroll
      for (int j = 0; j < 4; j++) mfma16(acc[i][j], af0[i], bf0[j]);
    __builtin_amdgcn_s_setprio(0);
    SCHED();

    if (pf) { STAGE_A(pbuf, pk0, 2); STAGE_A(pbuf, pk0, 3); STAGE_B(pbuf, pk0, 1); }
    if (t < nt - 2) asm volatile("s_waitcnt vmcnt(6) lgkmcnt(0)" ::: "memory");
    else            asm volatile("s_waitcnt vmcnt(0) lgkmcnt(0)" ::: "memory");
    SBAR();
    if (t < nt - 1) {
      const char* LAn = lds + ((t + 1) % 3) * 49152 + arow;
      const char* LBn = lds + ((t + 1) % 3) * 49152 + 32768 + brow;
#pragma unroll
      for (int i = 0; i < 4; i++) af0[i] = *(const bf16x8*)(LAn + i * 2048 + ko0);
#pragma unroll
      for (int j = 0; j < 4; j++) bf0[j] = *(const bf16x8*)(LBn + j * 2048 + ko0);
    }
    SCHED();
    __builtin_amdgcn_s_setprio(1);
#pragma unroll
    for (int i = 0; i < 4; i++)
#pragma unroll
      for (int j = 0; j < 4; j++) mfma16(acc[i][j], af1[i], bf1[j]);
    __builtin_amdgcn_s_setprio(0);
    SCHED();
  }
#undef STAGE_A
#undef STAGE_B

  const long crow = bm + wm * 64 + ((l >> 4) * 4);
  const long ccol = bn + wn * 64 + (l & 15);
  if constexpr (OUTB == 0) {
    float* C = (float*)Cv + (long)blockIdx.z * sC;
#pragma unroll
    for (int i = 0; i < 4; i++)
#pragma unroll
      for (int r = 0; r < 4; r++) {
        long row = crow + i * 16 + r;
#pragma unroll
        for (int j = 0; j < 4; j++) C[row * (long)ldc + ccol + j * 16] = acc[i][j][r];
      }
  } else {
    uint16_t* C = (uint16_t*)Cv + (long)blockIdx.z * sC;
#pragma unroll
    for (int i = 0; i < 4; i++)
#pragma unroll
      for (int r = 0; r < 4; r++) {
        long row = crow + i * 16 + r;
#pragma unroll
        for (int j = 0; j < 4; j++) C[row * (long)ldc + ccol + j * 16] = f2bf(acc[i][j][r]);
      }
  }
}

// ================= legacy 128x128 GEMM (small weight-prep matmuls, split-K via z) =================
template<int OUTB>
__global__ void __launch_bounds__(256) gemm_bt(
    const uint16_t* __restrict__ A, const uint16_t* __restrict__ B,
    void* __restrict__ Cv, int K, int lda, int ldb, int ldc,
    long sA, long sB, long sC)
{
  __shared__ alignas(16) uint16_t As[4096];
  __shared__ alignas(16) uint16_t Bs[4096];
  const int tid = threadIdx.x;
  const int w = tid >> 6, l = tid & 63;
  const int wr = w >> 1, wc = w & 1;
  const long bm = (long)blockIdx.x * 128, bn = (long)blockIdx.y * 128;
  A += (long)blockIdx.z * sA;
  B += (long)blockIdx.z * sB;

  const uint16_t* ga0 = A + (bm + w * 16 + (l >> 2)) * (long)lda + (l & 3) * 8;
  const uint16_t* ga1 = ga0 + 64L * lda;
  const uint16_t* gb0 = B + (bn + w * 16 + (l >> 2)) * (long)ldb + (l & 3) * 8;
  const uint16_t* gb1 = gb0 + 64L * ldb;
  uint16_t* la0 = &As[w * 512];
  uint16_t* la1 = &As[2048 + w * 512];
  uint16_t* lb0 = &Bs[w * 512];
  uint16_t* lb1 = &Bs[2048 + w * 512];

  floatx4 acc[4][4];
#pragma unroll
  for (int i = 0; i < 4; i++)
#pragma unroll
    for (int j = 0; j < 4; j++) acc[i][j] = (floatx4){0.f, 0.f, 0.f, 0.f};

  const int rA = (wr * 64 + (l & 15)) * 32 + (l >> 4) * 8;
  const int rB = (wc * 64 + (l & 15)) * 32 + (l >> 4) * 8;

  for (int k0 = 0; k0 < K; k0 += 32) {
    __builtin_amdgcn_global_load_lds(ga0, la0, 16, 0, 0);
    __builtin_amdgcn_global_load_lds(ga1, la1, 16, 0, 0);
    __builtin_amdgcn_global_load_lds(gb0, lb0, 16, 0, 0);
    __builtin_amdgcn_global_load_lds(gb1, lb1, 16, 0, 0);
    ga0 += 32; ga1 += 32; gb0 += 32; gb1 += 32;
    __syncthreads();
    bf16x8 af[4], bfr[4];
#pragma unroll
    for (int i = 0; i < 4; i++) af[i] = *(const bf16x8*)&As[rA + i * 512];
#pragma unroll
    for (int j = 0; j < 4; j++) bfr[j] = *(const bf16x8*)&Bs[rB + j * 512];
#pragma unroll
    for (int i = 0; i < 4; i++)
#pragma unroll
      for (int j = 0; j < 4; j++) mfma16(acc[i][j], af[i], bfr[j]);
    __syncthreads();
  }

  const long crow = bm + wr * 64 + ((l >> 4) * 4);
  const long ccol = bn + wc * 64 + (l & 15);
  if constexpr (OUTB == 0) {
    float* C = (float*)Cv + (long)blockIdx.z * sC;
#pragma unroll
    for (int i = 0; i < 4; i++)
#pragma unroll
      for (int r = 0; r < 4; r++) {
        long row = crow + i * 16 + r;
#pragma unroll
        for (int j = 0; j < 4; j++) C[row * (long)ldc + ccol + j * 16] = acc[i][j][r];
      }
  } else {
    uint16_t* C = (uint16_t*)Cv + (long)blockIdx.z * sC;
#pragma unroll
    for (int i = 0; i < 4; i++)
#pragma unroll
      for (int r = 0; r < 4; r++) {
        long row = crow + i * 16 + r;
#pragma unroll
        for (int j = 0; j < 4; j++) C[row * (long)ldc + ccol + j * 16] = f2bf(acc[i][j][r]);
      }
  }
}

// ---------- split-K reduce: out_bf16[i] = sum_s in[s*stride + i] ----------
__global__ void __launch_bounds__(256) reduceK(const float* __restrict__ in,
                                               uint16_t* __restrict__ out,
                                               long n, int S, long stride) {
  long i = ((long)blockIdx.x * 256 + threadIdx.x) * 4;
  if (i >= n) return;
  float4 s = *(const float4*)(in + i);
  for (int k = 1; k < S; k++) {
    float4 t = *(const float4*)(in + k * stride + i);
    s.x += t.x; s.y += t.y; s.z += t.z; s.w += t.w;
  }
  ushort4 o; o.x = f2bf(s.x); o.y = f2bf(s.y); o.z = f2bf(s.z); o.w = f2bf(s.w);
  *(ushort4*)(out + i) = o;
}

// ---------- fp32 -> bf16 convert (h) ----------
__global__ void __launch_bounds__(256) cvt_k(const float* __restrict__ in,
                                             uint16_t* __restrict__ out, long n) {
  long i = ((long)blockIdx.x * 256 + threadIdx.x) * 4;
  if (i >= n) return;
  float4 v = *(const float4*)(in + i);
  ushort4 o; o.x = f2bf(v.x); o.y = f2bf(v.y); o.z = f2bf(v.z); o.w = f2bf(v.w);
  *(ushort4*)(out + i) = o;
}

// ---------- fused small-weight converts + rope table (one launch) ----------
__global__ void __launch_bounds__(256) prep_small(
    const float* __restrict__ wdq, const float* __restrict__ wdkv,
    const float* __restrict__ wqr, const float* __restrict__ wkr,
    const float* __restrict__ wo,
    uint16_t* __restrict__ wdq_b, uint16_t* __restrict__ wdkv_b,
    uint16_t* __restrict__ wqr_b, uint16_t* __restrict__ wkr_b,
    uint16_t* __restrict__ wo_b, float2* __restrict__ rtab)
{
  const int b = blockIdx.x;
  if (b < 11264) {
    const float* src; uint16_t* dst; long off;
    if (b < 1024)      { src = wdq;  dst = wdq_b;  off = b; }
    else if (b < 2048) { src = wdkv; dst = wdkv_b; off = b - 1024; }
    else if (b < 3072) { src = wqr;  dst = wqr_b;  off = b - 2048; }
    else if (b < 7168) { src = wkr;  dst = wkr_b;  off = b - 3072; }
    else               { src = wo;   dst = wo_b;   off = b - 7168; }
    long i = (off * 256 + threadIdx.x) * 4;
    float4 v = *(const float4*)(src + i);
    ushort4 o; o.x = f2bf(v.x); o.y = f2bf(v.y); o.z = f2bf(v.z); o.w = f2bf(v.w);
    *(ushort4*)(dst + i) = o;
  } else {
    int idx = (b - 11264) * 256 + threadIdx.x;  // 2048*64
    int s = idx >> 6, fi = idx & 63;
    float f = powf(10000.0f, -(float)fi * (1.0f / 64.0f));
    float ang = (float)s * f;
    rtab[idx] = make_float2(cosf(ang), sinf(ang));
  }
}

// ---------- transpose (R,Cc) -> (Cc,R), bf16 out ----------
template<typename TIN>
__global__ void __launch_bounds__(256) transpose_to_bf16(
    const TIN* __restrict__ in, uint16_t* __restrict__ out,
    int ld_in, int ld_out, long sIn, long sOut)
{
  __shared__ float tile[32][33];
  in += (long)blockIdx.z * sIn;
  out += (long)blockIdx.z * sOut;
  const int rb = blockIdx.y * 32, cb = blockIdx.x * 32;
#pragma unroll
  for (int i = 0; i < 32; i += 8)
    tile[threadIdx.y + i][threadIdx.x] =
        ld_as_float(in[(long)(rb + threadIdx.y + i) * ld_in + cb + threadIdx.x]);
  __syncthreads();
#pragma unroll
  for (int i = 0; i < 32; i += 8)
    out[(long)(cb + threadIdx.y + i) * ld_out + rb + threadIdx.x] =
        f2bf(tile[threadIdx.x][threadIdx.y + i]);
}

// ---------- rmsnorm: one block per row; DIM = PT*256 ----------
template<int PT, typename TIN>
__global__ void __launch_bounds__(256) rmsnorm_k(
    const TIN* __restrict__ in, const float* __restrict__ g,
    float* __restrict__ out_f, uint16_t* __restrict__ out_b, int ld_b)
{
  constexpr int DIM = PT * 256;
  __shared__ float sm[9];
  const TIN* x = in + (long)blockIdx.x * DIM;
  const int base = threadIdx.x * PT;
  float v[PT];
  if constexpr (sizeof(TIN) == 2) {
    if constexpr (PT >= 8) {
#pragma unroll
      for (int i = 0; i < PT; i += 8) {
        u16x8 t = *(const u16x8*)&x[base + i];
#pragma unroll
        for (int q = 0; q < 8; q++) v[i + q] = bf2f(t[q]);
      }
    } else {
#pragma unroll
      for (int i = 0; i < PT; i += 2) {
        ushort2 t = *(const ushort2*)&x[base + i];
        v[i] = bf2f(t.x); v[i + 1] = bf2f(t.y);
      }
    }
  } else if constexpr (PT == 2) {
    float2 t = *(const float2*)&x[base]; v[0] = t.x; v[1] = t.y;
  } else {
#pragma unroll
    for (int i = 0; i < PT; i += 4) {
      float4 t = *(const float4*)&x[base + i];
      v[i] = t.x; v[i + 1] = t.y; v[i + 2] = t.z; v[i + 3] = t.w;
    }
  }
  float ss = 0.f;
#pragma unroll
  for (int i = 0; i < PT; i++) ss += v[i] * v[i];
#pragma unroll
  for (int o = 32; o; o >>= 1) ss += __shfl_down(ss, o);
  if ((threadIdx.x & 63) == 0) sm[threadIdx.x >> 6] = ss;
  __syncthreads();
  if (threadIdx.x == 0)
    sm[8] = rsqrtf((sm[0] + sm[1] + sm[2] + sm[3]) * (1.0f / DIM) + 1.1920929e-7f);
  __syncthreads();
  const float sc = sm[8];
#pragma unroll
  for (int i = 0; i < PT; i++) {
    float y = v[i] * sc * g[base + i];
    if (out_f) out_f[(long)blockIdx.x * DIM + base + i] = y;
    if (out_b) out_b[(long)blockIdx.x * ld_b + base + i] = f2bf(y);
  }
}

// ---------- rope apply: in bf16 (8192,2048); bf16 out -> cat[:,512:]; optional fp32 out ----------
template<bool WF32>
__global__ void __launch_bounds__(256) rope_k(
    const uint16_t* __restrict__ in, uint16_t* __restrict__ outb,
    float* __restrict__ outf, const float2* __restrict__ tab)
{
  long idx = (long)blockIdx.x * 256 + threadIdx.x;  // 8192*1024 pairs
  int r = (int)(idx >> 10);
  int pp = (int)idx & 1023;
  int s = r & 2047;
  int fi = pp & 63;
  ushort2 xv = *(const ushort2*)(in + ((long)r << 11) + 2 * pp);
  float x0 = bf2f(xv.x), x1 = bf2f(xv.y);
  float2 cs = tab[(s << 6) + fi];
  float y0 = x0 * cs.x - x1 * cs.y;
  float y1 = x0 * cs.y + x1 * cs.x;
  ushort2 ov; ov.x = f2bf(y0); ov.y = f2bf(y1);
  *(ushort2*)(outb + (long)r * 2560 + 512 + 2 * pp) = ov;
  if (WF32) *(float2*)(outf + ((long)r << 11) + 2 * pp) = make_float2(y0, y1);
}

// ---------- softmax over rows of 2048, bf16 in (pre-scaled), bf16 out ----------
__global__ void __launch_bounds__(256) softmax_k(const uint16_t* __restrict__ sc,
                                                 uint16_t* __restrict__ attn) {
  __shared__ float sm[9];
  const uint16_t* x = sc + ((long)blockIdx.x << 11);
  const int base = threadIdx.x * 8;
  float v[8];
  u16x8 t = *(const u16x8*)&x[base];
#pragma unroll
  for (int i = 0; i < 8; i++) v[i] = bf2f(t[i]);
  float m = -1e30f;
#pragma unroll
  for (int i = 0; i < 8; i++) m = fmaxf(m, v[i]);
#pragma unroll
  for (int o = 32; o; o >>= 1) m = fmaxf(m, __shfl_down(m, o));
  if ((threadIdx.x & 63) == 0) sm[threadIdx.x >> 6] = m;
  __syncthreads();
  if (threadIdx.x == 0)
    sm[8] = fmaxf(fmaxf(sm[0], sm[1]), fmaxf(sm[2], sm[3]));
  __syncthreads();
  m = sm[8];
  __syncthreads();
  float ss = 0.f;
#pragma unroll
  for (int i = 0; i < 8; i++) { v[i] = __expf(v[i] - m); ss += v[i]; }
#pragma unroll
  for (int o = 32; o; o >>= 1) ss += __shfl_down(ss, o);
  if ((threadIdx.x & 63) == 0) sm[threadIdx.x >> 6] = ss;
  __syncthreads();
  if (threadIdx.x == 0) sm[8] = 1.0f / (sm[0] + sm[1] + sm[2] + sm[3]);
  __syncthreads();
  const float r = sm[8];
  ushort4 o1, o2;
  o1.x = f2bf(v[0] * r); o1.y = f2bf(v[1] * r); o1.z = f2bf(v[2] * r); o1.w = f2bf(v[3] * r);
  o2.x = f2bf(v[4] * r); o2.y = f2bf(v[5] * r); o2.z = f2bf(v[6] * r); o2.w = f2bf(v[7] * r);
  uint16_t* dst = attn + ((long)blockIdx.x << 11) + base;
  *(ushort4*)dst = o1;
  *(ushort4*)(dst + 4) = o2;
}

// ---------- orchestration ----------
extern "C" void kernel_launch(void* const* d_in, const int* in_sizes, int n_in,
                              void* d_out, int out_size, void* d_ws, size_t ws_size,
                              hipStream_t stream) {
  (void)in_sizes; (void)n_in; (void)out_size; (void)ws_size;
  const float* h    = (const float*)d_in[0];
  const float* wdkv = (const float*)d_in[1];
  const float* wuk  = (const float*)d_in[2];
  const float* wuv  = (const float*)d_in[3];
  const float* wdq  = (const float*)d_in[4];
  const float* wuq  = (const float*)d_in[5];
  const float* wkr  = (const float*)d_in[6];
  const float* wqr  = (const float*)d_in[7];
  const float* wo   = (const float*)d_in[8];
  const float* g1   = (const float*)d_in[9];
  const float* g2   = (const float*)d_in[10];
  const float* g3   = (const float*)d_in[11];

  float* u_out   = (float*)d_out;                 // (4,2048,2048)
  float* ckv_out = u_out + 16777216L;             // (4,2048,512)
  float* kr_out  = ckv_out + 4194304L;            // (4,2048,2048)

  char* p = (char*)d_ws;
  auto alloc = [&](size_t bytes) -> void* {
    void* q = (void*)p; p += (bytes + 255) & ~(size_t)255; return q;
  };
  uint16_t* hb     = (uint16_t*)alloc(16777216ULL * 2);  // h bf16
  uint16_t* wcat   = (uint16_t*)alloc(3145728ULL * 2);   // (1536,2048) [wdq;wdkv;Bqt]
  uint16_t* wqr_b  = (uint16_t*)alloc(1048576ULL * 2);
  uint16_t* wkr_b  = (uint16_t*)alloc(4194304ULL * 2);
  uint16_t* wo_b   = (uint16_t*)alloc(4194304ULL * 2);
  uint16_t* wukT   = (uint16_t*)alloc(1048576ULL * 2);   // (512,2048)
  uint16_t* wuqT   = (uint16_t*)alloc(1048576ULL * 2);
  uint16_t* wuvT   = (uint16_t*)alloc(1048576ULL * 2);
  uint16_t* wdqT   = (uint16_t*)alloc(1048576ULL * 2);   // (2048,512)
  uint16_t* T1t    = (uint16_t*)alloc(262144ULL * 2);    // (512,512)
  uint16_t* awoT   = (uint16_t*)alloc(1048576ULL * 2);   // absorbed_w_o^T (2048,512)
  uint16_t* cqpre  = (uint16_t*)alloc(4194304ULL * 2);   // (8192,512) bf16 cq-pre
  uint16_t* cq_b   = (uint16_t*)alloc(4194304ULL * 2);   // (8192,512)
  uint16_t* catq   = (uint16_t*)alloc(20971520ULL * 2);  // (8192,2560) [aq|qr]
  uint16_t* catk   = (uint16_t*)alloc(20971520ULL * 2);  // (8192,2560) [ckv|kr]
  uint16_t* ckvT   = (uint16_t*)alloc(4194304ULL * 2);   // 4 x (512,2048)
  uint16_t* o_b    = (uint16_t*)alloc(4194304ULL * 2);   // (8192,512)
  float2*   rtab   = (float2*)alloc(131072ULL * 8);      // 2048x64 (cos,sin)
  float*    tmpS2  = (float*)alloc(4194304ULL * 4);      // (8192,512) fp32 ckv-pre
  float*    tmpB   = (float*)alloc(16777216ULL * 4);     // (8192,2048) scratch
  float*    redT   = (float*)alloc(1048576ULL * 4);      // 4 x (512,512) partials
  float*    redW   = (float*)alloc(4194304ULL * 4);      // 4 x (2048,512) partials
  uint16_t* tmpBb  = (uint16_t*)tmpB;                    // alias: (8192,2048) bf16
  uint16_t* attn   = catq;  // alias: catq dead after scores GEMM

  uint16_t* wdq_b  = wcat;                  // rows 0-511
  uint16_t* wdkv_b = wcat + 1048576;        // rows 512-1023
  uint16_t* Bqt    = wcat + 2097152;        // rows 1024-1535 (absorbed_w_q^T)

  const dim3 b256(256);
  const dim3 b512(512);
  const dim3 tb(32, 8);

  // h convert + fused small-weight converts + rope table
  cvt_k<<<dim3(16384), b256, 0, stream>>>(h, hb, 16777216L);
  prep_small<<<dim3(11776), b256, 0, stream>>>(
      wdq, wdkv, wqr, wkr, wo, wdq_b, wdkv_b, wqr_b, wkr_b, wo_b, rtab);
  // weight transposes (fp32 -> bf16)
  transpose_to_bf16<float><<<dim3(16, 64, 1), tb, 0, stream>>>(wuk, wukT, 512, 2048, 0, 0);
  transpose_to_bf16<float><<<dim3(16, 64, 1), tb, 0, stream>>>(wuq, wuqT, 512, 2048, 0, 0);
  transpose_to_bf16<float><<<dim3(16, 64, 1), tb, 0, stream>>>(wuv, wuvT, 512, 2048, 0, 0);
  transpose_to_bf16<float><<<dim3(64, 16, 1), tb, 0, stream>>>(wdq, wdqT, 2048, 512, 0, 0);

  // absorbed weights — split-K (z=4, Kc=512) + deterministic reduce
  gemm_bt<0><<<dim3(4, 4, 4), b256, 0, stream>>>(
      wukT, wuqT, redT, 512, 2048, 2048, 512, 512L, 512L, 262144L);
  reduceK<<<dim3(256), b256, 0, stream>>>(redT, T1t, 262144L, 4, 262144L);
  gemm_bt<0><<<dim3(16, 4, 4), b256, 0, stream>>>(
      wo_b, wuvT, redW, 512, 2048, 2048, 512, 512L, 512L, 1048576L);
  reduceK<<<dim3(1024), b256, 0, stream>>>(redW, awoT, 1048576L, 4, 1048576L);
  gemm_bt<1><<<dim3(4, 16, 1), b256, 0, stream>>>(T1t, wdqT, Bqt, 512, 512, 512, 2048, 0, 0, 0);

  // fused: [cq-pre(bf16) | ckv-pre(fp32) | aq(bf16)] = h @ [wdq; wdkv; Bqt]^T
  gemm256v3<2><<<dim3(32, 6, 1), b512, 0, stream>>>(
      hb, wcat, cqpre, tmpS2, catq, 2048, 2048, 2048, 0, 0, 0, 0, 2);
  // cq = rmsnorm(cq-pre, g1)
  rmsnorm_k<2, uint16_t><<<dim3(8192), b256, 0, stream>>>(cqpre, g1, nullptr, cq_b, 512);
  // qr = rope(cq @ wqr^T) -> catq[:,512:]
  gemm256v3<1><<<dim3(32, 8, 1), b512, 0, stream>>>(
      cq_b, wqr_b, tmpBb, nullptr, nullptr, 512, 512, 512, 2048, 0, 0, 0, 4);
  rope_k<false><<<dim3(32768), b256, 0, stream>>>(tmpBb, catq, nullptr, rtab);
  // ckv = rmsnorm(ckv-pre, g2) -> ckv_out (fp32) + catk[:,0:512] (bf16)
  rmsnorm_k<2, float><<<dim3(8192), b256, 0, stream>>>(tmpS2, g2, ckv_out, catk, 2560);
  // ckvT: 4 x (512,2048) from catk cols 0..511
  transpose_to_bf16<uint16_t><<<dim3(16, 64, 4), tb, 0, stream>>>(
      catk, ckvT, 2560, 2048, 2048L * 2560, 512L * 2048);
  // kr = rope(h @ wkr^T) -> kr_out (fp32) + catk[:,512:]
  gemm256v3<1><<<dim3(32, 8, 1), b512, 0, stream>>>(
      hb, wkr_b, tmpBb, nullptr, nullptr, 2048, 2048, 2048, 2048, 0, 0, 0, 4);
  rope_k<true><<<dim3(32768), b256, 0, stream>>>(tmpBb, catk, kr_out, rtab);
  // scores[b]/12 = (catq_b @ catk_b^T)/12 -> tmpBb bf16 (K=2560)
  gemm256v3<3><<<dim3(8, 8, 4), b512, 0, stream>>>(
      catq, catk, tmpBb, nullptr, nullptr, 2560, 2560, 2560, 2048,
      5242880L, 5242880L, 4194304L, 2);
  // softmax -> attn bf16 (aliases catq)
  softmax_k<<<dim3(8192), b256, 0, stream>>>(tmpBb, attn);
  // o[b] = attn_b @ ckv_b (via ckvT) -> o_b bf16
  gemm256<1><<<dim3(8, 4, 4), b512, 0, stream>>>(
      attn, ckvT, o_b, 2048, 2048, 2048, 512, 4194304L, 1048576L, 1048576L);
  // u = rmsnorm(o @ absorbed_w_o, g3) -> u_out
  gemm256v3<1><<<dim3(32, 8, 1), b512, 0, stream>>>(
      o_b, awoT, tmpBb, nullptr, nullptr, 512, 512, 512, 2048, 0, 0, 0, 4);
  rmsnorm_k<8, uint16_t><<<dim3(8192), b256, 0, stream>>>(tmpBb, g3, u_out, nullptr, 0);
}

// Round 11
// 493.886 us; speedup vs baseline: 1.1380x; 1.0173x over previous
//
#include <hip/hip_runtime.h>
#include <stdint.h>

// ---------- small helpers ----------
typedef __attribute__((ext_vector_type(8))) short bf16x8;
typedef __attribute__((ext_vector_type(8))) unsigned short u16x8;
typedef __attribute__((ext_vector_type(4))) float floatx4;

__device__ __forceinline__ uint16_t f2bf(float f) {
  union { float f; uint32_t u; } v; v.f = f;
  uint32_t r = v.u + 0x7fffu + ((v.u >> 16) & 1u);
  return (uint16_t)(r >> 16);
}
__device__ __forceinline__ float bf2f(uint16_t b) {
  union { uint32_t u; float f; } v; v.u = ((uint32_t)b) << 16;
  return v.f;
}
__device__ __forceinline__ float ld_as_float(float v) { return v; }
__device__ __forceinline__ float ld_as_float(uint16_t v) { return bf2f(v); }

__device__ __forceinline__ void mfma16(floatx4& d, bf16x8 a, bf16x8 b) {
  asm("v_mfma_f32_16x16x32_bf16 %0, %1, %2, %0" : "+v"(d) : "v"(a), "v"(b));
}

#define FENCE() asm volatile("" ::: "memory")
#define SCHED() __builtin_amdgcn_sched_barrier(0)
#define SBAR()                                  \
  do {                                          \
    FENCE();                                    \
    __builtin_amdgcn_sched_barrier(0);          \
    __builtin_amdgcn_s_barrier();               \
    __builtin_amdgcn_sched_barrier(0);          \
    FENCE();                                    \
  } while (0)

// ================= v5 GEMM: 256x256, BK=32, 4-slot ring, cross-tile reg prefetch =================
// C(M,N) = A(M,K) @ B(N,K)^T, bf16 in, fp32 acc. Requires K % 32 == 0, K >= 128.
// 512 threads = 8 waves (2M x 4N), per-wave 128x64 output (8x4 frags).
// LDS: 4 slots x (A 16KB + B 16KB) = 128 KB. Tile t in slot t%4, staging depth 3.
// v5 (r10 fix): every MFMA cluster consumes registers read >=1 phase earlier, so
// LDS service overlaps MFMA instead of alternating (r10 PMC: 1032 cyc MFMA busy
// vs 2591 cyc/tile; the idle gap was post-barrier ds_read serialization).
// Per tile t:  [regs hold Bf(t),Af0(t)]
//   ph1: read Af1(t) | stage(t+3) A,A | lgkmcnt(4) | 16 MFMA (Af0xBf)
//   mid: vmcnt(6|4|0 tail) + lgkmcnt(0) + barrier   [t+1 staging visible]
//   ph2: read Bfn,Af0(t+1) | stage(t+3) B,B | 16 MFMA (Af1xBf) | Bf=Bfn
// Hazards: WAR — slot t-1's last read drains before t-1's mid-barrier; its
// re-staging (as t+3) starts >=1 barrier later. RAW — mid vmcnt retires t+1
// (in-flight = t+2's 4 + t+3's 2 = 6), barrier makes it chip-visible.
// Chunk-XOR swizzle (both sides, same involution; r7-verified conflicts=0):
//   write: source chunk = (l&3) ^ ((l>>3)&3);  read: chunk = (l>>4) ^ ((lr>>1)&3)
// XCD mapping: 1D 8-way swizzle + swzG 2D supertile shaping (r10: -33% FETCH).
// MODE 0: fp32 C0; 1: bf16 C0; 2: routed (cols 0-511 bf16 C0 ld512 cq-pre,
//   512-1023 fp32 C1 ld512 ckv-pre, 1024-1535 bf16 C2 ld2560 aq);
// 3: bf16 C0 with fused *(1/12) scale.
template<int MODE>
__global__ void __launch_bounds__(512, 1) gemm256v3(
    const uint16_t* __restrict__ A, const uint16_t* __restrict__ B,
    void* __restrict__ C0v, void* __restrict__ C1v, void* __restrict__ C2v,
    int K, int lda, int ldb, int ldc,
    long sA, long sB, long sC, int swzG)
{
  __shared__ __attribute__((aligned(16))) char lds[131072];
  const int tid = threadIdx.x;
  const int w = tid >> 6, l = tid & 63;
  const int wm = w >> 2, wn = w & 3;

  // XCD-aware swizzle + 2D supertile shaping
  const int gx = gridDim.x;
  const int nwg = gx * gridDim.y;
  int id = blockIdx.y * gx + blockIdx.x;
  if ((nwg & 7) == 0) id = (id & 7) * (nwg >> 3) + (id >> 3);
  const int grp = gx * swzG;
  const int ing = id % grp;
  const long bm = (long)(ing / swzG) * 256;
  const long bn = ((long)(id / grp) * swzG + (ing % swzG)) * 256;
  A += (long)blockIdx.z * sA;
  B += (long)blockIdx.z * sB;

  // staging: one global_load_lds covers 128 rows x 64B (8 waves x 16 rows).
  const int scol = (((l & 3) ^ ((l >> 3) & 3)) << 3);  // pre-swizzled source chunk
  const uint16_t* gA = A + (bm + w * 16 + (l >> 2)) * (long)lda + scol;
  const uint16_t* gB = B + (bn + w * 16 + (l >> 2)) * (long)ldb + scol;
  const int ldsw = w * 1024;

#define STG_A3(slot, k0, r)                                                    \
  __builtin_amdgcn_global_load_lds(gA + (k0) + (long)(r) * 128 * lda,          \
      (uint16_t*)(lds + (slot) * 32768 + (r) * 8192 + ldsw), 16, 0, 0)
#define STG_B3(slot, k0, r)                                                    \
  __builtin_amdgcn_global_load_lds(gB + (k0) + (long)(r) * 128 * ldb,          \
      (uint16_t*)(lds + (slot) * 32768 + 16384 + (r) * 8192 + ldsw), 16, 0, 0)

  // fragment read geometry: row stride 64B; lane reads 16B at swizzled chunk
  const int lr = l & 15;
  const int chunkx = (((l >> 4) ^ ((lr >> 1) & 3)) << 4);  // bytes
  const int aoff = (wm * 128 + lr) * 64 + chunkx;
  const int boff = 16384 + (wn * 64 + lr) * 64 + chunkx;

  floatx4 acc[8][4];
#pragma unroll
  for (int i = 0; i < 8; i++)
#pragma unroll
    for (int j = 0; j < 4; j++) acc[i][j] = (floatx4){0.f, 0.f, 0.f, 0.f};

  const int nt = K >> 5;  // assumes nt >= 4
#pragma unroll
  for (int tt = 0; tt < 3; tt++) {
    STG_A3(tt, tt * 32, 0); STG_A3(tt, tt * 32, 1);
    STG_B3(tt, tt * 32, 0); STG_B3(tt, tt * 32, 1);
  }
  asm volatile("s_waitcnt vmcnt(8)" ::: "memory");  // tile 0 landed
  SBAR();

  bf16x8 Bf[4], Bfn[4], Af0[4], Af1[4];
#pragma unroll
  for (int j = 0; j < 4; j++) Bf[j] = *(const bf16x8*)(lds + boff + j * 1024);
#pragma unroll
  for (int i = 0; i < 4; i++) Af0[i] = *(const bf16x8*)(lds + aoff + i * 1024);

  for (int t = 0; t < nt; t++) {
    const char* Ls = lds + (t & 3) * 32768;
    const char* Ln = lds + ((t + 1) & 3) * 32768;
    const long pk0 = (long)(t + 3) << 5;
    const int pslot = (t + 3) & 3;
    const bool pf = (t + 3 < nt);

    // ---- phase 1: read Af1(t), stage (t+3) A, MFMA on Af0(t) x Bf(t) ----
#pragma unroll
    for (int i = 0; i < 4; i++) Af1[i] = *(const bf16x8*)(Ls + aoff + (4 + i) * 1024);
    SCHED();
    if (pf) { STG_A3(pslot, pk0, 0); STG_A3(pslot, pk0, 1); }
    asm volatile("s_waitcnt lgkmcnt(4)" ::: "memory");  // Bf+Af0 landed; Af1 in flight
    SCHED();
    __builtin_amdgcn_s_setprio(1);
#pragma unroll
    for (int i = 0; i < 4; i++)
#pragma unroll
      for (int j = 0; j < 4; j++) mfma16(acc[i][j], Af0[i], Bf[j]);
    __builtin_amdgcn_s_setprio(0);
    SCHED();

    // ---- mid: retire t+1 staging (counted), drain Af1 reads, fence ----
    if (t + 3 < nt)      asm volatile("s_waitcnt vmcnt(6)" ::: "memory");
    else if (t + 2 < nt) asm volatile("s_waitcnt vmcnt(4)" ::: "memory");
    else if (t + 1 < nt) asm volatile("s_waitcnt vmcnt(0)" ::: "memory");
    asm volatile("s_waitcnt lgkmcnt(0)" ::: "memory");
    SBAR();

    // ---- phase 2: read Bf/Af0 of t+1 (overlaps MFMA), stage (t+3) B, MFMA Af1 x Bf ----
    if (t + 1 < nt) {
#pragma unroll
      for (int j = 0; j < 4; j++) Bfn[j] = *(const bf16x8*)(Ln + boff + j * 1024);
#pragma unroll
      for (int i = 0; i < 4; i++) Af0[i] = *(const bf16x8*)(Ln + aoff + i * 1024);
    }
    SCHED();
    if (pf) { STG_B3(pslot, pk0, 0); STG_B3(pslot, pk0, 1); }
    SCHED();
    __builtin_amdgcn_s_setprio(1);
#pragma unroll
    for (int i = 0; i < 4; i++)
#pragma unroll
      for (int j = 0; j < 4; j++) mfma16(acc[4 + i][j], Af1[i], Bf[j]);
    __builtin_amdgcn_s_setprio(0);
    SCHED();
#pragma unroll
    for (int j = 0; j < 4; j++) Bf[j] = Bfn[j];
  }
#undef STG_A3
#undef STG_B3

  const long crow = bm + wm * 128 + ((l >> 4) * 4);
  const long ccol = bn + wn * 64 + (l & 15);
  if constexpr (MODE == 0) {
    float* C = (float*)C0v + (long)blockIdx.z * sC;
#pragma unroll
    for (int i = 0; i < 8; i++)
#pragma unroll
      for (int r = 0; r < 4; r++) {
        long row = crow + i * 16 + r;
#pragma unroll
        for (int j = 0; j < 4; j++) C[row * (long)ldc + ccol + j * 16] = acc[i][j][r];
      }
  } else if constexpr (MODE == 1) {
    uint16_t* C = (uint16_t*)C0v + (long)blockIdx.z * sC;
#pragma unroll
    for (int i = 0; i < 8; i++)
#pragma unroll
      for (int r = 0; r < 4; r++) {
        long row = crow + i * 16 + r;
#pragma unroll
        for (int j = 0; j < 4; j++) C[row * (long)ldc + ccol + j * 16] = f2bf(acc[i][j][r]);
      }
  } else if constexpr (MODE == 3) {
    const float s = 1.0f / 12.0f;
    uint16_t* C = (uint16_t*)C0v + (long)blockIdx.z * sC;
#pragma unroll
    for (int i = 0; i < 8; i++)
#pragma unroll
      for (int r = 0; r < 4; r++) {
        long row = crow + i * 16 + r;
#pragma unroll
        for (int j = 0; j < 4; j++) C[row * (long)ldc + ccol + j * 16] = f2bf(acc[i][j][r] * s);
      }
  } else {
    if (bn < 512) {
      uint16_t* C = (uint16_t*)C0v;
#pragma unroll
      for (int i = 0; i < 8; i++)
#pragma unroll
        for (int r = 0; r < 4; r++) {
          long row = crow + i * 16 + r;
#pragma unroll
          for (int j = 0; j < 4; j++) C[row * 512 + ccol + j * 16] = f2bf(acc[i][j][r]);
        }
    } else if (bn < 1024) {
      float* C = (float*)C1v;
      const long cc = ccol - 512;
#pragma unroll
      for (int i = 0; i < 8; i++)
#pragma unroll
        for (int r = 0; r < 4; r++) {
          long row = crow + i * 16 + r;
#pragma unroll
          for (int j = 0; j < 4; j++) C[row * 512 + cc + j * 16] = acc[i][j][r];
        }
    } else {
      uint16_t* C = (uint16_t*)C2v;
      const long cc = ccol - 1024;
#pragma unroll
      for (int i = 0; i < 8; i++)
#pragma unroll
        for (int r = 0; r < 4; r++) {
          long row = crow + i * 16 + r;
#pragma unroll
          for (int j = 0; j < 4; j++) C[row * 2560 + cc + j * 16] = f2bf(acc[i][j][r]);
        }
    }
  }
}

// ================= 256x128 pipelined GEMM (for the small-N o GEMM) =================
template<int OUTB>
__global__ void __launch_bounds__(512, 2) gemm256(
    const uint16_t* __restrict__ A, const uint16_t* __restrict__ B,
    void* __restrict__ Cv, int K, int lda, int ldb, int ldc,
    long sA, long sB, long sC)
{
  __shared__ __attribute__((aligned(16))) char lds[147456];
  const int tid = threadIdx.x;
  const int w = tid >> 6, l = tid & 63;
  const int wm = w >> 1, wn = w & 1;

  const int gx = gridDim.x;
  const int nwg = gx * gridDim.y;
  int id = blockIdx.y * gx + blockIdx.x;
  if ((nwg & 7) == 0) id = (id & 7) * (nwg >> 3) + (id >> 3);
  const long bm = (long)(id % gx) * 256;
  const long bn = (long)(id / gx) * 128;
  A += (long)blockIdx.z * sA;
  B += (long)blockIdx.z * sB;

  const int sr = l >> 3;
  const int sc = l & 7;
  const int scol = ((sc ^ sr) << 3);
  const uint16_t* gA = A + (bm + w * 8 + sr) * (long)lda + scol;
  const uint16_t* gB = B + (bn + w * 8 + sr) * (long)ldb + scol;
  const int ldsw = w * 1024;

#define STAGE_A(bufi, k0, r)                                                     \
  __builtin_amdgcn_global_load_lds(gA + (k0) + (long)(r) * 64 * lda,             \
      (uint16_t*)(lds + (bufi) * 49152 + (r) * 8192 + ldsw), 16, 0, 0)
#define STAGE_B(bufi, k0, r)                                                     \
  __builtin_amdgcn_global_load_lds(gB + (k0) + (long)(r) * 64 * ldb,             \
      (uint16_t*)(lds + (bufi) * 49152 + 32768 + (r) * 8192 + ldsw), 16, 0, 0)

  const int lr = l & 15;
  const int kk = (l >> 4) << 4;
  const int msk = (l & 7) << 4;
  const int ko0 = kk ^ msk;
  const int ko1 = (64 + kk) ^ msk;
  const int arow = (wm * 64 + lr) * 128;
  const int brow = (wn * 64 + lr) * 128;

  floatx4 acc[4][4];
#pragma unroll
  for (int i = 0; i < 4; i++)
#pragma unroll
    for (int j = 0; j < 4; j++) acc[i][j] = (floatx4){0.f, 0.f, 0.f, 0.f};

  const int nt = K >> 6;
#pragma unroll
  for (int r = 0; r < 4; r++) STAGE_A(0, 0, r);
#pragma unroll
  for (int r = 0; r < 2; r++) STAGE_B(0, 0, r);
#pragma unroll
  for (int r = 0; r < 4; r++) STAGE_A(1, 64, r);
#pragma unroll
  for (int r = 0; r < 2; r++) STAGE_B(1, 64, r);
  asm volatile("s_waitcnt vmcnt(6)" ::: "memory");
  SBAR();

  bf16x8 af0[4], bf0[4], af1[4], bf1[4];
  {
    const char* LA = lds + arow;
    const char* LB = lds + 32768 + brow;
#pragma unroll
    for (int i = 0; i < 4; i++) af0[i] = *(const bf16x8*)(LA + i * 2048 + ko0);
#pragma unroll
    for (int j = 0; j < 4; j++) bf0[j] = *(const bf16x8*)(LB + j * 2048 + ko0);
  }

  for (int t = 0; t < nt; t++) {
    const int buf = t % 3;
    const int pbuf = (t + 2) % 3;
    const long pk0 = (long)(t + 2) << 6;
    const char* LA = lds + buf * 49152 + arow;
    const char* LB = lds + buf * 49152 + 32768 + brow;
    const bool pf = (t + 2 < nt);

    if (pf) { STAGE_A(pbuf, pk0, 0); STAGE_A(pbuf, pk0, 1); STAGE_B(pbuf, pk0, 0); }
#pragma unroll
    for (int i = 0; i < 4; i++) af1[i] = *(const bf16x8*)(LA + i * 2048 + ko1);
#pragma unroll
    for (int j = 0; j < 4; j++) bf1[j] = *(const bf16x8*)(LB + j * 2048 + ko1);
    SCHED();
    __builtin_amdgcn_s_setprio(1);
#pragma unroll
    for (int i = 0; i < 4; i++)
#pragma unroll
      for (int j = 0; j < 4; j++) mfma16(acc[i][j], af0[i], bf0[j]);
    __builtin_amdgcn_s_setprio(0);
    SCHED();

    if (pf) { STAGE_A(pbuf, pk0, 2); STAGE_A(pbuf, pk0, 3); STAGE_B(pbuf, pk0, 1); }
    if (t < nt - 2) asm volatile("s_waitcnt vmcnt(6) lgkmcnt(0)" ::: "memory");
    else            asm volatile("s_waitcnt vmcnt(0) lgkmcnt(0)" ::: "memory");
    SBAR();
    if (t < nt - 1) {
      const char* LAn = lds + ((t + 1) % 3) * 49152 + arow;
      const char* LBn = lds + ((t + 1) % 3) * 49152 + 32768 + brow;
#pragma unroll
      for (int i = 0; i < 4; i++) af0[i] = *(const bf16x8*)(LAn + i * 2048 + ko0);
#pragma unroll
      for (int j = 0; j < 4; j++) bf0[j] = *(const bf16x8*)(LBn + j * 2048 + ko0);
    }
    SCHED();
    __builtin_amdgcn_s_setprio(1);
#pragma unroll
    for (int i = 0; i < 4; i++)
#pragma unroll
      for (int j = 0; j < 4; j++) mfma16(acc[i][j], af1[i], bf1[j]);
    __builtin_amdgcn_s_setprio(0);
    SCHED();
  }
#undef STAGE_A
#undef STAGE_B

  const long crow = bm + wm * 64 + ((l >> 4) * 4);
  const long ccol = bn + wn * 64 + (l & 15);
  if constexpr (OUTB == 0) {
    float* C = (float*)Cv + (long)blockIdx.z * sC;
#pragma unroll
    for (int i = 0; i < 4; i++)
#pragma unroll
      for (int r = 0; r < 4; r++) {
        long row = crow + i * 16 + r;
#pragma unroll
        for (int j = 0; j < 4; j++) C[row * (long)ldc + ccol + j * 16] = acc[i][j][r];
      }
  } else {
    uint16_t* C = (uint16_t*)Cv + (long)blockIdx.z * sC;
#pragma unroll
    for (int i = 0; i < 4; i++)
#pragma unroll
      for (int r = 0; r < 4; r++) {
        long row = crow + i * 16 + r;
#pragma unroll
        for (int j = 0; j < 4; j++) C[row * (long)ldc + ccol + j * 16] = f2bf(acc[i][j][r]);
      }
  }
}

// ================= legacy 128x128 GEMM (small weight-prep matmuls, split-K via z) =================
template<int OUTB>
__global__ void __launch_bounds__(256) gemm_bt(
    const uint16_t* __restrict__ A, const uint16_t* __restrict__ B,
    void* __restrict__ Cv, int K, int lda, int ldb, int ldc,
    long sA, long sB, long sC)
{
  __shared__ alignas(16) uint16_t As[4096];
  __shared__ alignas(16) uint16_t Bs[4096];
  const int tid = threadIdx.x;
  const int w = tid >> 6, l = tid & 63;
  const int wr = w >> 1, wc = w & 1;
  const long bm = (long)blockIdx.x * 128, bn = (long)blockIdx.y * 128;
  A += (long)blockIdx.z * sA;
  B += (long)blockIdx.z * sB;

  const uint16_t* ga0 = A + (bm + w * 16 + (l >> 2)) * (long)lda + (l & 3) * 8;
  const uint16_t* ga1 = ga0 + 64L * lda;
  const uint16_t* gb0 = B + (bn + w * 16 + (l >> 2)) * (long)ldb + (l & 3) * 8;
  const uint16_t* gb1 = gb0 + 64L * ldb;
  uint16_t* la0 = &As[w * 512];
  uint16_t* la1 = &As[2048 + w * 512];
  uint16_t* lb0 = &Bs[w * 512];
  uint16_t* lb1 = &Bs[2048 + w * 512];

  floatx4 acc[4][4];
#pragma unroll
  for (int i = 0; i < 4; i++)
#pragma unroll
    for (int j = 0; j < 4; j++) acc[i][j] = (floatx4){0.f, 0.f, 0.f, 0.f};

  const int rA = (wr * 64 + (l & 15)) * 32 + (l >> 4) * 8;
  const int rB = (wc * 64 + (l & 15)) * 32 + (l >> 4) * 8;

  for (int k0 = 0; k0 < K; k0 += 32) {
    __builtin_amdgcn_global_load_lds(ga0, la0, 16, 0, 0);
    __builtin_amdgcn_global_load_lds(ga1, la1, 16, 0, 0);
    __builtin_amdgcn_global_load_lds(gb0, lb0, 16, 0, 0);
    __builtin_amdgcn_global_load_lds(gb1, lb1, 16, 0, 0);
    ga0 += 32; ga1 += 32; gb0 += 32; gb1 += 32;
    __syncthreads();
    bf16x8 af[4], bfr[4];
#pragma unroll
    for (int i = 0; i < 4; i++) af[i] = *(const bf16x8*)&As[rA + i * 512];
#pragma unroll
    for (int j = 0; j < 4; j++) bfr[j] = *(const bf16x8*)&Bs[rB + j * 512];
#pragma unroll
    for (int i = 0; i < 4; i++)
#pragma unroll
      for (int j = 0; j < 4; j++) mfma16(acc[i][j], af[i], bfr[j]);
    __syncthreads();
  }

  const long crow = bm + wr * 64 + ((l >> 4) * 4);
  const long ccol = bn + wc * 64 + (l & 15);
  if constexpr (OUTB == 0) {
    float* C = (float*)Cv + (long)blockIdx.z * sC;
#pragma unroll
    for (int i = 0; i < 4; i++)
#pragma unroll
      for (int r = 0; r < 4; r++) {
        long row = crow + i * 16 + r;
#pragma unroll
        for (int j = 0; j < 4; j++) C[row * (long)ldc + ccol + j * 16] = acc[i][j][r];
      }
  } else {
    uint16_t* C = (uint16_t*)Cv + (long)blockIdx.z * sC;
#pragma unroll
    for (int i = 0; i < 4; i++)
#pragma unroll
      for (int r = 0; r < 4; r++) {
        long row = crow + i * 16 + r;
#pragma unroll
        for (int j = 0; j < 4; j++) C[row * (long)ldc + ccol + j * 16] = f2bf(acc[i][j][r]);
      }
  }
}

// ---------- split-K reduce: out_bf16[i] = sum_s in[s*stride + i] ----------
__global__ void __launch_bounds__(256) reduceK(const float* __restrict__ in,
                                               uint16_t* __restrict__ out,
                                               long n, int S, long stride) {
  long i = ((long)blockIdx.x * 256 + threadIdx.x) * 4;
  if (i >= n) return;
  float4 s = *(const float4*)(in + i);
  for (int k = 1; k < S; k++) {
    float4 t = *(const float4*)(in + k * stride + i);
    s.x += t.x; s.y += t.y; s.z += t.z; s.w += t.w;
  }
  ushort4 o; o.x = f2bf(s.x); o.y = f2bf(s.y); o.z = f2bf(s.z); o.w = f2bf(s.w);
  *(ushort4*)(out + i) = o;
}

// ---------- fused h convert + small-weight converts + rope table (one launch) ----------
__global__ void __launch_bounds__(256) prep_all(
    const float* __restrict__ h,
    const float* __restrict__ wdq, const float* __restrict__ wdkv,
    const float* __restrict__ wqr, const float* __restrict__ wkr,
    const float* __restrict__ wo,
    uint16_t* __restrict__ hb,
    uint16_t* __restrict__ wdq_b, uint16_t* __restrict__ wdkv_b,
    uint16_t* __restrict__ wqr_b, uint16_t* __restrict__ wkr_b,
    uint16_t* __restrict__ wo_b, float2* __restrict__ rtab)
{
  const int b = blockIdx.x;
  if (b < 27648) {
    const float* src; uint16_t* dst; long off;
    if (b < 16384)      { src = h;    dst = hb;     off = b; }
    else if (b < 17408) { src = wdq;  dst = wdq_b;  off = b - 16384; }
    else if (b < 18432) { src = wdkv; dst = wdkv_b; off = b - 17408; }
    else if (b < 19456) { src = wqr;  dst = wqr_b;  off = b - 18432; }
    else if (b < 23552) { src = wkr;  dst = wkr_b;  off = b - 19456; }
    else                { src = wo;   dst = wo_b;   off = b - 23552; }
    long i = (off * 256 + threadIdx.x) * 4;
    float4 v = *(const float4*)(src + i);
    ushort4 o; o.x = f2bf(v.x); o.y = f2bf(v.y); o.z = f2bf(v.z); o.w = f2bf(v.w);
    *(ushort4*)(dst + i) = o;
  } else {
    int idx = (b - 27648) * 256 + threadIdx.x;  // 2048*64
    int s = idx >> 6, fi = idx & 63;
    float f = powf(10000.0f, -(float)fi * (1.0f / 64.0f));
    float ang = (float)s * f;
    rtab[idx] = make_float2(cosf(ang), sinf(ang));
  }
}

// ---------- transpose (R,Cc) -> (Cc,R), bf16 out ----------
template<typename TIN>
__global__ void __launch_bounds__(256) transpose_to_bf16(
    const TIN* __restrict__ in, uint16_t* __restrict__ out,
    int ld_in, int ld_out, long sIn, long sOut)
{
  __shared__ float tile[32][33];
  in += (long)blockIdx.z * sIn;
  out += (long)blockIdx.z * sOut;
  const int rb = blockIdx.y * 32, cb = blockIdx.x * 32;
#pragma unroll
  for (int i = 0; i < 32; i += 8)
    tile[threadIdx.y + i][threadIdx.x] =
        ld_as_float(in[(long)(rb + threadIdx.y + i) * ld_in + cb + threadIdx.x]);
  __syncthreads();
#pragma unroll
  for (int i = 0; i < 32; i += 8)
    out[(long)(cb + threadIdx.y + i) * ld_out + rb + threadIdx.x] =
        f2bf(tile[threadIdx.x][threadIdx.y + i]);
}

// ---------- rmsnorm: one block per row; DIM = PT*256 ----------
template<int PT, typename TIN>
__global__ void __launch_bounds__(256) rmsnorm_k(
    const TIN* __restrict__ in, const float* __restrict__ g,
    float* __restrict__ out_f, uint16_t* __restrict__ out_b, int ld_b)
{
  constexpr int DIM = PT * 256;
  __shared__ float sm[9];
  const TIN* x = in + (long)blockIdx.x * DIM;
  const int base = threadIdx.x * PT;
  float v[PT];
  if constexpr (sizeof(TIN) == 2) {
    if constexpr (PT >= 8) {
#pragma unroll
      for (int i = 0; i < PT; i += 8) {
        u16x8 t = *(const u16x8*)&x[base + i];
#pragma unroll
        for (int q = 0; q < 8; q++) v[i + q] = bf2f(t[q]);
      }
    } else {
#pragma unroll
      for (int i = 0; i < PT; i += 2) {
        ushort2 t = *(const ushort2*)&x[base + i];
        v[i] = bf2f(t.x); v[i + 1] = bf2f(t.y);
      }
    }
  } else if constexpr (PT == 2) {
    float2 t = *(const float2*)&x[base]; v[0] = t.x; v[1] = t.y;
  } else {
#pragma unroll
    for (int i = 0; i < PT; i += 4) {
      float4 t = *(const float4*)&x[base + i];
      v[i] = t.x; v[i + 1] = t.y; v[i + 2] = t.z; v[i + 3] = t.w;
    }
  }
  float ss = 0.f;
#pragma unroll
  for (int i = 0; i < PT; i++) ss += v[i] * v[i];
#pragma unroll
  for (int o = 32; o; o >>= 1) ss += __shfl_down(ss, o);
  if ((threadIdx.x & 63) == 0) sm[threadIdx.x >> 6] = ss;
  __syncthreads();
  if (threadIdx.x == 0)
    sm[8] = rsqrtf((sm[0] + sm[1] + sm[2] + sm[3]) * (1.0f / DIM) + 1.1920929e-7f);
  __syncthreads();
  const float sc = sm[8];
#pragma unroll
  for (int i = 0; i < PT; i++) {
    float y = v[i] * sc * g[base + i];
    if (out_f) out_f[(long)blockIdx.x * DIM + base + i] = y;
    if (out_b) out_b[(long)blockIdx.x * ld_b + base + i] = f2bf(y);
  }
}

// ---------- rope apply: in bf16 (8192,2048); bf16 out -> cat[:,512:]; optional fp32 out ----------
template<bool WF32>
__global__ void __launch_bounds__(256) rope_k(
    const uint16_t* __restrict__ in, uint16_t* __restrict__ outb,
    float* __restrict__ outf, const float2* __restrict__ tab)
{
  long idx = (long)blockIdx.x * 256 + threadIdx.x;  // 8192*1024 pairs
  int r = (int)(idx >> 10);
  int pp = (int)idx & 1023;
  int s = r & 2047;
  int fi = pp & 63;
  ushort2 xv = *(const ushort2*)(in + ((long)r << 11) + 2 * pp);
  float x0 = bf2f(xv.x), x1 = bf2f(xv.y);
  float2 cs = tab[(s << 6) + fi];
  float y0 = x0 * cs.x - x1 * cs.y;
  float y1 = x0 * cs.y + x1 * cs.x;
  ushort2 ov; ov.x = f2bf(y0); ov.y = f2bf(y1);
  *(ushort2*)(outb + (long)r * 2560 + 512 + 2 * pp) = ov;
  if (WF32) *(float2*)(outf + ((long)r << 11) + 2 * pp) = make_float2(y0, y1);
}

// ---------- softmax over rows of 2048, bf16 in (pre-scaled), bf16 out ----------
__global__ void __launch_bounds__(256) softmax_k(const uint16_t* __restrict__ sc,
                                                 uint16_t* __restrict__ attn) {
  __shared__ float sm[9];
  const uint16_t* x = sc + ((long)blockIdx.x << 11);
  const int base = threadIdx.x * 8;
  float v[8];
  u16x8 t = *(const u16x8*)&x[base];
#pragma unroll
  for (int i = 0; i < 8; i++) v[i] = bf2f(t[i]);
  float m = -1e30f;
#pragma unroll
  for (int i = 0; i < 8; i++) m = fmaxf(m, v[i]);
#pragma unroll
  for (int o = 32; o; o >>= 1) m = fmaxf(m, __shfl_down(m, o));
  if ((threadIdx.x & 63) == 0) sm[threadIdx.x >> 6] = m;
  __syncthreads();
  if (threadIdx.x == 0)
    sm[8] = fmaxf(fmaxf(sm[0], sm[1]), fmaxf(sm[2], sm[3]));
  __syncthreads();
  m = sm[8];
  __syncthreads();
  float ss = 0.f;
#pragma unroll
  for (int i = 0; i < 8; i++) { v[i] = __expf(v[i] - m); ss += v[i]; }
#pragma unroll
  for (int o = 32; o; o >>= 1) ss += __shfl_down(ss, o);
  if ((threadIdx.x & 63) == 0) sm[threadIdx.x >> 6] = ss;
  __syncthreads();
  if (threadIdx.x == 0) sm[8] = 1.0f / (sm[0] + sm[1] + sm[2] + sm[3]);
  __syncthreads();
  const float r = sm[8];
  ushort4 o1, o2;
  o1.x = f2bf(v[0] * r); o1.y = f2bf(v[1] * r); o1.z = f2bf(v[2] * r); o1.w = f2bf(v[3] * r);
  o2.x = f2bf(v[4] * r); o2.y = f2bf(v[5] * r); o2.z = f2bf(v[6] * r); o2.w = f2bf(v[7] * r);
  uint16_t* dst = attn + ((long)blockIdx.x << 11) + base;
  *(ushort4*)dst = o1;
  *(ushort4*)(dst + 4) = o2;
}

// ---------- orchestration ----------
extern "C" void kernel_launch(void* const* d_in, const int* in_sizes, int n_in,
                              void* d_out, int out_size, void* d_ws, size_t ws_size,
                              hipStream_t stream) {
  (void)in_sizes; (void)n_in; (void)out_size; (void)ws_size;
  const float* h    = (const float*)d_in[0];
  const float* wdkv = (const float*)d_in[1];
  const float* wuk  = (const float*)d_in[2];
  const float* wuv  = (const float*)d_in[3];
  const float* wdq  = (const float*)d_in[4];
  const float* wuq  = (const float*)d_in[5];
  const float* wkr  = (const float*)d_in[6];
  const float* wqr  = (const float*)d_in[7];
  const float* wo   = (const float*)d_in[8];
  const float* g1   = (const float*)d_in[9];
  const float* g2   = (const float*)d_in[10];
  const float* g3   = (const float*)d_in[11];

  float* u_out   = (float*)d_out;                 // (4,2048,2048)
  float* ckv_out = u_out + 16777216L;             // (4,2048,512)
  float* kr_out  = ckv_out + 4194304L;            // (4,2048,2048)

  char* p = (char*)d_ws;
  auto alloc = [&](size_t bytes) -> void* {
    void* q = (void*)p; p += (bytes + 255) & ~(size_t)255; return q;
  };
  uint16_t* hb     = (uint16_t*)alloc(16777216ULL * 2);  // h bf16
  uint16_t* wcat   = (uint16_t*)alloc(3145728ULL * 2);   // (1536,2048) [wdq;wdkv;Bqt]
  uint16_t* wqr_b  = (uint16_t*)alloc(1048576ULL * 2);
  uint16_t* wkr_b  = (uint16_t*)alloc(4194304ULL * 2);
  uint16_t* wo_b   = (uint16_t*)alloc(4194304ULL * 2);
  uint16_t* wukT   = (uint16_t*)alloc(1048576ULL * 2);   // (512,2048)
  uint16_t* wuqT   = (uint16_t*)alloc(1048576ULL * 2);
  uint16_t* wuvT   = (uint16_t*)alloc(1048576ULL * 2);
  uint16_t* wdqT   = (uint16_t*)alloc(1048576ULL * 2);   // (2048,512)
  uint16_t* T1t    = (uint16_t*)alloc(262144ULL * 2);    // (512,512)
  uint16_t* awoT   = (uint16_t*)alloc(1048576ULL * 2);   // absorbed_w_o^T (2048,512)
  uint16_t* cqpre  = (uint16_t*)alloc(4194304ULL * 2);   // (8192,512) bf16 cq-pre
  uint16_t* cq_b   = (uint16_t*)alloc(4194304ULL * 2);   // (8192,512)
  uint16_t* catq   = (uint16_t*)alloc(20971520ULL * 2);  // (8192,2560) [aq|qr]
  uint16_t* catk   = (uint16_t*)alloc(20971520ULL * 2);  // (8192,2560) [ckv|kr]
  uint16_t* ckvT   = (uint16_t*)alloc(4194304ULL * 2);   // 4 x (512,2048)
  uint16_t* o_b    = (uint16_t*)alloc(4194304ULL * 2);   // (8192,512)
  float2*   rtab   = (float2*)alloc(131072ULL * 8);      // 2048x64 (cos,sin)
  float*    tmpS2  = (float*)alloc(4194304ULL * 4);      // (8192,512) fp32 ckv-pre
  float*    tmpB   = (float*)alloc(16777216ULL * 4);     // (8192,2048) scratch
  float*    redT   = (float*)alloc(1048576ULL * 4);      // 4 x (512,512) partials
  float*    redW   = (float*)alloc(4194304ULL * 4);      // 4 x (2048,512) partials
  uint16_t* tmpBb  = (uint16_t*)tmpB;                    // alias: (8192,2048) bf16
  uint16_t* attn   = catq;  // alias: catq dead after scores GEMM

  uint16_t* wdq_b  = wcat;                  // rows 0-511
  uint16_t* wdkv_b = wcat + 1048576;        // rows 512-1023
  uint16_t* Bqt    = wcat + 2097152;        // rows 1024-1535 (absorbed_w_q^T)

  const dim3 b256(256);
  const dim3 b512(512);
  const dim3 tb(32, 8);

  // fused h convert + small-weight converts + rope table
  prep_all<<<dim3(28160), b256, 0, stream>>>(
      h, wdq, wdkv, wqr, wkr, wo, hb, wdq_b, wdkv_b, wqr_b, wkr_b, wo_b, rtab);
  // weight transposes (fp32 -> bf16)
  transpose_to_bf16<float><<<dim3(16, 64, 1), tb, 0, stream>>>(wuk, wukT, 512, 2048, 0, 0);
  transpose_to_bf16<float><<<dim3(16, 64, 1), tb, 0, stream>>>(wuq, wuqT, 512, 2048, 0, 0);
  transpose_to_bf16<float><<<dim3(16, 64, 1), tb, 0, stream>>>(wuv, wuvT, 512, 2048, 0, 0);
  transpose_to_bf16<float><<<dim3(64, 16, 1), tb, 0, stream>>>(wdq, wdqT, 2048, 512, 0, 0);

  // absorbed weights — split-K (z=4, Kc=512) + deterministic reduce
  gemm_bt<0><<<dim3(4, 4, 4), b256, 0, stream>>>(
      wukT, wuqT, redT, 512, 2048, 2048, 512, 512L, 512L, 262144L);
  reduceK<<<dim3(256), b256, 0, stream>>>(redT, T1t, 262144L, 4, 262144L);
  gemm_bt<0><<<dim3(16, 4, 4), b256, 0, stream>>>(
      wo_b, wuvT, redW, 512, 2048, 2048, 512, 512L, 512L, 1048576L);
  reduceK<<<dim3(1024), b256, 0, stream>>>(redW, awoT, 1048576L, 4, 1048576L);
  gemm_bt<1><<<dim3(4, 16, 1), b256, 0, stream>>>(T1t, wdqT, Bqt, 512, 512, 512, 2048, 0, 0, 0);

  // fused: [cq-pre(bf16) | ckv-pre(fp32) | aq(bf16)] = h @ [wdq; wdkv; Bqt]^T
  gemm256v3<2><<<dim3(32, 6, 1), b512, 0, stream>>>(
      hb, wcat, cqpre, tmpS2, catq, 2048, 2048, 2048, 0, 0, 0, 0, 2);
  // cq = rmsnorm(cq-pre, g1)
  rmsnorm_k<2, uint16_t><<<dim3(8192), b256, 0, stream>>>(cqpre, g1, nullptr, cq_b, 512);
  // qr = rope(cq @ wqr^T) -> catq[:,512:]
  gemm256v3<1><<<dim3(32, 8, 1), b512, 0, stream>>>(
      cq_b, wqr_b, tmpBb, nullptr, nullptr, 512, 512, 512, 2048, 0, 0, 0, 4);
  rope_k<false><<<dim3(32768), b256, 0, stream>>>(tmpBb, catq, nullptr, rtab);
  // ckv = rmsnorm(ckv-pre, g2) -> ckv_out (fp32) + catk[:,0:512] (bf16)
  rmsnorm_k<2, float><<<dim3(8192), b256, 0, stream>>>(tmpS2, g2, ckv_out, catk, 2560);
  // ckvT: 4 x (512,2048) from catk cols 0..511
  transpose_to_bf16<uint16_t><<<dim3(16, 64, 4), tb, 0, stream>>>(
      catk, ckvT, 2560, 2048, 2048L * 2560, 512L * 2048);
  // kr = rope(h @ wkr^T) -> kr_out (fp32) + catk[:,512:]
  gemm256v3<1><<<dim3(32, 8, 1), b512, 0, stream>>>(
      hb, wkr_b, tmpBb, nullptr, nullptr, 2048, 2048, 2048, 2048, 0, 0, 0, 4);
  rope_k<true><<<dim3(32768), b256, 0, stream>>>(tmpBb, catk, kr_out, rtab);
  // scores[b]/12 = (catq_b @ catk_b^T)/12 -> tmpBb bf16 (K=2560)
  gemm256v3<3><<<dim3(8, 8, 4), b512, 0, stream>>>(
      catq, catk, tmpBb, nullptr, nullptr, 2560, 2560, 2560, 2048,
      5242880L, 5242880L, 4194304L, 2);
  // softmax -> attn bf16 (aliases catq)
  softmax_k<<<dim3(8192), b256, 0, stream>>>(tmpBb, attn);
  // o[b] = attn_b @ ckv_b (via ckvT) -> o_b bf16
  gemm256<1><<<dim3(8, 4, 4), b512, 0, stream>>>(
      attn, ckvT, o_b, 2048, 2048, 2048, 512, 4194304L, 1048576L, 1048576L);
  // u = rmsnorm(o @ absorbed_w_o, g3) -> u_out
  gemm256v3<1><<<dim3(32, 8, 1), b512, 0, stream>>>(
      o_b, awoT, tmpBb, nullptr, nullptr, 512, 512, 512, 2048, 0, 0, 0, 4);
  rmsnorm_k<8, uint16_t><<<dim3(8192), b256, 0, stream>>>(tmpBb, g3, u_out, nullptr, 0);
}

// Round 12
// 472.245 us; speedup vs baseline: 1.1901x; 1.0458x over previous
//
#include <hip/hip_runtime.h>
#include <stdint.h>

// ---------- small helpers ----------
typedef __attribute__((ext_vector_type(8))) short bf16x8;
typedef __attribute__((ext_vector_type(8))) unsigned short u16x8;
typedef __attribute__((ext_vector_type(4))) float floatx4;

__device__ __forceinline__ uint16_t f2bf(float f) {
  union { float f; uint32_t u; } v; v.f = f;
  uint32_t r = v.u + 0x7fffu + ((v.u >> 16) & 1u);
  return (uint16_t)(r >> 16);
}
__device__ __forceinline__ float bf2f(uint16_t b) {
  union { uint32_t u; float f; } v; v.u = ((uint32_t)b) << 16;
  return v.f;
}
__device__ __forceinline__ float ld_as_float(float v) { return v; }
__device__ __forceinline__ float ld_as_float(uint16_t v) { return bf2f(v); }

__device__ __forceinline__ void mfma16(floatx4& d, bf16x8 a, bf16x8 b) {
  asm("v_mfma_f32_16x16x32_bf16 %0, %1, %2, %0" : "+v"(d) : "v"(a), "v"(b));
}

#define FENCE() asm volatile("" ::: "memory")
#define SCHED() __builtin_amdgcn_sched_barrier(0)
#define SBAR()                                  \
  do {                                          \
    FENCE();                                    \
    __builtin_amdgcn_sched_barrier(0);          \
    __builtin_amdgcn_s_barrier();               \
    __builtin_amdgcn_sched_barrier(0);          \
    FENCE();                                    \
  } while (0)

// ================= v5 GEMM: 256x256, BK=32, 4-slot ring, cross-tile reg prefetch =================
// C(M,N) = A(M,K) @ B(N,K)^T, bf16 in, fp32 acc. Requires K % 32 == 0, K >= 128.
// 512 threads = 8 waves (2M x 4N), per-wave 128x64 output (8x4 frags).
// LDS: 4 slots x (A 16KB + B 16KB) = 128 KB. Tile t in slot t%4, staging depth 3.
// Schedule (r11): every MFMA cluster consumes registers read >=1 phase earlier.
//   ph1: read Af1(t) | stage(t+3) A,A | lgkmcnt(4) | 16 MFMA (Af0xBf)
//   mid: vmcnt(6|4|0 tail) + lgkmcnt(0) + barrier   [t+1 staging visible]
//   ph2: read Bfn,Af0(t+1) | stage(t+3) B,B | 16 MFMA (Af1xBf) | Bf=Bfn
// Chunk-XOR swizzle (both sides, same involution; r7-verified conflicts=0).
// XCD mapping: 1D 8-way swizzle + swzG 2D supertile shaping (r10: -33% FETCH).
// MODE 0: fp32 C0; 1: bf16 C0; 2: routed (cols 0-511 bf16 C0 ld512 cq-pre,
//   512-1023 fp32 C1 ld512 ckv-pre, 1024-1535 bf16 C2 ld2560 aq);
// 3: bf16 C0 with fused *(1/12) scale;
// 4: RoPE epilogue -> bf16 C0[row*2560 + 512 + c]         (C1v = rope table)
// 5: RoPE epilogue -> bf16 C0[row*2560 + 512 + c] AND fp32 C2v[row*2048 + c].
//    Rope pair partner col c^1 lives in lane l^1 (crow has no bit-0 dep;
//    ccol = bn + wn*64 + (l&15)), so p = shfl_xor(v,1);
//    y = v*cos + sgn*p*sin, sgn = (l&1) ? +1 : -1;  fi = (c&127)>>1, s = row&2047.
template<int MODE>
__global__ void __launch_bounds__(512, 1) gemm256v3(
    const uint16_t* __restrict__ A, const uint16_t* __restrict__ B,
    void* __restrict__ C0v, void* __restrict__ C1v, void* __restrict__ C2v,
    int K, int lda, int ldb, int ldc,
    long sA, long sB, long sC, int swzG)
{
  __shared__ __attribute__((aligned(16))) char lds[131072];
  const int tid = threadIdx.x;
  const int w = tid >> 6, l = tid & 63;
  const int wm = w >> 2, wn = w & 3;

  // XCD-aware swizzle + 2D supertile shaping
  const int gx = gridDim.x;
  const int nwg = gx * gridDim.y;
  int id = blockIdx.y * gx + blockIdx.x;
  if ((nwg & 7) == 0) id = (id & 7) * (nwg >> 3) + (id >> 3);
  const int grp = gx * swzG;
  const int ing = id % grp;
  const long bm = (long)(ing / swzG) * 256;
  const long bn = ((long)(id / grp) * swzG + (ing % swzG)) * 256;
  A += (long)blockIdx.z * sA;
  B += (long)blockIdx.z * sB;

  // staging: one global_load_lds covers 128 rows x 64B (8 waves x 16 rows).
  const int scol = (((l & 3) ^ ((l >> 3) & 3)) << 3);  // pre-swizzled source chunk
  const uint16_t* gA = A + (bm + w * 16 + (l >> 2)) * (long)lda + scol;
  const uint16_t* gB = B + (bn + w * 16 + (l >> 2)) * (long)ldb + scol;
  const int ldsw = w * 1024;

#define STG_A3(slot, k0, r)                                                    \
  __builtin_amdgcn_global_load_lds(gA + (k0) + (long)(r) * 128 * lda,          \
      (uint16_t*)(lds + (slot) * 32768 + (r) * 8192 + ldsw), 16, 0, 0)
#define STG_B3(slot, k0, r)                                                    \
  __builtin_amdgcn_global_load_lds(gB + (k0) + (long)(r) * 128 * ldb,          \
      (uint16_t*)(lds + (slot) * 32768 + 16384 + (r) * 8192 + ldsw), 16, 0, 0)

  // fragment read geometry: row stride 64B; lane reads 16B at swizzled chunk
  const int lr = l & 15;
  const int chunkx = (((l >> 4) ^ ((lr >> 1) & 3)) << 4);  // bytes
  const int aoff = (wm * 128 + lr) * 64 + chunkx;
  const int boff = 16384 + (wn * 64 + lr) * 64 + chunkx;

  floatx4 acc[8][4];
#pragma unroll
  for (int i = 0; i < 8; i++)
#pragma unroll
    for (int j = 0; j < 4; j++) acc[i][j] = (floatx4){0.f, 0.f, 0.f, 0.f};

  const int nt = K >> 5;  // assumes nt >= 4
#pragma unroll
  for (int tt = 0; tt < 3; tt++) {
    STG_A3(tt, tt * 32, 0); STG_A3(tt, tt * 32, 1);
    STG_B3(tt, tt * 32, 0); STG_B3(tt, tt * 32, 1);
  }
  asm volatile("s_waitcnt vmcnt(8)" ::: "memory");  // tile 0 landed
  SBAR();

  bf16x8 Bf[4], Bfn[4], Af0[4], Af1[4];
#pragma unroll
  for (int j = 0; j < 4; j++) Bf[j] = *(const bf16x8*)(lds + boff + j * 1024);
#pragma unroll
  for (int i = 0; i < 4; i++) Af0[i] = *(const bf16x8*)(lds + aoff + i * 1024);

  for (int t = 0; t < nt; t++) {
    const char* Ls = lds + (t & 3) * 32768;
    const char* Ln = lds + ((t + 1) & 3) * 32768;
    const long pk0 = (long)(t + 3) << 5;
    const int pslot = (t + 3) & 3;
    const bool pf = (t + 3 < nt);

    // ---- phase 1: read Af1(t), stage (t+3) A, MFMA on Af0(t) x Bf(t) ----
#pragma unroll
    for (int i = 0; i < 4; i++) Af1[i] = *(const bf16x8*)(Ls + aoff + (4 + i) * 1024);
    SCHED();
    if (pf) { STG_A3(pslot, pk0, 0); STG_A3(pslot, pk0, 1); }
    asm volatile("s_waitcnt lgkmcnt(4)" ::: "memory");  // Bf+Af0 landed; Af1 in flight
    SCHED();
    __builtin_amdgcn_s_setprio(1);
#pragma unroll
    for (int i = 0; i < 4; i++)
#pragma unroll
      for (int j = 0; j < 4; j++) mfma16(acc[i][j], Af0[i], Bf[j]);
    __builtin_amdgcn_s_setprio(0);
    SCHED();

    // ---- mid: retire t+1 staging (counted), drain Af1 reads, fence ----
    if (t + 3 < nt)      asm volatile("s_waitcnt vmcnt(6)" ::: "memory");
    else if (t + 2 < nt) asm volatile("s_waitcnt vmcnt(4)" ::: "memory");
    else if (t + 1 < nt) asm volatile("s_waitcnt vmcnt(0)" ::: "memory");
    asm volatile("s_waitcnt lgkmcnt(0)" ::: "memory");
    SBAR();

    // ---- phase 2: read Bf/Af0 of t+1 (overlaps MFMA), stage (t+3) B, MFMA Af1 x Bf ----
    if (t + 1 < nt) {
#pragma unroll
      for (int j = 0; j < 4; j++) Bfn[j] = *(const bf16x8*)(Ln + boff + j * 1024);
#pragma unroll
      for (int i = 0; i < 4; i++) Af0[i] = *(const bf16x8*)(Ln + aoff + i * 1024);
    }
    SCHED();
    if (pf) { STG_B3(pslot, pk0, 0); STG_B3(pslot, pk0, 1); }
    SCHED();
    __builtin_amdgcn_s_setprio(1);
#pragma unroll
    for (int i = 0; i < 4; i++)
#pragma unroll
      for (int j = 0; j < 4; j++) mfma16(acc[4 + i][j], Af1[i], Bf[j]);
    __builtin_amdgcn_s_setprio(0);
    SCHED();
#pragma unroll
    for (int j = 0; j < 4; j++) Bf[j] = Bfn[j];
  }
#undef STG_A3
#undef STG_B3

  const long crow = bm + wm * 128 + ((l >> 4) * 4);
  const long ccol = bn + wn * 64 + (l & 15);
  if constexpr (MODE == 0) {
    float* C = (float*)C0v + (long)blockIdx.z * sC;
#pragma unroll
    for (int i = 0; i < 8; i++)
#pragma unroll
      for (int r = 0; r < 4; r++) {
        long row = crow + i * 16 + r;
#pragma unroll
        for (int j = 0; j < 4; j++) C[row * (long)ldc + ccol + j * 16] = acc[i][j][r];
      }
  } else if constexpr (MODE == 1) {
    uint16_t* C = (uint16_t*)C0v + (long)blockIdx.z * sC;
#pragma unroll
    for (int i = 0; i < 8; i++)
#pragma unroll
      for (int r = 0; r < 4; r++) {
        long row = crow + i * 16 + r;
#pragma unroll
        for (int j = 0; j < 4; j++) C[row * (long)ldc + ccol + j * 16] = f2bf(acc[i][j][r]);
      }
  } else if constexpr (MODE == 3) {
    const float s = 1.0f / 12.0f;
    uint16_t* C = (uint16_t*)C0v + (long)blockIdx.z * sC;
#pragma unroll
    for (int i = 0; i < 8; i++)
#pragma unroll
      for (int r = 0; r < 4; r++) {
        long row = crow + i * 16 + r;
#pragma unroll
        for (int j = 0; j < 4; j++) C[row * (long)ldc + ccol + j * 16] = f2bf(acc[i][j][r] * s);
      }
  } else if constexpr (MODE == 4 || MODE == 5) {
    // RoPE epilogue: C0 bf16 cat at col 512+c (ld 2560); MODE 5 also fp32 C2 (ld 2048).
    const float2* __restrict__ tab = (const float2*)C1v;
    uint16_t* Cb = (uint16_t*)C0v;
    float* Cf = (float*)C2v;
    const float sgn = (l & 1) ? 1.0f : -1.0f;
#pragma unroll
    for (int i = 0; i < 8; i++)
#pragma unroll
      for (int r = 0; r < 4; r++) {
        long row = crow + i * 16 + r;
        const float2* trow = tab + (((int)(row & 2047)) << 6);
#pragma unroll
        for (int j = 0; j < 4; j++) {
          long c = ccol + j * 16;
          float v = acc[i][j][r];
          float pp = __shfl_xor(v, 1);
          float2 cs = trow[((int)(c & 127)) >> 1];
          float y = v * cs.x + sgn * pp * cs.y;
          Cb[row * 2560 + 512 + c] = f2bf(y);
          if constexpr (MODE == 5) Cf[row * 2048 + c] = y;
        }
      }
  } else {
    if (bn < 512) {
      uint16_t* C = (uint16_t*)C0v;
#pragma unroll
      for (int i = 0; i < 8; i++)
#pragma unroll
        for (int r = 0; r < 4; r++) {
          long row = crow + i * 16 + r;
#pragma unroll
          for (int j = 0; j < 4; j++) C[row * 512 + ccol + j * 16] = f2bf(acc[i][j][r]);
        }
    } else if (bn < 1024) {
      float* C = (float*)C1v;
      const long cc = ccol - 512;
#pragma unroll
      for (int i = 0; i < 8; i++)
#pragma unroll
        for (int r = 0; r < 4; r++) {
          long row = crow + i * 16 + r;
#pragma unroll
          for (int j = 0; j < 4; j++) C[row * 512 + cc + j * 16] = acc[i][j][r];
        }
    } else {
      uint16_t* C = (uint16_t*)C2v;
      const long cc = ccol - 1024;
#pragma unroll
      for (int i = 0; i < 8; i++)
#pragma unroll
        for (int r = 0; r < 4; r++) {
          long row = crow + i * 16 + r;
#pragma unroll
          for (int j = 0; j < 4; j++) C[row * 2560 + cc + j * 16] = f2bf(acc[i][j][r]);
        }
    }
  }
}

// ================= 256x128 pipelined GEMM (for the small-N o GEMM) =================
template<int OUTB>
__global__ void __launch_bounds__(512, 2) gemm256(
    const uint16_t* __restrict__ A, const uint16_t* __restrict__ B,
    void* __restrict__ Cv, int K, int lda, int ldb, int ldc,
    long sA, long sB, long sC)
{
  __shared__ __attribute__((aligned(16))) char lds[147456];
  const int tid = threadIdx.x;
  const int w = tid >> 6, l = tid & 63;
  const int wm = w >> 1, wn = w & 1;

  const int gx = gridDim.x;
  const int nwg = gx * gridDim.y;
  int id = blockIdx.y * gx + blockIdx.x;
  if ((nwg & 7) == 0) id = (id & 7) * (nwg >> 3) + (id >> 3);
  const long bm = (long)(id % gx) * 256;
  const long bn = (long)(id / gx) * 128;
  A += (long)blockIdx.z * sA;
  B += (long)blockIdx.z * sB;

  const int sr = l >> 3;
  const int sc = l & 7;
  const int scol = ((sc ^ sr) << 3);
  const uint16_t* gA = A + (bm + w * 8 + sr) * (long)lda + scol;
  const uint16_t* gB = B + (bn + w * 8 + sr) * (long)ldb + scol;
  const int ldsw = w * 1024;

#define STAGE_A(bufi, k0, r)                                                     \
  __builtin_amdgcn_global_load_lds(gA + (k0) + (long)(r) * 64 * lda,             \
      (uint16_t*)(lds + (bufi) * 49152 + (r) * 8192 + ldsw), 16, 0, 0)
#define STAGE_B(bufi, k0, r)                                                     \
  __builtin_amdgcn_global_load_lds(gB + (k0) + (long)(r) * 64 * ldb,             \
      (uint16_t*)(lds + (bufi) * 49152 + 32768 + (r) * 8192 + ldsw), 16, 0, 0)

  const int lr = l & 15;
  const int kk = (l >> 4) << 4;
  const int msk = (l & 7) << 4;
  const int ko0 = kk ^ msk;
  const int ko1 = (64 + kk) ^ msk;
  const int arow = (wm * 64 + lr) * 128;
  const int brow = (wn * 64 + lr) * 128;

  floatx4 acc[4][4];
#pragma unroll
  for (int i = 0; i < 4; i++)
#pragma unroll
    for (int j = 0; j < 4; j++) acc[i][j] = (floatx4){0.f, 0.f, 0.f, 0.f};

  const int nt = K >> 6;
#pragma unroll
  for (int r = 0; r < 4; r++) STAGE_A(0, 0, r);
#pragma unroll
  for (int r = 0; r < 2; r++) STAGE_B(0, 0, r);
#pragma unroll
  for (int r = 0; r < 4; r++) STAGE_A(1, 64, r);
#pragma unroll
  for (int r = 0; r < 2; r++) STAGE_B(1, 64, r);
  asm volatile("s_waitcnt vmcnt(6)" ::: "memory");
  SBAR();

  bf16x8 af0[4], bf0[4], af1[4], bf1[4];
  {
    const char* LA = lds + arow;
    const char* LB = lds + 32768 + brow;
#pragma unroll
    for (int i = 0; i < 4; i++) af0[i] = *(const bf16x8*)(LA + i * 2048 + ko0);
#pragma unroll
    for (int j = 0; j < 4; j++) bf0[j] = *(const bf16x8*)(LB + j * 2048 + ko0);
  }

  for (int t = 0; t < nt; t++) {
    const int buf = t % 3;
    const int pbuf = (t + 2) % 3;
    const long pk0 = (long)(t + 2) << 6;
    const char* LA = lds + buf * 49152 + arow;
    const char* LB = lds + buf * 49152 + 32768 + brow;
    const bool pf = (t + 2 < nt);

    if (pf) { STAGE_A(pbuf, pk0, 0); STAGE_A(pbuf, pk0, 1); STAGE_B(pbuf, pk0, 0); }
#pragma unroll
    for (int i = 0; i < 4; i++) af1[i] = *(const bf16x8*)(LA + i * 2048 + ko1);
#pragma unroll
    for (int j = 0; j < 4; j++) bf1[j] = *(const bf16x8*)(LB + j * 2048 + ko1);
    SCHED();
    __builtin_amdgcn_s_setprio(1);
#pragma unroll
    for (int i = 0; i < 4; i++)
#pragma unroll
      for (int j = 0; j < 4; j++) mfma16(acc[i][j], af0[i], bf0[j]);
    __builtin_amdgcn_s_setprio(0);
    SCHED();

    if (pf) { STAGE_A(pbuf, pk0, 2); STAGE_A(pbuf, pk0, 3); STAGE_B(pbuf, pk0, 1); }
    if (t < nt - 2) asm volatile("s_waitcnt vmcnt(6) lgkmcnt(0)" ::: "memory");
    else            asm volatile("s_waitcnt vmcnt(0) lgkmcnt(0)" ::: "memory");
    SBAR();
    if (t < nt - 1) {
      const char* LAn = lds + ((t + 1) % 3) * 49152 + arow;
      const char* LBn = lds + ((t + 1) % 3) * 49152 + 32768 + brow;
#pragma unroll
      for (int i = 0; i < 4; i++) af0[i] = *(const bf16x8*)(LAn + i * 2048 + ko0);
#pragma unroll
      for (int j = 0; j < 4; j++) bf0[j] = *(const bf16x8*)(LBn + j * 2048 + ko0);
    }
    SCHED();
    __builtin_amdgcn_s_setprio(1);
#pragma unroll
    for (int i = 0; i < 4; i++)
#pragma unroll
      for (int j = 0; j < 4; j++) mfma16(acc[i][j], af1[i], bf1[j]);
    __builtin_amdgcn_s_setprio(0);
    SCHED();
  }
#undef STAGE_A
#undef STAGE_B

  const long crow = bm + wm * 64 + ((l >> 4) * 4);
  const long ccol = bn + wn * 64 + (l & 15);
  if constexpr (OUTB == 0) {
    float* C = (float*)Cv + (long)blockIdx.z * sC;
#pragma unroll
    for (int i = 0; i < 4; i++)
#pragma unroll
      for (int r = 0; r < 4; r++) {
        long row = crow + i * 16 + r;
#pragma unroll
        for (int j = 0; j < 4; j++) C[row * (long)ldc + ccol + j * 16] = acc[i][j][r];
      }
  } else {
    uint16_t* C = (uint16_t*)Cv + (long)blockIdx.z * sC;
#pragma unroll
    for (int i = 0; i < 4; i++)
#pragma unroll
      for (int r = 0; r < 4; r++) {
        long row = crow + i * 16 + r;
#pragma unroll
        for (int j = 0; j < 4; j++) C[row * (long)ldc + ccol + j * 16] = f2bf(acc[i][j][r]);
      }
  }
}

// ================= legacy 128x128 GEMM (small weight-prep matmuls, split-K via z) =================
template<int OUTB>
__global__ void __launch_bounds__(256) gemm_bt(
    const uint16_t* __restrict__ A, const uint16_t* __restrict__ B,
    void* __restrict__ Cv, int K, int lda, int ldb, int ldc,
    long sA, long sB, long sC)
{
  __shared__ alignas(16) uint16_t As[4096];
  __shared__ alignas(16) uint16_t Bs[4096];
  const int tid = threadIdx.x;
  const int w = tid >> 6, l = tid & 63;
  const int wr = w >> 1, wc = w & 1;
  const long bm = (long)blockIdx.x * 128, bn = (long)blockIdx.y * 128;
  A += (long)blockIdx.z * sA;
  B += (long)blockIdx.z * sB;

  const uint16_t* ga0 = A + (bm + w * 16 + (l >> 2)) * (long)lda + (l & 3) * 8;
  const uint16_t* ga1 = ga0 + 64L * lda;
  const uint16_t* gb0 = B + (bn + w * 16 + (l >> 2)) * (long)ldb + (l & 3) * 8;
  const uint16_t* gb1 = gb0 + 64L * ldb;
  uint16_t* la0 = &As[w * 512];
  uint16_t* la1 = &As[2048 + w * 512];
  uint16_t* lb0 = &Bs[w * 512];
  uint16_t* lb1 = &Bs[2048 + w * 512];

  floatx4 acc[4][4];
#pragma unroll
  for (int i = 0; i < 4; i++)
#pragma unroll
    for (int j = 0; j < 4; j++) acc[i][j] = (floatx4){0.f, 0.f, 0.f, 0.f};

  const int rA = (wr * 64 + (l & 15)) * 32 + (l >> 4) * 8;
  const int rB = (wc * 64 + (l & 15)) * 32 + (l >> 4) * 8;

  for (int k0 = 0; k0 < K; k0 += 32) {
    __builtin_amdgcn_global_load_lds(ga0, la0, 16, 0, 0);
    __builtin_amdgcn_global_load_lds(ga1, la1, 16, 0, 0);
    __builtin_amdgcn_global_load_lds(gb0, lb0, 16, 0, 0);
    __builtin_amdgcn_global_load_lds(gb1, lb1, 16, 0, 0);
    ga0 += 32; ga1 += 32; gb0 += 32; gb1 += 32;
    __syncthreads();
    bf16x8 af[4], bfr[4];
#pragma unroll
    for (int i = 0; i < 4; i++) af[i] = *(const bf16x8*)&As[rA + i * 512];
#pragma unroll
    for (int j = 0; j < 4; j++) bfr[j] = *(const bf16x8*)&Bs[rB + j * 512];
#pragma unroll
    for (int i = 0; i < 4; i++)
#pragma unroll
      for (int j = 0; j < 4; j++) mfma16(acc[i][j], af[i], bfr[j]);
    __syncthreads();
  }

  const long crow = bm + wr * 64 + ((l >> 4) * 4);
  const long ccol = bn + wc * 64 + (l & 15);
  if constexpr (OUTB == 0) {
    float* C = (float*)Cv + (long)blockIdx.z * sC;
#pragma unroll
    for (int i = 0; i < 4; i++)
#pragma unroll
      for (int r = 0; r < 4; r++) {
        long row = crow + i * 16 + r;
#pragma unroll
        for (int j = 0; j < 4; j++) C[row * (long)ldc + ccol + j * 16] = acc[i][j][r];
      }
  } else {
    uint16_t* C = (uint16_t*)Cv + (long)blockIdx.z * sC;
#pragma unroll
    for (int i = 0; i < 4; i++)
#pragma unroll
      for (int r = 0; r < 4; r++) {
        long row = crow + i * 16 + r;
#pragma unroll
        for (int j = 0; j < 4; j++) C[row * (long)ldc + ccol + j * 16] = f2bf(acc[i][j][r]);
      }
  }
}

// ---------- split-K reduce: out_bf16[i] = sum_s in[s*stride + i] ----------
__global__ void __launch_bounds__(256) reduceK(const float* __restrict__ in,
                                               uint16_t* __restrict__ out,
                                               long n, int S, long stride) {
  long i = ((long)blockIdx.x * 256 + threadIdx.x) * 4;
  if (i >= n) return;
  float4 s = *(const float4*)(in + i);
  for (int k = 1; k < S; k++) {
    float4 t = *(const float4*)(in + k * stride + i);
    s.x += t.x; s.y += t.y; s.z += t.z; s.w += t.w;
  }
  ushort4 o; o.x = f2bf(s.x); o.y = f2bf(s.y); o.z = f2bf(s.z); o.w = f2bf(s.w);
  *(ushort4*)(out + i) = o;
}

// ---------- fused h convert + small-weight converts + rope table (one launch) ----------
__global__ void __launch_bounds__(256) prep_all(
    const float* __restrict__ h,
    const float* __restrict__ wdq, const float* __restrict__ wdkv,
    const float* __restrict__ wqr, const float* __restrict__ wkr,
    const float* __restrict__ wo,
    uint16_t* __restrict__ hb,
    uint16_t* __restrict__ wdq_b, uint16_t* __restrict__ wdkv_b,
    uint16_t* __restrict__ wqr_b, uint16_t* __restrict__ wkr_b,
    uint16_t* __restrict__ wo_b, float2* __restrict__ rtab)
{
  const int b = blockIdx.x;
  if (b < 27648) {
    const float* src; uint16_t* dst; long off;
    if (b < 16384)      { src = h;    dst = hb;     off = b; }
    else if (b < 17408) { src = wdq;  dst = wdq_b;  off = b - 16384; }
    else if (b < 18432) { src = wdkv; dst = wdkv_b; off = b - 17408; }
    else if (b < 19456) { src = wqr;  dst = wqr_b;  off = b - 18432; }
    else if (b < 23552) { src = wkr;  dst = wkr_b;  off = b - 19456; }
    else                { src = wo;   dst = wo_b;   off = b - 23552; }
    long i = (off * 256 + threadIdx.x) * 4;
    float4 v = *(const float4*)(src + i);
    ushort4 o; o.x = f2bf(v.x); o.y = f2bf(v.y); o.z = f2bf(v.z); o.w = f2bf(v.w);
    *(ushort4*)(dst + i) = o;
  } else {
    int idx = (b - 27648) * 256 + threadIdx.x;  // 2048*64
    int s = idx >> 6, fi = idx & 63;
    float f = powf(10000.0f, -(float)fi * (1.0f / 64.0f));
    float ang = (float)s * f;
    rtab[idx] = make_float2(cosf(ang), sinf(ang));
  }
}

// ---------- fused 4-way weight transpose (fp32 -> bf16), one launch ----------
__global__ void __launch_bounds__(256) transpose4(
    const float* __restrict__ wuk, const float* __restrict__ wuq,
    const float* __restrict__ wuv, const float* __restrict__ wdq,
    uint16_t* __restrict__ wukT, uint16_t* __restrict__ wuqT,
    uint16_t* __restrict__ wuvT, uint16_t* __restrict__ wdqT)
{
  __shared__ float tile[32][33];
  const int bt = blockIdx.x;
  const float* in; uint16_t* out; int ld_in, ld_out, rb, cb;
  if (bt < 3072) {  // wuk/wuq/wuv: (2048 x 512) -> (512 x 2048)
    const int op = bt >> 10, rem = bt & 1023;
    in = (op == 0) ? wuk : (op == 1) ? wuq : wuv;
    out = (op == 0) ? wukT : (op == 1) ? wuqT : wuvT;
    ld_in = 512; ld_out = 2048;
    cb = (rem & 15) * 32; rb = (rem >> 4) * 32;
  } else {          // wdq: (512 x 2048) -> (2048 x 512)
    const int rem = bt - 3072;
    in = wdq; out = wdqT; ld_in = 2048; ld_out = 512;
    cb = (rem & 63) * 32; rb = (rem >> 6) * 32;
  }
#pragma unroll
  for (int i = 0; i < 32; i += 8)
    tile[threadIdx.y + i][threadIdx.x] =
        in[(long)(rb + threadIdx.y + i) * ld_in + cb + threadIdx.x];
  __syncthreads();
#pragma unroll
  for (int i = 0; i < 32; i += 8)
    out[(long)(cb + threadIdx.y + i) * ld_out + rb + threadIdx.x] =
        f2bf(tile[threadIdx.x][threadIdx.y + i]);
}

// ---------- transpose (R,Cc) -> (Cc,R), bf16 out (used for ckvT) ----------
template<typename TIN>
__global__ void __launch_bounds__(256) transpose_to_bf16(
    const TIN* __restrict__ in, uint16_t* __restrict__ out,
    int ld_in, int ld_out, long sIn, long sOut)
{
  __shared__ float tile[32][33];
  in += (long)blockIdx.z * sIn;
  out += (long)blockIdx.z * sOut;
  const int rb = blockIdx.y * 32, cb = blockIdx.x * 32;
#pragma unroll
  for (int i = 0; i < 32; i += 8)
    tile[threadIdx.y + i][threadIdx.x] =
        ld_as_float(in[(long)(rb + threadIdx.y + i) * ld_in + cb + threadIdx.x]);
  __syncthreads();
#pragma unroll
  for (int i = 0; i < 32; i += 8)
    out[(long)(cb + threadIdx.y + i) * ld_out + rb + threadIdx.x] =
        f2bf(tile[threadIdx.x][threadIdx.y + i]);
}

// ---------- rmsnorm: one block per row; DIM = PT*256 ----------
template<int PT, typename TIN>
__global__ void __launch_bounds__(256) rmsnorm_k(
    const TIN* __restrict__ in, const float* __restrict__ g,
    float* __restrict__ out_f, uint16_t* __restrict__ out_b, int ld_b)
{
  constexpr int DIM = PT * 256;
  __shared__ float sm[9];
  const TIN* x = in + (long)blockIdx.x * DIM;
  const int base = threadIdx.x * PT;
  float v[PT];
  if constexpr (sizeof(TIN) == 2) {
    if constexpr (PT >= 8) {
#pragma unroll
      for (int i = 0; i < PT; i += 8) {
        u16x8 t = *(const u16x8*)&x[base + i];
#pragma unroll
        for (int q = 0; q < 8; q++) v[i + q] = bf2f(t[q]);
      }
    } else {
#pragma unroll
      for (int i = 0; i < PT; i += 2) {
        ushort2 t = *(const ushort2*)&x[base + i];
        v[i] = bf2f(t.x); v[i + 1] = bf2f(t.y);
      }
    }
  } else if constexpr (PT == 2) {
    float2 t = *(const float2*)&x[base]; v[0] = t.x; v[1] = t.y;
  } else {
#pragma unroll
    for (int i = 0; i < PT; i += 4) {
      float4 t = *(const float4*)&x[base + i];
      v[i] = t.x; v[i + 1] = t.y; v[i + 2] = t.z; v[i + 3] = t.w;
    }
  }
  float ss = 0.f;
#pragma unroll
  for (int i = 0; i < PT; i++) ss += v[i] * v[i];
#pragma unroll
  for (int o = 32; o; o >>= 1) ss += __shfl_down(ss, o);
  if ((threadIdx.x & 63) == 0) sm[threadIdx.x >> 6] = ss;
  __syncthreads();
  if (threadIdx.x == 0)
    sm[8] = rsqrtf((sm[0] + sm[1] + sm[2] + sm[3]) * (1.0f / DIM) + 1.1920929e-7f);
  __syncthreads();
  const float sc = sm[8];
#pragma unroll
  for (int i = 0; i < PT; i++) {
    float y = v[i] * sc * g[base + i];
    if (out_f) out_f[(long)blockIdx.x * DIM + base + i] = y;
    if (out_b) out_b[(long)blockIdx.x * ld_b + base + i] = f2bf(y);
  }
}

// ---------- softmax over rows of 2048, bf16 in (pre-scaled), bf16 out ----------
__global__ void __launch_bounds__(256) softmax_k(const uint16_t* __restrict__ sc,
                                                 uint16_t* __restrict__ attn) {
  __shared__ float sm[9];
  const uint16_t* x = sc + ((long)blockIdx.x << 11);
  const int base = threadIdx.x * 8;
  float v[8];
  u16x8 t = *(const u16x8*)&x[base];
#pragma unroll
  for (int i = 0; i < 8; i++) v[i] = bf2f(t[i]);
  float m = -1e30f;
#pragma unroll
  for (int i = 0; i < 8; i++) m = fmaxf(m, v[i]);
#pragma unroll
  for (int o = 32; o; o >>= 1) m = fmaxf(m, __shfl_down(m, o));
  if ((threadIdx.x & 63) == 0) sm[threadIdx.x >> 6] = m;
  __syncthreads();
  if (threadIdx.x == 0)
    sm[8] = fmaxf(fmaxf(sm[0], sm[1]), fmaxf(sm[2], sm[3]));
  __syncthreads();
  m = sm[8];
  __syncthreads();
  float ss = 0.f;
#pragma unroll
  for (int i = 0; i < 8; i++) { v[i] = __expf(v[i] - m); ss += v[i]; }
#pragma unroll
  for (int o = 32; o; o >>= 1) ss += __shfl_down(ss, o);
  if ((threadIdx.x & 63) == 0) sm[threadIdx.x >> 6] = ss;
  __syncthreads();
  if (threadIdx.x == 0) sm[8] = 1.0f / (sm[0] + sm[1] + sm[2] + sm[3]);
  __syncthreads();
  const float r = sm[8];
  ushort4 o1, o2;
  o1.x = f2bf(v[0] * r); o1.y = f2bf(v[1] * r); o1.z = f2bf(v[2] * r); o1.w = f2bf(v[3] * r);
  o2.x = f2bf(v[4] * r); o2.y = f2bf(v[5] * r); o2.z = f2bf(v[6] * r); o2.w = f2bf(v[7] * r);
  uint16_t* dst = attn + ((long)blockIdx.x << 11) + base;
  *(ushort4*)dst = o1;
  *(ushort4*)(dst + 4) = o2;
}

// ---------- orchestration ----------
extern "C" void kernel_launch(void* const* d_in, const int* in_sizes, int n_in,
                              void* d_out, int out_size, void* d_ws, size_t ws_size,
                              hipStream_t stream) {
  (void)in_sizes; (void)n_in; (void)out_size; (void)ws_size;
  const float* h    = (const float*)d_in[0];
  const float* wdkv = (const float*)d_in[1];
  const float* wuk  = (const float*)d_in[2];
  const float* wuv  = (const float*)d_in[3];
  const float* wdq  = (const float*)d_in[4];
  const float* wuq  = (const float*)d_in[5];
  const float* wkr  = (const float*)d_in[6];
  const float* wqr  = (const float*)d_in[7];
  const float* wo   = (const float*)d_in[8];
  const float* g1   = (const float*)d_in[9];
  const float* g2   = (const float*)d_in[10];
  const float* g3   = (const float*)d_in[11];

  float* u_out   = (float*)d_out;                 // (4,2048,2048)
  float* ckv_out = u_out + 16777216L;             // (4,2048,512)
  float* kr_out  = ckv_out + 4194304L;            // (4,2048,2048)

  char* p = (char*)d_ws;
  auto alloc = [&](size_t bytes) -> void* {
    void* q = (void*)p; p += (bytes + 255) & ~(size_t)255; return q;
  };
  uint16_t* hb     = (uint16_t*)alloc(16777216ULL * 2);  // h bf16
  uint16_t* wcat   = (uint16_t*)alloc(3145728ULL * 2);   // (1536,2048) [wdq;wdkv;Bqt]
  uint16_t* wqr_b  = (uint16_t*)alloc(1048576ULL * 2);
  uint16_t* wkr_b  = (uint16_t*)alloc(4194304ULL * 2);
  uint16_t* wo_b   = (uint16_t*)alloc(4194304ULL * 2);
  uint16_t* wukT   = (uint16_t*)alloc(1048576ULL * 2);   // (512,2048)
  uint16_t* wuqT   = (uint16_t*)alloc(1048576ULL * 2);
  uint16_t* wuvT   = (uint16_t*)alloc(1048576ULL * 2);
  uint16_t* wdqT   = (uint16_t*)alloc(1048576ULL * 2);   // (2048,512)
  uint16_t* T1t    = (uint16_t*)alloc(262144ULL * 2);    // (512,512)
  uint16_t* awoT   = (uint16_t*)alloc(1048576ULL * 2);   // absorbed_w_o^T (2048,512)
  uint16_t* cqpre  = (uint16_t*)alloc(4194304ULL * 2);   // (8192,512) bf16 cq-pre
  uint16_t* cq_b   = (uint16_t*)alloc(4194304ULL * 2);   // (8192,512)
  uint16_t* catq   = (uint16_t*)alloc(20971520ULL * 2);  // (8192,2560) [aq|qr]
  uint16_t* catk   = (uint16_t*)alloc(20971520ULL * 2);  // (8192,2560) [ckv|kr]
  uint16_t* ckvT   = (uint16_t*)alloc(4194304ULL * 2);   // 4 x (512,2048)
  uint16_t* o_b    = (uint16_t*)alloc(4194304ULL * 2);   // (8192,512)
  float2*   rtab   = (float2*)alloc(131072ULL * 8);      // 2048x64 (cos,sin)
  float*    tmpS2  = (float*)alloc(4194304ULL * 4);      // (8192,512) fp32 ckv-pre
  float*    tmpB   = (float*)alloc(16777216ULL * 4);     // (8192,2048) scratch
  float*    redT   = (float*)alloc(1048576ULL * 4);      // 4 x (512,512) partials
  float*    redW   = (float*)alloc(4194304ULL * 4);      // 4 x (2048,512) partials
  uint16_t* tmpBb  = (uint16_t*)tmpB;                    // alias: (8192,2048) bf16
  uint16_t* attn   = catq;  // alias: catq dead after scores GEMM

  uint16_t* wdq_b  = wcat;                  // rows 0-511
  uint16_t* wdkv_b = wcat + 1048576;        // rows 512-1023
  uint16_t* Bqt    = wcat + 2097152;        // rows 1024-1535 (absorbed_w_q^T)

  const dim3 b256(256);
  const dim3 b512(512);
  const dim3 tb(32, 8);

  // fused h convert + small-weight converts + rope table
  prep_all<<<dim3(28160), b256, 0, stream>>>(
      h, wdq, wdkv, wqr, wkr, wo, hb, wdq_b, wdkv_b, wqr_b, wkr_b, wo_b, rtab);
  // fused weight transposes (fp32 -> bf16), one launch
  transpose4<<<dim3(4096), tb, 0, stream>>>(
      wuk, wuq, wuv, wdq, wukT, wuqT, wuvT, wdqT);

  // absorbed weights — split-K (z=4, Kc=512) + deterministic reduce
  gemm_bt<0><<<dim3(4, 4, 4), b256, 0, stream>>>(
      wukT, wuqT, redT, 512, 2048, 2048, 512, 512L, 512L, 262144L);
  reduceK<<<dim3(256), b256, 0, stream>>>(redT, T1t, 262144L, 4, 262144L);
  gemm_bt<0><<<dim3(16, 4, 4), b256, 0, stream>>>(
      wo_b, wuvT, redW, 512, 2048, 2048, 512, 512L, 512L, 1048576L);
  reduceK<<<dim3(1024), b256, 0, stream>>>(redW, awoT, 1048576L, 4, 1048576L);
  gemm_bt<1><<<dim3(4, 16, 1), b256, 0, stream>>>(T1t, wdqT, Bqt, 512, 512, 512, 2048, 0, 0, 0);

  // fused: [cq-pre(bf16) | ckv-pre(fp32) | aq(bf16)] = h @ [wdq; wdkv; Bqt]^T
  gemm256v3<2><<<dim3(32, 6, 1), b512, 0, stream>>>(
      hb, wcat, cqpre, tmpS2, catq, 2048, 2048, 2048, 0, 0, 0, 0, 2);
  // cq = rmsnorm(cq-pre, g1)
  rmsnorm_k<2, uint16_t><<<dim3(8192), b256, 0, stream>>>(cqpre, g1, nullptr, cq_b, 512);
  // qr = rope(cq @ wqr^T) fused in epilogue -> catq[:,512:]
  gemm256v3<4><<<dim3(32, 8, 1), b512, 0, stream>>>(
      cq_b, wqr_b, catq, rtab, nullptr, 512, 512, 512, 2560, 0, 0, 0, 4);
  // ckv = rmsnorm(ckv-pre, g2) -> ckv_out (fp32) + catk[:,0:512] (bf16)
  rmsnorm_k<2, float><<<dim3(8192), b256, 0, stream>>>(tmpS2, g2, ckv_out, catk, 2560);
  // ckvT: 4 x (512,2048) from catk cols 0..511
  transpose_to_bf16<uint16_t><<<dim3(16, 64, 4), tb, 0, stream>>>(
      catk, ckvT, 2560, 2048, 2048L * 2560, 512L * 2048);
  // kr = rope(h @ wkr^T) fused in epilogue -> catk[:,512:] + kr_out (fp32)
  gemm256v3<5><<<dim3(32, 8, 1), b512, 0, stream>>>(
      hb, wkr_b, catk, rtab, kr_out, 2048, 2048, 2048, 2560, 0, 0, 0, 4);
  // scores[b]/12 = (catq_b @ catk_b^T)/12 -> tmpBb bf16 (K=2560)
  gemm256v3<3><<<dim3(8, 8, 4), b512, 0, stream>>>(
      catq, catk, tmpBb, nullptr, nullptr, 2560, 2560, 2560, 2048,
      5242880L, 5242880L, 4194304L, 2);
  // softmax -> attn bf16 (aliases catq)
  softmax_k<<<dim3(8192), b256, 0, stream>>>(tmpBb, attn);
  // o[b] = attn_b @ ckv_b (via ckvT) -> o_b bf16
  gemm256<1><<<dim3(8, 4, 4), b512, 0, stream>>>(
      attn, ckvT, o_b, 2048, 2048, 2048, 512, 4194304L, 1048576L, 1048576L);
  // u = rmsnorm(o @ absorbed_w_o, g3) -> u_out
  gemm256v3<1><<<dim3(32, 8, 1), b512, 0, stream>>>(
      o_b, awoT, tmpBb, nullptr, nullptr, 512, 512, 512, 2048, 0, 0, 0, 4);
  rmsnorm_k<8, uint16_t><<<dim3(8192), b256, 0, stream>>>(tmpBb, g3, u_out, nullptr, 0);
}

// Round 13
// 462.805 us; speedup vs baseline: 1.2144x; 1.0204x over previous
//
#include <hip/hip_runtime.h>
#include <stdint.h>

// ---------- small helpers ----------
typedef __attribute__((ext_vector_type(8))) short bf16x8;
typedef __attribute__((ext_vector_type(8))) unsigned short u16x8;
typedef __attribute__((ext_vector_type(4))) float floatx4;

__device__ __forceinline__ uint16_t f2bf(float f) {
  union { float f; uint32_t u; } v; v.f = f;
  uint32_t r = v.u + 0x7fffu + ((v.u >> 16) & 1u);
  return (uint16_t)(r >> 16);
}
__device__ __forceinline__ float bf2f(uint16_t b) {
  union { uint32_t u; float f; } v; v.u = ((uint32_t)b) << 16;
  return v.f;
}
__device__ __forceinline__ float ld_as_float(float v) { return v; }
__device__ __forceinline__ float ld_as_float(uint16_t v) { return bf2f(v); }

__device__ __forceinline__ void mfma16(floatx4& d, bf16x8 a, bf16x8 b) {
  asm("v_mfma_f32_16x16x32_bf16 %0, %1, %2, %0" : "+v"(d) : "v"(a), "v"(b));
}

#define FENCE() asm volatile("" ::: "memory")
#define SCHED() __builtin_amdgcn_sched_barrier(0)
#define SBAR()                                  \
  do {                                          \
    FENCE();                                    \
    __builtin_amdgcn_sched_barrier(0);          \
    __builtin_amdgcn_s_barrier();               \
    __builtin_amdgcn_sched_barrier(0);          \
    FENCE();                                    \
  } while (0)

// ================= v5 GEMM: 256x256, BK=32, 4-slot ring, cross-tile reg prefetch =================
// C(M,N) = A(M,K) @ B(N,K)^T, bf16 in, fp32 acc. Requires K % 32 == 0, K >= 128.
// 512 threads = 8 waves (2M x 4N), per-wave 128x64 output (8x4 frags).
// LDS: 4 slots x (A 16KB + B 16KB) = 128 KB. Tile t in slot t%4, staging depth 3.
// Schedule (r11): every MFMA cluster consumes registers read >=1 phase earlier.
// Chunk-XOR swizzle (both sides, same involution; r7-verified conflicts=0).
// XCD mapping: 1D 8-way swizzle + swzG 2D supertile shaping (r10: -33% FETCH).
// MODE 0: fp32 C0; 1: bf16 C0; 2: routed (cols 0-511 bf16 C0 ld512 cq-pre,
//   512-1023 fp32 C1 ld512 ckv-pre, 1024-1535 bf16 C2 ld2560 aq);
// 3: bf16 C0 with fused *(1/12) scale;
// 4: RoPE epilogue -> bf16 C0[row*2560 + 512 + c]; C1v = rope table;
//    C2v = optional per-row fp32 scale vector s (rmsnorm fold: applied to acc
//    BEFORE the rotation; partner lane has the same row so scales agree).
// 5: RoPE epilogue -> bf16 C0[row*2560 + 512 + c] AND fp32 C2v[row*2048 + c].
//    Rope pair partner col c^1 lives in lane l^1 (crow has no bit-0 dep;
//    ccol = bn + wn*64 + (l&15)), so p = shfl_xor(v,1);
//    y = v*cos + sgn*p*sin, sgn = (l&1) ? +1 : -1;  fi = (c&127)>>1, s = row&2047.
template<int MODE>
__global__ void __launch_bounds__(512, 1) gemm256v3(
    const uint16_t* __restrict__ A, const uint16_t* __restrict__ B,
    void* __restrict__ C0v, void* __restrict__ C1v, void* __restrict__ C2v,
    int K, int lda, int ldb, int ldc,
    long sA, long sB, long sC, int swzG)
{
  __shared__ __attribute__((aligned(16))) char lds[131072];
  const int tid = threadIdx.x;
  const int w = tid >> 6, l = tid & 63;
  const int wm = w >> 2, wn = w & 3;

  // XCD-aware swizzle + 2D supertile shaping
  const int gx = gridDim.x;
  const int nwg = gx * gridDim.y;
  int id = blockIdx.y * gx + blockIdx.x;
  if ((nwg & 7) == 0) id = (id & 7) * (nwg >> 3) + (id >> 3);
  const int grp = gx * swzG;
  const int ing = id % grp;
  const long bm = (long)(ing / swzG) * 256;
  const long bn = ((long)(id / grp) * swzG + (ing % swzG)) * 256;
  A += (long)blockIdx.z * sA;
  B += (long)blockIdx.z * sB;

  // staging: one global_load_lds covers 128 rows x 64B (8 waves x 16 rows).
  const int scol = (((l & 3) ^ ((l >> 3) & 3)) << 3);  // pre-swizzled source chunk
  const uint16_t* gA = A + (bm + w * 16 + (l >> 2)) * (long)lda + scol;
  const uint16_t* gB = B + (bn + w * 16 + (l >> 2)) * (long)ldb + scol;
  const int ldsw = w * 1024;

#define STG_A3(slot, k0, r)                                                    \
  __builtin_amdgcn_global_load_lds(gA + (k0) + (long)(r) * 128 * lda,          \
      (uint16_t*)(lds + (slot) * 32768 + (r) * 8192 + ldsw), 16, 0, 0)
#define STG_B3(slot, k0, r)                                                    \
  __builtin_amdgcn_global_load_lds(gB + (k0) + (long)(r) * 128 * ldb,          \
      (uint16_t*)(lds + (slot) * 32768 + 16384 + (r) * 8192 + ldsw), 16, 0, 0)

  // fragment read geometry: row stride 64B; lane reads 16B at swizzled chunk
  const int lr = l & 15;
  const int chunkx = (((l >> 4) ^ ((lr >> 1) & 3)) << 4);  // bytes
  const int aoff = (wm * 128 + lr) * 64 + chunkx;
  const int boff = 16384 + (wn * 64 + lr) * 64 + chunkx;

  floatx4 acc[8][4];
#pragma unroll
  for (int i = 0; i < 8; i++)
#pragma unroll
    for (int j = 0; j < 4; j++) acc[i][j] = (floatx4){0.f, 0.f, 0.f, 0.f};

  const int nt = K >> 5;  // assumes nt >= 4
#pragma unroll
  for (int tt = 0; tt < 3; tt++) {
    STG_A3(tt, tt * 32, 0); STG_A3(tt, tt * 32, 1);
    STG_B3(tt, tt * 32, 0); STG_B3(tt, tt * 32, 1);
  }
  asm volatile("s_waitcnt vmcnt(8)" ::: "memory");  // tile 0 landed
  SBAR();

  bf16x8 Bf[4], Bfn[4], Af0[4], Af1[4];
#pragma unroll
  for (int j = 0; j < 4; j++) Bf[j] = *(const bf16x8*)(lds + boff + j * 1024);
#pragma unroll
  for (int i = 0; i < 4; i++) Af0[i] = *(const bf16x8*)(lds + aoff + i * 1024);

  for (int t = 0; t < nt; t++) {
    const char* Ls = lds + (t & 3) * 32768;
    const char* Ln = lds + ((t + 1) & 3) * 32768;
    const long pk0 = (long)(t + 3) << 5;
    const int pslot = (t + 3) & 3;
    const bool pf = (t + 3 < nt);

    // ---- phase 1: read Af1(t), stage (t+3) A, MFMA on Af0(t) x Bf(t) ----
#pragma unroll
    for (int i = 0; i < 4; i++) Af1[i] = *(const bf16x8*)(Ls + aoff + (4 + i) * 1024);
    SCHED();
    if (pf) { STG_A3(pslot, pk0, 0); STG_A3(pslot, pk0, 1); }
    asm volatile("s_waitcnt lgkmcnt(4)" ::: "memory");  // Bf+Af0 landed; Af1 in flight
    SCHED();
    __builtin_amdgcn_s_setprio(1);
#pragma unroll
    for (int i = 0; i < 4; i++)
#pragma unroll
      for (int j = 0; j < 4; j++) mfma16(acc[i][j], Af0[i], Bf[j]);
    __builtin_amdgcn_s_setprio(0);
    SCHED();

    // ---- mid: retire t+1 staging (counted), drain Af1 reads, fence ----
    if (t + 3 < nt)      asm volatile("s_waitcnt vmcnt(6)" ::: "memory");
    else if (t + 2 < nt) asm volatile("s_waitcnt vmcnt(4)" ::: "memory");
    else if (t + 1 < nt) asm volatile("s_waitcnt vmcnt(0)" ::: "memory");
    asm volatile("s_waitcnt lgkmcnt(0)" ::: "memory");
    SBAR();

    // ---- phase 2: read Bf/Af0 of t+1 (overlaps MFMA), stage (t+3) B, MFMA Af1 x Bf ----
    if (t + 1 < nt) {
#pragma unroll
      for (int j = 0; j < 4; j++) Bfn[j] = *(const bf16x8*)(Ln + boff + j * 1024);
#pragma unroll
      for (int i = 0; i < 4; i++) Af0[i] = *(const bf16x8*)(Ln + aoff + i * 1024);
    }
    SCHED();
    if (pf) { STG_B3(pslot, pk0, 0); STG_B3(pslot, pk0, 1); }
    SCHED();
    __builtin_amdgcn_s_setprio(1);
#pragma unroll
    for (int i = 0; i < 4; i++)
#pragma unroll
      for (int j = 0; j < 4; j++) mfma16(acc[4 + i][j], Af1[i], Bf[j]);
    __builtin_amdgcn_s_setprio(0);
    SCHED();
#pragma unroll
    for (int j = 0; j < 4; j++) Bf[j] = Bfn[j];
  }
#undef STG_A3
#undef STG_B3

  const long crow = bm + wm * 128 + ((l >> 4) * 4);
  const long ccol = bn + wn * 64 + (l & 15);
  if constexpr (MODE == 0) {
    float* C = (float*)C0v + (long)blockIdx.z * sC;
#pragma unroll
    for (int i = 0; i < 8; i++)
#pragma unroll
      for (int r = 0; r < 4; r++) {
        long row = crow + i * 16 + r;
#pragma unroll
        for (int j = 0; j < 4; j++) C[row * (long)ldc + ccol + j * 16] = acc[i][j][r];
      }
  } else if constexpr (MODE == 1) {
    uint16_t* C = (uint16_t*)C0v + (long)blockIdx.z * sC;
#pragma unroll
    for (int i = 0; i < 8; i++)
#pragma unroll
      for (int r = 0; r < 4; r++) {
        long row = crow + i * 16 + r;
#pragma unroll
        for (int j = 0; j < 4; j++) C[row * (long)ldc + ccol + j * 16] = f2bf(acc[i][j][r]);
      }
  } else if constexpr (MODE == 3) {
    const float s = 1.0f / 12.0f;
    uint16_t* C = (uint16_t*)C0v + (long)blockIdx.z * sC;
#pragma unroll
    for (int i = 0; i < 8; i++)
#pragma unroll
      for (int r = 0; r < 4; r++) {
        long row = crow + i * 16 + r;
#pragma unroll
        for (int j = 0; j < 4; j++) C[row * (long)ldc + ccol + j * 16] = f2bf(acc[i][j][r] * s);
      }
  } else if constexpr (MODE == 4 || MODE == 5) {
    // RoPE epilogue. MODE 4: optional per-row scale vector in C2v (rmsnorm fold).
    // MODE 5: also write fp32 pre-cat output to C2v (ld 2048).
    const float2* __restrict__ tab = (const float2*)C1v;
    uint16_t* Cb = (uint16_t*)C0v;
    const float* __restrict__ S = (MODE == 4) ? (const float*)C2v : nullptr;
    float* Cf = (MODE == 5) ? (float*)C2v : nullptr;
    const float sgn = (l & 1) ? 1.0f : -1.0f;
#pragma unroll
    for (int i = 0; i < 8; i++)
#pragma unroll
      for (int r = 0; r < 4; r++) {
        long row = crow + i * 16 + r;
        const float2* trow = tab + (((int)(row & 2047)) << 6);
        float srow = 1.0f;
        if constexpr (MODE == 4) srow = S ? S[row] : 1.0f;
#pragma unroll
        for (int j = 0; j < 4; j++) {
          long c = ccol + j * 16;
          float v = acc[i][j][r];
          if constexpr (MODE == 4) v *= srow;
          float pp = __shfl_xor(v, 1);
          float2 cs = trow[((int)(c & 127)) >> 1];
          float y = v * cs.x + sgn * pp * cs.y;
          Cb[row * 2560 + 512 + c] = f2bf(y);
          if constexpr (MODE == 5) Cf[row * 2048 + c] = y;
        }
      }
  } else {
    if (bn < 512) {
      uint16_t* C = (uint16_t*)C0v;
#pragma unroll
      for (int i = 0; i < 8; i++)
#pragma unroll
        for (int r = 0; r < 4; r++) {
          long row = crow + i * 16 + r;
#pragma unroll
          for (int j = 0; j < 4; j++) C[row * 512 + ccol + j * 16] = f2bf(acc[i][j][r]);
        }
    } else if (bn < 1024) {
      float* C = (float*)C1v;
      const long cc = ccol - 512;
#pragma unroll
      for (int i = 0; i < 8; i++)
#pragma unroll
        for (int r = 0; r < 4; r++) {
          long row = crow + i * 16 + r;
#pragma unroll
          for (int j = 0; j < 4; j++) C[row * 512 + cc + j * 16] = acc[i][j][r];
        }
    } else {
      uint16_t* C = (uint16_t*)C2v;
      const long cc = ccol - 1024;
#pragma unroll
      for (int i = 0; i < 8; i++)
#pragma unroll
        for (int r = 0; r < 4; r++) {
          long row = crow + i * 16 + r;
#pragma unroll
          for (int j = 0; j < 4; j++) C[row * 2560 + cc + j * 16] = f2bf(acc[i][j][r]);
        }
    }
  }
}

// ================= 256x128 pipelined GEMM (for the small-N o GEMM) =================
template<int OUTB>
__global__ void __launch_bounds__(512, 2) gemm256(
    const uint16_t* __restrict__ A, const uint16_t* __restrict__ B,
    void* __restrict__ Cv, int K, int lda, int ldb, int ldc,
    long sA, long sB, long sC)
{
  __shared__ __attribute__((aligned(16))) char lds[147456];
  const int tid = threadIdx.x;
  const int w = tid >> 6, l = tid & 63;
  const int wm = w >> 1, wn = w & 1;

  const int gx = gridDim.x;
  const int nwg = gx * gridDim.y;
  int id = blockIdx.y * gx + blockIdx.x;
  if ((nwg & 7) == 0) id = (id & 7) * (nwg >> 3) + (id >> 3);
  const long bm = (long)(id % gx) * 256;
  const long bn = (long)(id / gx) * 128;
  A += (long)blockIdx.z * sA;
  B += (long)blockIdx.z * sB;

  const int sr = l >> 3;
  const int sc = l & 7;
  const int scol = ((sc ^ sr) << 3);
  const uint16_t* gA = A + (bm + w * 8 + sr) * (long)lda + scol;
  const uint16_t* gB = B + (bn + w * 8 + sr) * (long)ldb + scol;
  const int ldsw = w * 1024;

#define STAGE_A(bufi, k0, r)                                                     \
  __builtin_amdgcn_global_load_lds(gA + (k0) + (long)(r) * 64 * lda,             \
      (uint16_t*)(lds + (bufi) * 49152 + (r) * 8192 + ldsw), 16, 0, 0)
#define STAGE_B(bufi, k0, r)                                                     \
  __builtin_amdgcn_global_load_lds(gB + (k0) + (long)(r) * 64 * ldb,             \
      (uint16_t*)(lds + (bufi) * 49152 + 32768 + (r) * 8192 + ldsw), 16, 0, 0)

  const int lr = l & 15;
  const int kk = (l >> 4) << 4;
  const int msk = (l & 7) << 4;
  const int ko0 = kk ^ msk;
  const int ko1 = (64 + kk) ^ msk;
  const int arow = (wm * 64 + lr) * 128;
  const int brow = (wn * 64 + lr) * 128;

  floatx4 acc[4][4];
#pragma unroll
  for (int i = 0; i < 4; i++)
#pragma unroll
    for (int j = 0; j < 4; j++) acc[i][j] = (floatx4){0.f, 0.f, 0.f, 0.f};

  const int nt = K >> 6;
#pragma unroll
  for (int r = 0; r < 4; r++) STAGE_A(0, 0, r);
#pragma unroll
  for (int r = 0; r < 2; r++) STAGE_B(0, 0, r);
#pragma unroll
  for (int r = 0; r < 4; r++) STAGE_A(1, 64, r);
#pragma unroll
  for (int r = 0; r < 2; r++) STAGE_B(1, 64, r);
  asm volatile("s_waitcnt vmcnt(6)" ::: "memory");
  SBAR();

  bf16x8 af0[4], bf0[4], af1[4], bf1[4];
  {
    const char* LA = lds + arow;
    const char* LB = lds + 32768 + brow;
#pragma unroll
    for (int i = 0; i < 4; i++) af0[i] = *(const bf16x8*)(LA + i * 2048 + ko0);
#pragma unroll
    for (int j = 0; j < 4; j++) bf0[j] = *(const bf16x8*)(LB + j * 2048 + ko0);
  }

  for (int t = 0; t < nt; t++) {
    const int buf = t % 3;
    const int pbuf = (t + 2) % 3;
    const long pk0 = (long)(t + 2) << 6;
    const char* LA = lds + buf * 49152 + arow;
    const char* LB = lds + buf * 49152 + 32768 + brow;
    const bool pf = (t + 2 < nt);

    if (pf) { STAGE_A(pbuf, pk0, 0); STAGE_A(pbuf, pk0, 1); STAGE_B(pbuf, pk0, 0); }
#pragma unroll
    for (int i = 0; i < 4; i++) af1[i] = *(const bf16x8*)(LA + i * 2048 + ko1);
#pragma unroll
    for (int j = 0; j < 4; j++) bf1[j] = *(const bf16x8*)(LB + j * 2048 + ko1);
    SCHED();
    __builtin_amdgcn_s_setprio(1);
#pragma unroll
    for (int i = 0; i < 4; i++)
#pragma unroll
      for (int j = 0; j < 4; j++) mfma16(acc[i][j], af0[i], bf0[j]);
    __builtin_amdgcn_s_setprio(0);
    SCHED();

    if (pf) { STAGE_A(pbuf, pk0, 2); STAGE_A(pbuf, pk0, 3); STAGE_B(pbuf, pk0, 1); }
    if (t < nt - 2) asm volatile("s_waitcnt vmcnt(6) lgkmcnt(0)" ::: "memory");
    else            asm volatile("s_waitcnt vmcnt(0) lgkmcnt(0)" ::: "memory");
    SBAR();
    if (t < nt - 1) {
      const char* LAn = lds + ((t + 1) % 3) * 49152 + arow;
      const char* LBn = lds + ((t + 1) % 3) * 49152 + 32768 + brow;
#pragma unroll
      for (int i = 0; i < 4; i++) af0[i] = *(const bf16x8*)(LAn + i * 2048 + ko0);
#pragma unroll
      for (int j = 0; j < 4; j++) bf0[j] = *(const bf16x8*)(LBn + j * 2048 + ko0);
    }
    SCHED();
    __builtin_amdgcn_s_setprio(1);
#pragma unroll
    for (int i = 0; i < 4; i++)
#pragma unroll
      for (int j = 0; j < 4; j++) mfma16(acc[i][j], af1[i], bf1[j]);
    __builtin_amdgcn_s_setprio(0);
    SCHED();
  }
#undef STAGE_A
#undef STAGE_B

  const long crow = bm + wm * 64 + ((l >> 4) * 4);
  const long ccol = bn + wn * 64 + (l & 15);
  if constexpr (OUTB == 0) {
    float* C = (float*)Cv + (long)blockIdx.z * sC;
#pragma unroll
    for (int i = 0; i < 4; i++)
#pragma unroll
      for (int r = 0; r < 4; r++) {
        long row = crow + i * 16 + r;
#pragma unroll
        for (int j = 0; j < 4; j++) C[row * (long)ldc + ccol + j * 16] = acc[i][j][r];
      }
  } else {
    uint16_t* C = (uint16_t*)Cv + (long)blockIdx.z * sC;
#pragma unroll
    for (int i = 0; i < 4; i++)
#pragma unroll
      for (int r = 0; r < 4; r++) {
        long row = crow + i * 16 + r;
#pragma unroll
        for (int j = 0; j < 4; j++) C[row * (long)ldc + ccol + j * 16] = f2bf(acc[i][j][r]);
      }
  }
}

// ================= legacy 128x128 GEMM (small weight-prep matmuls, split-K via z) =================
template<int OUTB>
__global__ void __launch_bounds__(256) gemm_bt(
    const uint16_t* __restrict__ A, const uint16_t* __restrict__ B,
    void* __restrict__ Cv, int K, int lda, int ldb, int ldc,
    long sA, long sB, long sC)
{
  __shared__ alignas(16) uint16_t As[4096];
  __shared__ alignas(16) uint16_t Bs[4096];
  const int tid = threadIdx.x;
  const int w = tid >> 6, l = tid & 63;
  const int wr = w >> 1, wc = w & 1;
  const long bm = (long)blockIdx.x * 128, bn = (long)blockIdx.y * 128;
  A += (long)blockIdx.z * sA;
  B += (long)blockIdx.z * sB;

  const uint16_t* ga0 = A + (bm + w * 16 + (l >> 2)) * (long)lda + (l & 3) * 8;
  const uint16_t* ga1 = ga0 + 64L * lda;
  const uint16_t* gb0 = B + (bn + w * 16 + (l >> 2)) * (long)ldb + (l & 3) * 8;
  const uint16_t* gb1 = gb0 + 64L * ldb;
  uint16_t* la0 = &As[w * 512];
  uint16_t* la1 = &As[2048 + w * 512];
  uint16_t* lb0 = &Bs[w * 512];
  uint16_t* lb1 = &Bs[2048 + w * 512];

  floatx4 acc[4][4];
#pragma unroll
  for (int i = 0; i < 4; i++)
#pragma unroll
    for (int j = 0; j < 4; j++) acc[i][j] = (floatx4){0.f, 0.f, 0.f, 0.f};

  const int rA = (wr * 64 + (l & 15)) * 32 + (l >> 4) * 8;
  const int rB = (wc * 64 + (l & 15)) * 32 + (l >> 4) * 8;

  for (int k0 = 0; k0 < K; k0 += 32) {
    __builtin_amdgcn_global_load_lds(ga0, la0, 16, 0, 0);
    __builtin_amdgcn_global_load_lds(ga1, la1, 16, 0, 0);
    __builtin_amdgcn_global_load_lds(gb0, lb0, 16, 0, 0);
    __builtin_amdgcn_global_load_lds(gb1, lb1, 16, 0, 0);
    ga0 += 32; ga1 += 32; gb0 += 32; gb1 += 32;
    __syncthreads();
    bf16x8 af[4], bfr[4];
#pragma unroll
    for (int i = 0; i < 4; i++) af[i] = *(const bf16x8*)&As[rA + i * 512];
#pragma unroll
    for (int j = 0; j < 4; j++) bfr[j] = *(const bf16x8*)&Bs[rB + j * 512];
#pragma unroll
    for (int i = 0; i < 4; i++)
#pragma unroll
      for (int j = 0; j < 4; j++) mfma16(acc[i][j], af[i], bfr[j]);
    __syncthreads();
  }

  const long crow = bm + wr * 64 + ((l >> 4) * 4);
  const long ccol = bn + wc * 64 + (l & 15);
  if constexpr (OUTB == 0) {
    float* C = (float*)Cv + (long)blockIdx.z * sC;
#pragma unroll
    for (int i = 0; i < 4; i++)
#pragma unroll
      for (int r = 0; r < 4; r++) {
        long row = crow + i * 16 + r;
#pragma unroll
        for (int j = 0; j < 4; j++) C[row * (long)ldc + ccol + j * 16] = acc[i][j][r];
      }
  } else {
    uint16_t* C = (uint16_t*)Cv + (long)blockIdx.z * sC;
#pragma unroll
    for (int i = 0; i < 4; i++)
#pragma unroll
      for (int r = 0; r < 4; r++) {
        long row = crow + i * 16 + r;
#pragma unroll
        for (int j = 0; j < 4; j++) C[row * (long)ldc + ccol + j * 16] = f2bf(acc[i][j][r]);
      }
  }
}

// ---------- split-K reduce: out_bf16[i] = sum_s in[s*stride + i] ----------
__global__ void __launch_bounds__(256) reduceK(const float* __restrict__ in,
                                               uint16_t* __restrict__ out,
                                               long n, int S, long stride) {
  long i = ((long)blockIdx.x * 256 + threadIdx.x) * 4;
  if (i >= n) return;
  float4 s = *(const float4*)(in + i);
  for (int k = 1; k < S; k++) {
    float4 t = *(const float4*)(in + k * stride + i);
    s.x += t.x; s.y += t.y; s.z += t.z; s.w += t.w;
  }
  ushort4 o; o.x = f2bf(s.x); o.y = f2bf(s.y); o.z = f2bf(s.z); o.w = f2bf(s.w);
  *(ushort4*)(out + i) = o;
}

// ---------- fused prep: h/weight converts + g1-folded wqr + rope table + transposes ----------
__global__ void __launch_bounds__(256) prep_all(
    const float* __restrict__ h,
    const float* __restrict__ wdq, const float* __restrict__ wdkv,
    const float* __restrict__ wqr, const float* __restrict__ wkr,
    const float* __restrict__ wo, const float* __restrict__ g1,
    const float* __restrict__ wuk, const float* __restrict__ wuq,
    const float* __restrict__ wuv,
    uint16_t* __restrict__ hb,
    uint16_t* __restrict__ wdq_b, uint16_t* __restrict__ wdkv_b,
    uint16_t* __restrict__ wqr_b, uint16_t* __restrict__ wkr_b,
    uint16_t* __restrict__ wo_b, float2* __restrict__ rtab,
    uint16_t* __restrict__ wukT, uint16_t* __restrict__ wuqT,
    uint16_t* __restrict__ wuvT, uint16_t* __restrict__ wdqT)
{
  const int b = blockIdx.x;
  if (b < 27648) {
    // vector bf16 convert region
    if (b >= 18432 && b < 19456) {  // wqr with g1 fold: wqr_b[e,c] = wqr[e,c]*g1[c]
      long i = ((long)(b - 18432) * 256 + threadIdx.x) * 4;
      float4 v = *(const float4*)(wqr + i);
      int c = (int)(i & 511);
      float4 g = *(const float4*)(g1 + c);
      ushort4 o;
      o.x = f2bf(v.x * g.x); o.y = f2bf(v.y * g.y);
      o.z = f2bf(v.z * g.z); o.w = f2bf(v.w * g.w);
      *(ushort4*)(wqr_b + i) = o;
      return;
    }
    const float* src; uint16_t* dst; long off;
    if (b < 16384)      { src = h;    dst = hb;     off = b; }
    else if (b < 17408) { src = wdq;  dst = wdq_b;  off = b - 16384; }
    else if (b < 18432) { src = wdkv; dst = wdkv_b; off = b - 17408; }
    else if (b < 23552) { src = wkr;  dst = wkr_b;  off = b - 19456; }
    else                { src = wo;   dst = wo_b;   off = b - 23552; }
    long i = (off * 256 + threadIdx.x) * 4;
    float4 v = *(const float4*)(src + i);
    ushort4 o; o.x = f2bf(v.x); o.y = f2bf(v.y); o.z = f2bf(v.z); o.w = f2bf(v.w);
    *(ushort4*)(dst + i) = o;
  } else if (b < 28160) {
    int idx = (b - 27648) * 256 + threadIdx.x;  // 2048*64 rope table
    int s = idx >> 6, fi = idx & 63;
    float f = powf(10000.0f, -(float)fi * (1.0f / 64.0f));
    float ang = (float)s * f;
    rtab[idx] = make_float2(cosf(ang), sinf(ang));
  } else {
    // transpose region (flat 256 threads: x = tid&31, y = tid>>5 -> 8 rows/pass)
    __shared__ float tile[32][33];
    const int bt = b - 28160;
    const int tx = threadIdx.x & 31, ty = threadIdx.x >> 5;
    const float* in; uint16_t* out; int ld_in, ld_out, rb, cb;
    if (bt < 3072) {  // wuk/wuq/wuv: (2048 x 512) -> (512 x 2048)
      const int op = bt >> 10, rem = bt & 1023;
      in = (op == 0) ? wuk : (op == 1) ? wuq : wuv;
      out = (op == 0) ? wukT : (op == 1) ? wuqT : wuvT;
      ld_in = 512; ld_out = 2048;
      cb = (rem & 15) * 32; rb = (rem >> 4) * 32;
    } else {          // wdq: (512 x 2048) -> (2048 x 512)
      const int rem = bt - 3072;
      in = wdq; out = wdqT; ld_in = 2048; ld_out = 512;
      cb = (rem & 63) * 32; rb = (rem >> 6) * 32;
    }
#pragma unroll
    for (int i = 0; i < 32; i += 8)
      tile[ty + i][tx] = in[(long)(rb + ty + i) * ld_in + cb + tx];
    __syncthreads();
#pragma unroll
    for (int i = 0; i < 32; i += 8)
      out[(long)(cb + ty + i) * ld_out + rb + tx] = f2bf(tile[tx][ty + i]);
  }
}

// ---------- transpose (R,Cc) -> (Cc,R), bf16 out (used for ckvT) ----------
template<typename TIN>
__global__ void __launch_bounds__(256) transpose_to_bf16(
    const TIN* __restrict__ in, uint16_t* __restrict__ out,
    int ld_in, int ld_out, long sIn, long sOut)
{
  __shared__ float tile[32][33];
  in += (long)blockIdx.z * sIn;
  out += (long)blockIdx.z * sOut;
  const int rb = blockIdx.y * 32, cb = blockIdx.x * 32;
#pragma unroll
  for (int i = 0; i < 32; i += 8)
    tile[threadIdx.y + i][threadIdx.x] =
        ld_as_float(in[(long)(rb + threadIdx.y + i) * ld_in + cb + threadIdx.x]);
  __syncthreads();
#pragma unroll
  for (int i = 0; i < 32; i += 8)
    out[(long)(cb + threadIdx.y + i) * ld_out + rb + threadIdx.x] =
        f2bf(tile[threadIdx.x][threadIdx.y + i]);
}

// ---------- fused norms: blocks 0..8191 cq-scale only; 8192..16383 ckv full ----------
// cq:  s[row] = rsqrt(mean(cqpre_row^2) + eps)            (cqpre bf16, 512)
// ckv: y = rmsnorm(ckvpre_row, g2) -> ckv_out fp32 + catk[:,0:512] bf16 (ld 2560)
__global__ void __launch_bounds__(256) norm_pair(
    const uint16_t* __restrict__ cqpre, float* __restrict__ sVec,
    const float* __restrict__ ckvpre, const float* __restrict__ g2,
    float* __restrict__ ckv_out, uint16_t* __restrict__ catk)
{
  __shared__ float sm[9];
  const int b = blockIdx.x;
  const int base = threadIdx.x * 2;
  float v0, v1;
  if (b < 8192) {
    ushort2 t = *(const ushort2*)&cqpre[(long)b * 512 + base];
    v0 = bf2f(t.x); v1 = bf2f(t.y);
  } else {
    float2 t = *(const float2*)&ckvpre[(long)(b - 8192) * 512 + base];
    v0 = t.x; v1 = t.y;
  }
  float ss = v0 * v0 + v1 * v1;
#pragma unroll
  for (int o = 32; o; o >>= 1) ss += __shfl_down(ss, o);
  if ((threadIdx.x & 63) == 0) sm[threadIdx.x >> 6] = ss;
  __syncthreads();
  if (threadIdx.x == 0)
    sm[8] = rsqrtf((sm[0] + sm[1] + sm[2] + sm[3]) * (1.0f / 512.0f) + 1.1920929e-7f);
  __syncthreads();
  const float sc = sm[8];
  if (b < 8192) {
    if (threadIdx.x == 0) sVec[b] = sc;
  } else {
    const long row = b - 8192;
    float y0 = v0 * sc * g2[base];
    float y1 = v1 * sc * g2[base + 1];
    *(float2*)&ckv_out[row * 512 + base] = make_float2(y0, y1);
    ushort2 o; o.x = f2bf(y0); o.y = f2bf(y1);
    *(ushort2*)&catk[row * 2560 + base] = o;
  }
}

// ---------- rmsnorm: one block per row; DIM = PT*256 (u-norm) ----------
template<int PT, typename TIN>
__global__ void __launch_bounds__(256) rmsnorm_k(
    const TIN* __restrict__ in, const float* __restrict__ g,
    float* __restrict__ out_f, uint16_t* __restrict__ out_b, int ld_b)
{
  constexpr int DIM = PT * 256;
  __shared__ float sm[9];
  const TIN* x = in + (long)blockIdx.x * DIM;
  const int base = threadIdx.x * PT;
  float v[PT];
  if constexpr (sizeof(TIN) == 2) {
#pragma unroll
    for (int i = 0; i < PT; i += 8) {
      u16x8 t = *(const u16x8*)&x[base + i];
#pragma unroll
      for (int q = 0; q < 8; q++) v[i + q] = bf2f(t[q]);
    }
  } else {
#pragma unroll
    for (int i = 0; i < PT; i += 4) {
      float4 t = *(const float4*)&x[base + i];
      v[i] = t.x; v[i + 1] = t.y; v[i + 2] = t.z; v[i + 3] = t.w;
    }
  }
  float ss = 0.f;
#pragma unroll
  for (int i = 0; i < PT; i++) ss += v[i] * v[i];
#pragma unroll
  for (int o = 32; o; o >>= 1) ss += __shfl_down(ss, o);
  if ((threadIdx.x & 63) == 0) sm[threadIdx.x >> 6] = ss;
  __syncthreads();
  if (threadIdx.x == 0)
    sm[8] = rsqrtf((sm[0] + sm[1] + sm[2] + sm[3]) * (1.0f / DIM) + 1.1920929e-7f);
  __syncthreads();
  const float sc = sm[8];
#pragma unroll
  for (int i = 0; i < PT; i++) {
    float y = v[i] * sc * g[base + i];
    if (out_f) out_f[(long)blockIdx.x * DIM + base + i] = y;
    if (out_b) out_b[(long)blockIdx.x * ld_b + base + i] = f2bf(y);
  }
}

// ---------- softmax over rows of 2048, bf16 in (pre-scaled), bf16 out ----------
__global__ void __launch_bounds__(256) softmax_k(const uint16_t* __restrict__ sc,
                                                 uint16_t* __restrict__ attn) {
  __shared__ float sm[9];
  const uint16_t* x = sc + ((long)blockIdx.x << 11);
  const int base = threadIdx.x * 8;
  float v[8];
  u16x8 t = *(const u16x8*)&x[base];
#pragma unroll
  for (int i = 0; i < 8; i++) v[i] = bf2f(t[i]);
  float m = -1e30f;
#pragma unroll
  for (int i = 0; i < 8; i++) m = fmaxf(m, v[i]);
#pragma unroll
  for (int o = 32; o; o >>= 1) m = fmaxf(m, __shfl_down(m, o));
  if ((threadIdx.x & 63) == 0) sm[threadIdx.x >> 6] = m;
  __syncthreads();
  if (threadIdx.x == 0)
    sm[8] = fmaxf(fmaxf(sm[0], sm[1]), fmaxf(sm[2], sm[3]));
  __syncthreads();
  m = sm[8];
  __syncthreads();
  float ss = 0.f;
#pragma unroll
  for (int i = 0; i < 8; i++) { v[i] = __expf(v[i] - m); ss += v[i]; }
#pragma unroll
  for (int o = 32; o; o >>= 1) ss += __shfl_down(ss, o);
  if ((threadIdx.x & 63) == 0) sm[threadIdx.x >> 6] = ss;
  __syncthreads();
  if (threadIdx.x == 0) sm[8] = 1.0f / (sm[0] + sm[1] + sm[2] + sm[3]);
  __syncthreads();
  const float r = sm[8];
  ushort4 o1, o2;
  o1.x = f2bf(v[0] * r); o1.y = f2bf(v[1] * r); o1.z = f2bf(v[2] * r); o1.w = f2bf(v[3] * r);
  o2.x = f2bf(v[4] * r); o2.y = f2bf(v[5] * r); o2.z = f2bf(v[6] * r); o2.w = f2bf(v[7] * r);
  uint16_t* dst = attn + ((long)blockIdx.x << 11) + base;
  *(ushort4*)dst = o1;
  *(ushort4*)(dst + 4) = o2;
}

// ---------- orchestration ----------
extern "C" void kernel_launch(void* const* d_in, const int* in_sizes, int n_in,
                              void* d_out, int out_size, void* d_ws, size_t ws_size,
                              hipStream_t stream) {
  (void)in_sizes; (void)n_in; (void)out_size; (void)ws_size;
  const float* h    = (const float*)d_in[0];
  const float* wdkv = (const float*)d_in[1];
  const float* wuk  = (const float*)d_in[2];
  const float* wuv  = (const float*)d_in[3];
  const float* wdq  = (const float*)d_in[4];
  const float* wuq  = (const float*)d_in[5];
  const float* wkr  = (const float*)d_in[6];
  const float* wqr  = (const float*)d_in[7];
  const float* wo   = (const float*)d_in[8];
  const float* g1   = (const float*)d_in[9];
  const float* g2   = (const float*)d_in[10];
  const float* g3   = (const float*)d_in[11];

  float* u_out   = (float*)d_out;                 // (4,2048,2048)
  float* ckv_out = u_out + 16777216L;             // (4,2048,512)
  float* kr_out  = ckv_out + 4194304L;            // (4,2048,2048)

  char* p = (char*)d_ws;
  auto alloc = [&](size_t bytes) -> void* {
    void* q = (void*)p; p += (bytes + 255) & ~(size_t)255; return q;
  };
  uint16_t* hb     = (uint16_t*)alloc(16777216ULL * 2);  // h bf16
  uint16_t* wcat   = (uint16_t*)alloc(3145728ULL * 2);   // (1536,2048) [wdq;wdkv;Bqt]
  uint16_t* wqr_b  = (uint16_t*)alloc(1048576ULL * 2);
  uint16_t* wkr_b  = (uint16_t*)alloc(4194304ULL * 2);
  uint16_t* wo_b   = (uint16_t*)alloc(4194304ULL * 2);
  uint16_t* wukT   = (uint16_t*)alloc(1048576ULL * 2);   // (512,2048)
  uint16_t* wuqT   = (uint16_t*)alloc(1048576ULL * 2);
  uint16_t* wuvT   = (uint16_t*)alloc(1048576ULL * 2);
  uint16_t* wdqT   = (uint16_t*)alloc(1048576ULL * 2);   // (2048,512)
  uint16_t* T1t    = (uint16_t*)alloc(262144ULL * 2);    // (512,512)
  uint16_t* awoT   = (uint16_t*)alloc(1048576ULL * 2);   // absorbed_w_o^T (2048,512)
  uint16_t* cqpre  = (uint16_t*)alloc(4194304ULL * 2);   // (8192,512) bf16 cq-pre
  float*    sVec   = (float*)alloc(8192ULL * 4);         // per-row rmsnorm scale for cq
  uint16_t* catq   = (uint16_t*)alloc(20971520ULL * 2);  // (8192,2560) [aq|qr]
  uint16_t* catk   = (uint16_t*)alloc(20971520ULL * 2);  // (8192,2560) [ckv|kr]
  uint16_t* ckvT   = (uint16_t*)alloc(4194304ULL * 2);   // 4 x (512,2048)
  uint16_t* o_b    = (uint16_t*)alloc(4194304ULL * 2);   // (8192,512)
  float2*   rtab   = (float2*)alloc(131072ULL * 8);      // 2048x64 (cos,sin)
  float*    tmpS2  = (float*)alloc(4194304ULL * 4);      // (8192,512) fp32 ckv-pre
  float*    tmpB   = (float*)alloc(16777216ULL * 4);     // (8192,2048) scratch
  float*    redT   = (float*)alloc(1048576ULL * 4);      // 4 x (512,512) partials
  float*    redW   = (float*)alloc(4194304ULL * 4);      // 4 x (2048,512) partials
  uint16_t* tmpBb  = (uint16_t*)tmpB;                    // alias: (8192,2048) bf16
  uint16_t* attn   = catq;  // alias: catq dead after scores GEMM

  uint16_t* wdq_b  = wcat;                  // rows 0-511
  uint16_t* wdkv_b = wcat + 1048576;        // rows 512-1023
  uint16_t* Bqt    = wcat + 2097152;        // rows 1024-1535 (absorbed_w_q^T)

  const dim3 b256(256);
  const dim3 b512(512);
  const dim3 tb(32, 8);

  // fused prep: converts (g1 folded into wqr_b) + rope table + weight transposes
  prep_all<<<dim3(32256), b256, 0, stream>>>(
      h, wdq, wdkv, wqr, wkr, wo, g1, wuk, wuq, wuv,
      hb, wdq_b, wdkv_b, wqr_b, wkr_b, wo_b, rtab, wukT, wuqT, wuvT, wdqT);

  // absorbed weights — split-K (z=4, Kc=512) + deterministic reduce
  gemm_bt<0><<<dim3(4, 4, 4), b256, 0, stream>>>(
      wukT, wuqT, redT, 512, 2048, 2048, 512, 512L, 512L, 262144L);
  reduceK<<<dim3(256), b256, 0, stream>>>(redT, T1t, 262144L, 4, 262144L);
  gemm_bt<0><<<dim3(16, 4, 4), b256, 0, stream>>>(
      wo_b, wuvT, redW, 512, 2048, 2048, 512, 512L, 512L, 1048576L);
  reduceK<<<dim3(1024), b256, 0, stream>>>(redW, awoT, 1048576L, 4, 1048576L);
  gemm_bt<1><<<dim3(4, 16, 1), b256, 0, stream>>>(T1t, wdqT, Bqt, 512, 512, 512, 2048, 0, 0, 0);

  // fused: [cq-pre(bf16) | ckv-pre(fp32) | aq(bf16)] = h @ [wdq; wdkv; Bqt]^T
  gemm256v3<2><<<dim3(32, 6, 1), b512, 0, stream>>>(
      hb, wcat, cqpre, tmpS2, catq, 2048, 2048, 2048, 0, 0, 0, 0, 2);
  // fused norms: cq scale vector + full ckv rmsnorm
  norm_pair<<<dim3(16384), b256, 0, stream>>>(cqpre, sVec, tmpS2, g2, ckv_out, catk);
  // qr = rope(s * (cqpre @ (wqr*g1)^T)) fused in epilogue -> catq[:,512:]
  gemm256v3<4><<<dim3(32, 8, 1), b512, 0, stream>>>(
      cqpre, wqr_b, catq, rtab, sVec, 512, 512, 512, 2560, 0, 0, 0, 4);
  // ckvT: 4 x (512,2048) from catk cols 0..511
  transpose_to_bf16<uint16_t><<<dim3(16, 64, 4), tb, 0, stream>>>(
      catk, ckvT, 2560, 2048, 2048L * 2560, 512L * 2048);
  // kr = rope(h @ wkr^T) fused in epilogue -> catk[:,512:] + kr_out (fp32)
  gemm256v3<5><<<dim3(32, 8, 1), b512, 0, stream>>>(
      hb, wkr_b, catk, rtab, kr_out, 2048, 2048, 2048, 2560, 0, 0, 0, 4);
  // scores[b]/12 = (catq_b @ catk_b^T)/12 -> tmpBb bf16 (K=2560)
  gemm256v3<3><<<dim3(8, 8, 4), b512, 0, stream>>>(
      catq, catk, tmpBb, nullptr, nullptr, 2560, 2560, 2560, 2048,
      5242880L, 5242880L, 4194304L, 2);
  // softmax -> attn bf16 (aliases catq)
  softmax_k<<<dim3(8192), b256, 0, stream>>>(tmpBb, attn);
  // o[b] = attn_b @ ckv_b (via ckvT) -> o_b bf16
  gemm256<1><<<dim3(8, 4, 4), b512, 0, stream>>>(
      attn, ckvT, o_b, 2048, 2048, 2048, 512, 4194304L, 1048576L, 1048576L);
  // u = rmsnorm(o @ absorbed_w_o, g3) -> u_out
  gemm256v3<1><<<dim3(32, 8, 1), b512, 0, stream>>>(
      o_b, awoT, tmpBb, nullptr, nullptr, 512, 512, 512, 2048, 0, 0, 0, 4);
  rmsnorm_k<8, uint16_t><<<dim3(8192), b256, 0, stream>>>(tmpBb, g3, u_out, nullptr, 0);
}

// Round 14
// 451.541 us; speedup vs baseline: 1.2447x; 1.0249x over previous
//
#include <hip/hip_runtime.h>
#include <stdint.h>

// ---------- small helpers ----------
typedef __attribute__((ext_vector_type(8))) short bf16x8;
typedef __attribute__((ext_vector_type(8))) unsigned short u16x8;
typedef __attribute__((ext_vector_type(4))) float floatx4;

__device__ __forceinline__ uint16_t f2bf(float f) {
  union { float f; uint32_t u; } v; v.f = f;
  uint32_t r = v.u + 0x7fffu + ((v.u >> 16) & 1u);
  return (uint16_t)(r >> 16);
}
__device__ __forceinline__ float bf2f(uint16_t b) {
  union { uint32_t u; float f; } v; v.u = ((uint32_t)b) << 16;
  return v.f;
}
__device__ __forceinline__ float ld_as_float(float v) { return v; }
__device__ __forceinline__ float ld_as_float(uint16_t v) { return bf2f(v); }

__device__ __forceinline__ void mfma16(floatx4& d, bf16x8 a, bf16x8 b) {
  asm("v_mfma_f32_16x16x32_bf16 %0, %1, %2, %0" : "+v"(d) : "v"(a), "v"(b));
}

#define FENCE() asm volatile("" ::: "memory")
#define SCHED() __builtin_amdgcn_sched_barrier(0)
#define SBAR()                                  \
  do {                                          \
    FENCE();                                    \
    __builtin_amdgcn_sched_barrier(0);          \
    __builtin_amdgcn_s_barrier();               \
    __builtin_amdgcn_sched_barrier(0);          \
    FENCE();                                    \
  } while (0)

// ================= v5 GEMM: 256x256, BK=32, 4-slot ring, cross-tile reg prefetch =================
// C(M,N) = A(M,K) @ B(N,K)^T, bf16 in, fp32 acc. Requires K % 32 == 0, K >= 128.
// 512 threads = 8 waves (2M x 4N), per-wave 128x64 output (8x4 frags).
// LDS: 4 slots x (A 16KB + B 16KB) = 128 KB. Tile t in slot t%4, staging depth 3.
// Schedule (r11): every MFMA cluster consumes registers read >=1 phase earlier.
// Chunk-XOR swizzle (both sides, same involution; r7-verified conflicts=0).
// XCD mapping: 1D 8-way swizzle + swzG 2D supertile shaping (r10: -33% FETCH).
// MODE 0: fp32 C0; 1: bf16 C0; 2: routed (cols 0-511 bf16 C0 ld512 cq-pre,
//   512-1023 fp32 C1 ld512 ckv-pre, 1024-1535 bf16 C2 ld2560 aq);
// 3: bf16 C0 with fused *(1/12) scale;
// 4: RoPE epilogue -> bf16 C0[row*2560 + 512 + c]; C1v = rope table;
//    C2v = optional per-row fp32 scale vector s (rmsnorm fold, applied pre-rotation).
// 5: RoPE epilogue -> bf16 C0[row*2560 + 512 + c] AND fp32 C2v[row*2048 + c].
template<int MODE>
__global__ void __launch_bounds__(512, 1) gemm256v3(
    const uint16_t* __restrict__ A, const uint16_t* __restrict__ B,
    void* __restrict__ C0v, void* __restrict__ C1v, void* __restrict__ C2v,
    int K, int lda, int ldb, int ldc,
    long sA, long sB, long sC, int swzG)
{
  __shared__ __attribute__((aligned(16))) char lds[131072];
  const int tid = threadIdx.x;
  const int w = tid >> 6, l = tid & 63;
  const int wm = w >> 2, wn = w & 3;

  const int gx = gridDim.x;
  const int nwg = gx * gridDim.y;
  int id = blockIdx.y * gx + blockIdx.x;
  if ((nwg & 7) == 0) id = (id & 7) * (nwg >> 3) + (id >> 3);
  const int grp = gx * swzG;
  const int ing = id % grp;
  const long bm = (long)(ing / swzG) * 256;
  const long bn = ((long)(id / grp) * swzG + (ing % swzG)) * 256;
  A += (long)blockIdx.z * sA;
  B += (long)blockIdx.z * sB;

  const int scol = (((l & 3) ^ ((l >> 3) & 3)) << 3);  // pre-swizzled source chunk
  const uint16_t* gA = A + (bm + w * 16 + (l >> 2)) * (long)lda + scol;
  const uint16_t* gB = B + (bn + w * 16 + (l >> 2)) * (long)ldb + scol;
  const int ldsw = w * 1024;

#define STG_A3(slot, k0, r)                                                    \
  __builtin_amdgcn_global_load_lds(gA + (k0) + (long)(r) * 128 * lda,          \
      (uint16_t*)(lds + (slot) * 32768 + (r) * 8192 + ldsw), 16, 0, 0)
#define STG_B3(slot, k0, r)                                                    \
  __builtin_amdgcn_global_load_lds(gB + (k0) + (long)(r) * 128 * ldb,          \
      (uint16_t*)(lds + (slot) * 32768 + 16384 + (r) * 8192 + ldsw), 16, 0, 0)

  const int lr = l & 15;
  const int chunkx = (((l >> 4) ^ ((lr >> 1) & 3)) << 4);  // bytes
  const int aoff = (wm * 128 + lr) * 64 + chunkx;
  const int boff = 16384 + (wn * 64 + lr) * 64 + chunkx;

  floatx4 acc[8][4];
#pragma unroll
  for (int i = 0; i < 8; i++)
#pragma unroll
    for (int j = 0; j < 4; j++) acc[i][j] = (floatx4){0.f, 0.f, 0.f, 0.f};

  const int nt = K >> 5;  // assumes nt >= 4
#pragma unroll
  for (int tt = 0; tt < 3; tt++) {
    STG_A3(tt, tt * 32, 0); STG_A3(tt, tt * 32, 1);
    STG_B3(tt, tt * 32, 0); STG_B3(tt, tt * 32, 1);
  }
  asm volatile("s_waitcnt vmcnt(8)" ::: "memory");  // tile 0 landed
  SBAR();

  bf16x8 Bf[4], Bfn[4], Af0[4], Af1[4];
#pragma unroll
  for (int j = 0; j < 4; j++) Bf[j] = *(const bf16x8*)(lds + boff + j * 1024);
#pragma unroll
  for (int i = 0; i < 4; i++) Af0[i] = *(const bf16x8*)(lds + aoff + i * 1024);

  for (int t = 0; t < nt; t++) {
    const char* Ls = lds + (t & 3) * 32768;
    const char* Ln = lds + ((t + 1) & 3) * 32768;
    const long pk0 = (long)(t + 3) << 5;
    const int pslot = (t + 3) & 3;
    const bool pf = (t + 3 < nt);

    // ---- phase 1: read Af1(t), stage (t+3) A, MFMA on Af0(t) x Bf(t) ----
#pragma unroll
    for (int i = 0; i < 4; i++) Af1[i] = *(const bf16x8*)(Ls + aoff + (4 + i) * 1024);
    SCHED();
    if (pf) { STG_A3(pslot, pk0, 0); STG_A3(pslot, pk0, 1); }
    asm volatile("s_waitcnt lgkmcnt(4)" ::: "memory");
    SCHED();
    __builtin_amdgcn_s_setprio(1);
#pragma unroll
    for (int i = 0; i < 4; i++)
#pragma unroll
      for (int j = 0; j < 4; j++) mfma16(acc[i][j], Af0[i], Bf[j]);
    __builtin_amdgcn_s_setprio(0);
    SCHED();

    // ---- mid: retire t+1 staging (counted), drain Af1 reads, fence ----
    if (t + 3 < nt)      asm volatile("s_waitcnt vmcnt(6)" ::: "memory");
    else if (t + 2 < nt) asm volatile("s_waitcnt vmcnt(4)" ::: "memory");
    else if (t + 1 < nt) asm volatile("s_waitcnt vmcnt(0)" ::: "memory");
    asm volatile("s_waitcnt lgkmcnt(0)" ::: "memory");
    SBAR();

    // ---- phase 2: read Bf/Af0 of t+1, stage (t+3) B, MFMA Af1 x Bf ----
    if (t + 1 < nt) {
#pragma unroll
      for (int j = 0; j < 4; j++) Bfn[j] = *(const bf16x8*)(Ln + boff + j * 1024);
#pragma unroll
      for (int i = 0; i < 4; i++) Af0[i] = *(const bf16x8*)(Ln + aoff + i * 1024);
    }
    SCHED();
    if (pf) { STG_B3(pslot, pk0, 0); STG_B3(pslot, pk0, 1); }
    SCHED();
    __builtin_amdgcn_s_setprio(1);
#pragma unroll
    for (int i = 0; i < 4; i++)
#pragma unroll
      for (int j = 0; j < 4; j++) mfma16(acc[4 + i][j], Af1[i], Bf[j]);
    __builtin_amdgcn_s_setprio(0);
    SCHED();
#pragma unroll
    for (int j = 0; j < 4; j++) Bf[j] = Bfn[j];
  }
#undef STG_A3
#undef STG_B3

  const long crow = bm + wm * 128 + ((l >> 4) * 4);
  const long ccol = bn + wn * 64 + (l & 15);
  if constexpr (MODE == 0) {
    float* C = (float*)C0v + (long)blockIdx.z * sC;
#pragma unroll
    for (int i = 0; i < 8; i++)
#pragma unroll
      for (int r = 0; r < 4; r++) {
        long row = crow + i * 16 + r;
#pragma unroll
        for (int j = 0; j < 4; j++) C[row * (long)ldc + ccol + j * 16] = acc[i][j][r];
      }
  } else if constexpr (MODE == 1) {
    uint16_t* C = (uint16_t*)C0v + (long)blockIdx.z * sC;
#pragma unroll
    for (int i = 0; i < 8; i++)
#pragma unroll
      for (int r = 0; r < 4; r++) {
        long row = crow + i * 16 + r;
#pragma unroll
        for (int j = 0; j < 4; j++) C[row * (long)ldc + ccol + j * 16] = f2bf(acc[i][j][r]);
      }
  } else if constexpr (MODE == 3) {
    const float s = 1.0f / 12.0f;
    uint16_t* C = (uint16_t*)C0v + (long)blockIdx.z * sC;
#pragma unroll
    for (int i = 0; i < 8; i++)
#pragma unroll
      for (int r = 0; r < 4; r++) {
        long row = crow + i * 16 + r;
#pragma unroll
        for (int j = 0; j < 4; j++) C[row * (long)ldc + ccol + j * 16] = f2bf(acc[i][j][r] * s);
      }
  } else if constexpr (MODE == 4 || MODE == 5) {
    const float2* __restrict__ tab = (const float2*)C1v;
    uint16_t* Cb = (uint16_t*)C0v;
    const float* __restrict__ S = (MODE == 4) ? (const float*)C2v : nullptr;
    float* Cf = (MODE == 5) ? (float*)C2v : nullptr;
    const float sgn = (l & 1) ? 1.0f : -1.0f;
#pragma unroll
    for (int i = 0; i < 8; i++)
#pragma unroll
      for (int r = 0; r < 4; r++) {
        long row = crow + i * 16 + r;
        const float2* trow = tab + (((int)(row & 2047)) << 6);
        float srow = 1.0f;
        if constexpr (MODE == 4) srow = S ? S[row] : 1.0f;
#pragma unroll
        for (int j = 0; j < 4; j++) {
          long c = ccol + j * 16;
          float v = acc[i][j][r];
          if constexpr (MODE == 4) v *= srow;
          float pp = __shfl_xor(v, 1);
          float2 cs = trow[((int)(c & 127)) >> 1];
          float y = v * cs.x + sgn * pp * cs.y;
          Cb[row * 2560 + 512 + c] = f2bf(y);
          if constexpr (MODE == 5) Cf[row * 2048 + c] = y;
        }
      }
  } else {
    if (bn < 512) {
      uint16_t* C = (uint16_t*)C0v;
#pragma unroll
      for (int i = 0; i < 8; i++)
#pragma unroll
        for (int r = 0; r < 4; r++) {
          long row = crow + i * 16 + r;
#pragma unroll
          for (int j = 0; j < 4; j++) C[row * 512 + ccol + j * 16] = f2bf(acc[i][j][r]);
        }
    } else if (bn < 1024) {
      float* C = (float*)C1v;
      const long cc = ccol - 512;
#pragma unroll
      for (int i = 0; i < 8; i++)
#pragma unroll
        for (int r = 0; r < 4; r++) {
          long row = crow + i * 16 + r;
#pragma unroll
          for (int j = 0; j < 4; j++) C[row * 512 + cc + j * 16] = acc[i][j][r];
        }
    } else {
      uint16_t* C = (uint16_t*)C2v;
      const long cc = ccol - 1024;
#pragma unroll
      for (int i = 0; i < 8; i++)
#pragma unroll
        for (int r = 0; r < 4; r++) {
          long row = crow + i * 16 + r;
#pragma unroll
          for (int j = 0; j < 4; j++) C[row * 2560 + cc + j * 16] = f2bf(acc[i][j][r]);
        }
    }
  }
}

// ================= 256x128 pipelined GEMM (for the small-N o GEMM) =================
template<int OUTB>
__global__ void __launch_bounds__(512, 2) gemm256(
    const uint16_t* __restrict__ A, const uint16_t* __restrict__ B,
    void* __restrict__ Cv, int K, int lda, int ldb, int ldc,
    long sA, long sB, long sC)
{
  __shared__ __attribute__((aligned(16))) char lds[147456];
  const int tid = threadIdx.x;
  const int w = tid >> 6, l = tid & 63;
  const int wm = w >> 1, wn = w & 1;

  const int gx = gridDim.x;
  const int nwg = gx * gridDim.y;
  int id = blockIdx.y * gx + blockIdx.x;
  if ((nwg & 7) == 0) id = (id & 7) * (nwg >> 3) + (id >> 3);
  const long bm = (long)(id % gx) * 256;
  const long bn = (long)(id / gx) * 128;
  A += (long)blockIdx.z * sA;
  B += (long)blockIdx.z * sB;

  const int sr = l >> 3;
  const int sc = l & 7;
  const int scol = ((sc ^ sr) << 3);
  const uint16_t* gA = A + (bm + w * 8 + sr) * (long)lda + scol;
  const uint16_t* gB = B + (bn + w * 8 + sr) * (long)ldb + scol;
  const int ldsw = w * 1024;

#define STAGE_A(bufi, k0, r)                                                     \
  __builtin_amdgcn_global_load_lds(gA + (k0) + (long)(r) * 64 * lda,             \
      (uint16_t*)(lds + (bufi) * 49152 + (r) * 8192 + ldsw), 16, 0, 0)
#define STAGE_B(bufi, k0, r)                                                     \
  __builtin_amdgcn_global_load_lds(gB + (k0) + (long)(r) * 64 * ldb,             \
      (uint16_t*)(lds + (bufi) * 49152 + 32768 + (r) * 8192 + ldsw), 16, 0, 0)

  const int lr = l & 15;
  const int kk = (l >> 4) << 4;
  const int msk = (l & 7) << 4;
  const int ko0 = kk ^ msk;
  const int ko1 = (64 + kk) ^ msk;
  const int arow = (wm * 64 + lr) * 128;
  const int brow = (wn * 64 + lr) * 128;

  floatx4 acc[4][4];
#pragma unroll
  for (int i = 0; i < 4; i++)
#pragma unroll
    for (int j = 0; j < 4; j++) acc[i][j] = (floatx4){0.f, 0.f, 0.f, 0.f};

  const int nt = K >> 6;
#pragma unroll
  for (int r = 0; r < 4; r++) STAGE_A(0, 0, r);
#pragma unroll
  for (int r = 0; r < 2; r++) STAGE_B(0, 0, r);
#pragma unroll
  for (int r = 0; r < 4; r++) STAGE_A(1, 64, r);
#pragma unroll
  for (int r = 0; r < 2; r++) STAGE_B(1, 64, r);
  asm volatile("s_waitcnt vmcnt(6)" ::: "memory");
  SBAR();

  bf16x8 af0[4], bf0[4], af1[4], bf1[4];
  {
    const char* LA = lds + arow;
    const char* LB = lds + 32768 + brow;
#pragma unroll
    for (int i = 0; i < 4; i++) af0[i] = *(const bf16x8*)(LA + i * 2048 + ko0);
#pragma unroll
    for (int j = 0; j < 4; j++) bf0[j] = *(const bf16x8*)(LB + j * 2048 + ko0);
  }

  for (int t = 0; t < nt; t++) {
    const int buf = t % 3;
    const int pbuf = (t + 2) % 3;
    const long pk0 = (long)(t + 2) << 6;
    const char* LA = lds + buf * 49152 + arow;
    const char* LB = lds + buf * 49152 + 32768 + brow;
    const bool pf = (t + 2 < nt);

    if (pf) { STAGE_A(pbuf, pk0, 0); STAGE_A(pbuf, pk0, 1); STAGE_B(pbuf, pk0, 0); }
#pragma unroll
    for (int i = 0; i < 4; i++) af1[i] = *(const bf16x8*)(LA + i * 2048 + ko1);
#pragma unroll
    for (int j = 0; j < 4; j++) bf1[j] = *(const bf16x8*)(LB + j * 2048 + ko1);
    SCHED();
    __builtin_amdgcn_s_setprio(1);
#pragma unroll
    for (int i = 0; i < 4; i++)
#pragma unroll
      for (int j = 0; j < 4; j++) mfma16(acc[i][j], af0[i], bf0[j]);
    __builtin_amdgcn_s_setprio(0);
    SCHED();

    if (pf) { STAGE_A(pbuf, pk0, 2); STAGE_A(pbuf, pk0, 3); STAGE_B(pbuf, pk0, 1); }
    if (t < nt - 2) asm volatile("s_waitcnt vmcnt(6) lgkmcnt(0)" ::: "memory");
    else            asm volatile("s_waitcnt vmcnt(0) lgkmcnt(0)" ::: "memory");
    SBAR();
    if (t < nt - 1) {
      const char* LAn = lds + ((t + 1) % 3) * 49152 + arow;
      const char* LBn = lds + ((t + 1) % 3) * 49152 + 32768 + brow;
#pragma unroll
      for (int i = 0; i < 4; i++) af0[i] = *(const bf16x8*)(LAn + i * 2048 + ko0);
#pragma unroll
      for (int j = 0; j < 4; j++) bf0[j] = *(const bf16x8*)(LBn + j * 2048 + ko0);
    }
    SCHED();
    __builtin_amdgcn_s_setprio(1);
#pragma unroll
    for (int i = 0; i < 4; i++)
#pragma unroll
      for (int j = 0; j < 4; j++) mfma16(acc[i][j], af1[i], bf1[j]);
    __builtin_amdgcn_s_setprio(0);
    SCHED();
  }
#undef STAGE_A
#undef STAGE_B

  const long crow = bm + wm * 64 + ((l >> 4) * 4);
  const long ccol = bn + wn * 64 + (l & 15);
  if constexpr (OUTB == 0) {
    float* C = (float*)Cv + (long)blockIdx.z * sC;
#pragma unroll
    for (int i = 0; i < 4; i++)
#pragma unroll
      for (int r = 0; r < 4; r++) {
        long row = crow + i * 16 + r;
#pragma unroll
        for (int j = 0; j < 4; j++) C[row * (long)ldc + ccol + j * 16] = acc[i][j][r];
      }
  } else {
    uint16_t* C = (uint16_t*)Cv + (long)blockIdx.z * sC;
#pragma unroll
    for (int i = 0; i < 4; i++)
#pragma unroll
      for (int r = 0; r < 4; r++) {
        long row = crow + i * 16 + r;
#pragma unroll
        for (int j = 0; j < 4; j++) C[row * (long)ldc + ccol + j * 16] = f2bf(acc[i][j][r]);
      }
  }
}

// ================= routed prep GEMM: T1t partials (x<4) + awoT partials (x>=4) =================
// 128x128 tile, 256 thr; split-K over z (Kc=512). fp32 partial outputs.
// T1t: A=wukT, B=wuqT, C=redT (ldc 512, sC 262144)
// awoT: A=wo_b, B=wuvT, C=redW (ldc 512, sC 1048576)
__global__ void __launch_bounds__(256) gemm_prep(
    const uint16_t* __restrict__ wukT, const uint16_t* __restrict__ wuqT,
    const uint16_t* __restrict__ wo_b, const uint16_t* __restrict__ wuvT,
    float* __restrict__ redT, float* __restrict__ redW)
{
  __shared__ alignas(16) uint16_t As[4096];
  __shared__ alignas(16) uint16_t Bs[4096];
  const int tid = threadIdx.x;
  const int w = tid >> 6, l = tid & 63;
  const int wr = w >> 1, wc = w & 1;

  const bool isT1 = (blockIdx.x < 4);
  const long bm = (long)(isT1 ? blockIdx.x : (blockIdx.x - 4)) * 128;
  const long bn = (long)blockIdx.y * 128;
  const uint16_t* A = (isT1 ? wukT : wo_b) + (long)blockIdx.z * 512;
  const uint16_t* B = (isT1 ? wuqT : wuvT) + (long)blockIdx.z * 512;
  float* C = (isT1 ? redT : redW) + (long)blockIdx.z * (isT1 ? 262144L : 1048576L);
  const int lda = 2048, ldb = 2048, ldc = 512;

  const uint16_t* ga0 = A + (bm + w * 16 + (l >> 2)) * (long)lda + (l & 3) * 8;
  const uint16_t* ga1 = ga0 + 64L * lda;
  const uint16_t* gb0 = B + (bn + w * 16 + (l >> 2)) * (long)ldb + (l & 3) * 8;
  const uint16_t* gb1 = gb0 + 64L * ldb;
  uint16_t* la0 = &As[w * 512];
  uint16_t* la1 = &As[2048 + w * 512];
  uint16_t* lb0 = &Bs[w * 512];
  uint16_t* lb1 = &Bs[2048 + w * 512];

  floatx4 acc[4][4];
#pragma unroll
  for (int i = 0; i < 4; i++)
#pragma unroll
    for (int j = 0; j < 4; j++) acc[i][j] = (floatx4){0.f, 0.f, 0.f, 0.f};

  const int rA = (wr * 64 + (l & 15)) * 32 + (l >> 4) * 8;
  const int rB = (wc * 64 + (l & 15)) * 32 + (l >> 4) * 8;

  for (int k0 = 0; k0 < 512; k0 += 32) {
    __builtin_amdgcn_global_load_lds(ga0, la0, 16, 0, 0);
    __builtin_amdgcn_global_load_lds(ga1, la1, 16, 0, 0);
    __builtin_amdgcn_global_load_lds(gb0, lb0, 16, 0, 0);
    __builtin_amdgcn_global_load_lds(gb1, lb1, 16, 0, 0);
    ga0 += 32; ga1 += 32; gb0 += 32; gb1 += 32;
    __syncthreads();
    bf16x8 af[4], bfr[4];
#pragma unroll
    for (int i = 0; i < 4; i++) af[i] = *(const bf16x8*)&As[rA + i * 512];
#pragma unroll
    for (int j = 0; j < 4; j++) bfr[j] = *(const bf16x8*)&Bs[rB + j * 512];
#pragma unroll
    for (int i = 0; i < 4; i++)
#pragma unroll
      for (int j = 0; j < 4; j++) mfma16(acc[i][j], af[i], bfr[j]);
    __syncthreads();
  }

  const long crow = bm + wr * 64 + ((l >> 4) * 4);
  const long ccol = bn + wc * 64 + (l & 15);
#pragma unroll
  for (int i = 0; i < 4; i++)
#pragma unroll
    for (int r = 0; r < 4; r++) {
      long row = crow + i * 16 + r;
#pragma unroll
      for (int j = 0; j < 4; j++) C[row * (long)ldc + ccol + j * 16] = acc[i][j][r];
    }
}

// ================= legacy 128x128 GEMM (Bqt only) =================
template<int OUTB>
__global__ void __launch_bounds__(256) gemm_bt(
    const uint16_t* __restrict__ A, const uint16_t* __restrict__ B,
    void* __restrict__ Cv, int K, int lda, int ldb, int ldc,
    long sA, long sB, long sC)
{
  __shared__ alignas(16) uint16_t As[4096];
  __shared__ alignas(16) uint16_t Bs[4096];
  const int tid = threadIdx.x;
  const int w = tid >> 6, l = tid & 63;
  const int wr = w >> 1, wc = w & 1;
  const long bm = (long)blockIdx.x * 128, bn = (long)blockIdx.y * 128;
  A += (long)blockIdx.z * sA;
  B += (long)blockIdx.z * sB;

  const uint16_t* ga0 = A + (bm + w * 16 + (l >> 2)) * (long)lda + (l & 3) * 8;
  const uint16_t* ga1 = ga0 + 64L * lda;
  const uint16_t* gb0 = B + (bn + w * 16 + (l >> 2)) * (long)ldb + (l & 3) * 8;
  const uint16_t* gb1 = gb0 + 64L * ldb;
  uint16_t* la0 = &As[w * 512];
  uint16_t* la1 = &As[2048 + w * 512];
  uint16_t* lb0 = &Bs[w * 512];
  uint16_t* lb1 = &Bs[2048 + w * 512];

  floatx4 acc[4][4];
#pragma unroll
  for (int i = 0; i < 4; i++)
#pragma unroll
    for (int j = 0; j < 4; j++) acc[i][j] = (floatx4){0.f, 0.f, 0.f, 0.f};

  const int rA = (wr * 64 + (l & 15)) * 32 + (l >> 4) * 8;
  const int rB = (wc * 64 + (l & 15)) * 32 + (l >> 4) * 8;

  for (int k0 = 0; k0 < K; k0 += 32) {
    __builtin_amdgcn_global_load_lds(ga0, la0, 16, 0, 0);
    __builtin_amdgcn_global_load_lds(ga1, la1, 16, 0, 0);
    __builtin_amdgcn_global_load_lds(gb0, lb0, 16, 0, 0);
    __builtin_amdgcn_global_load_lds(gb1, lb1, 16, 0, 0);
    ga0 += 32; ga1 += 32; gb0 += 32; gb1 += 32;
    __syncthreads();
    bf16x8 af[4], bfr[4];
#pragma unroll
    for (int i = 0; i < 4; i++) af[i] = *(const bf16x8*)&As[rA + i * 512];
#pragma unroll
    for (int j = 0; j < 4; j++) bfr[j] = *(const bf16x8*)&Bs[rB + j * 512];
#pragma unroll
    for (int i = 0; i < 4; i++)
#pragma unroll
      for (int j = 0; j < 4; j++) mfma16(acc[i][j], af[i], bfr[j]);
    __syncthreads();
  }

  const long crow = bm + wr * 64 + ((l >> 4) * 4);
  const long ccol = bn + wc * 64 + (l & 15);
  if constexpr (OUTB == 0) {
    float* C = (float*)Cv + (long)blockIdx.z * sC;
#pragma unroll
    for (int i = 0; i < 4; i++)
#pragma unroll
      for (int r = 0; r < 4; r++) {
        long row = crow + i * 16 + r;
#pragma unroll
        for (int j = 0; j < 4; j++) C[row * (long)ldc + ccol + j * 16] = acc[i][j][r];
      }
  } else {
    uint16_t* C = (uint16_t*)Cv + (long)blockIdx.z * sC;
#pragma unroll
    for (int i = 0; i < 4; i++)
#pragma unroll
      for (int r = 0; r < 4; r++) {
        long row = crow + i * 16 + r;
#pragma unroll
        for (int j = 0; j < 4; j++) C[row * (long)ldc + ccol + j * 16] = f2bf(acc[i][j][r]);
      }
  }
}

// ---------- merged split-K reduce: blocks 0..255 -> T1t; 256..1279 -> awoT ----------
__global__ void __launch_bounds__(256) reduce2(
    const float* __restrict__ redT, uint16_t* __restrict__ T1t,
    const float* __restrict__ redW, uint16_t* __restrict__ awoT)
{
  const int b = blockIdx.x;
  const float* in; uint16_t* out; long i, stride;
  if (b < 256) { in = redT; out = T1t; i = ((long)b * 256 + threadIdx.x) * 4; stride = 262144L; }
  else         { in = redW; out = awoT; i = ((long)(b - 256) * 256 + threadIdx.x) * 4; stride = 1048576L; }
  float4 s = *(const float4*)(in + i);
  for (int k = 1; k < 4; k++) {
    float4 t = *(const float4*)(in + k * stride + i);
    s.x += t.x; s.y += t.y; s.z += t.z; s.w += t.w;
  }
  ushort4 o; o.x = f2bf(s.x); o.y = f2bf(s.y); o.z = f2bf(s.z); o.w = f2bf(s.w);
  *(ushort4*)(out + i) = o;
}

// ---------- fused prep: h/weight converts + g1-folded wqr + rope table + transposes ----------
__global__ void __launch_bounds__(256) prep_all(
    const float* __restrict__ h,
    const float* __restrict__ wdq, const float* __restrict__ wdkv,
    const float* __restrict__ wqr, const float* __restrict__ wkr,
    const float* __restrict__ wo, const float* __restrict__ g1,
    const float* __restrict__ wuk, const float* __restrict__ wuq,
    const float* __restrict__ wuv,
    uint16_t* __restrict__ hb,
    uint16_t* __restrict__ wdq_b, uint16_t* __restrict__ wdkv_b,
    uint16_t* __restrict__ wqr_b, uint16_t* __restrict__ wkr_b,
    uint16_t* __restrict__ wo_b, float2* __restrict__ rtab,
    uint16_t* __restrict__ wukT, uint16_t* __restrict__ wuqT,
    uint16_t* __restrict__ wuvT, uint16_t* __restrict__ wdqT)
{
  const int b = blockIdx.x;
  if (b < 27648) {
    if (b >= 18432 && b < 19456) {  // wqr with g1 fold
      long i = ((long)(b - 18432) * 256 + threadIdx.x) * 4;
      float4 v = *(const float4*)(wqr + i);
      int c = (int)(i & 511);
      float4 g = *(const float4*)(g1 + c);
      ushort4 o;
      o.x = f2bf(v.x * g.x); o.y = f2bf(v.y * g.y);
      o.z = f2bf(v.z * g.z); o.w = f2bf(v.w * g.w);
      *(ushort4*)(wqr_b + i) = o;
      return;
    }
    const float* src; uint16_t* dst; long off;
    if (b < 16384)      { src = h;    dst = hb;     off = b; }
    else if (b < 17408) { src = wdq;  dst = wdq_b;  off = b - 16384; }
    else if (b < 18432) { src = wdkv; dst = wdkv_b; off = b - 17408; }
    else if (b < 23552) { src = wkr;  dst = wkr_b;  off = b - 19456; }
    else                { src = wo;   dst = wo_b;   off = b - 23552; }
    long i = (off * 256 + threadIdx.x) * 4;
    float4 v = *(const float4*)(src + i);
    ushort4 o; o.x = f2bf(v.x); o.y = f2bf(v.y); o.z = f2bf(v.z); o.w = f2bf(v.w);
    *(ushort4*)(dst + i) = o;
  } else if (b < 28160) {
    int idx = (b - 27648) * 256 + threadIdx.x;
    int s = idx >> 6, fi = idx & 63;
    float f = powf(10000.0f, -(float)fi * (1.0f / 64.0f));
    float ang = (float)s * f;
    rtab[idx] = make_float2(cosf(ang), sinf(ang));
  } else {
    __shared__ float tile[32][33];
    const int bt = b - 28160;
    const int tx = threadIdx.x & 31, ty = threadIdx.x >> 5;
    const float* in; uint16_t* out; int ld_in, ld_out, rb, cb;
    if (bt < 3072) {
      const int op = bt >> 10, rem = bt & 1023;
      in = (op == 0) ? wuk : (op == 1) ? wuq : wuv;
      out = (op == 0) ? wukT : (op == 1) ? wuqT : wuvT;
      ld_in = 512; ld_out = 2048;
      cb = (rem & 15) * 32; rb = (rem >> 4) * 32;
    } else {
      const int rem = bt - 3072;
      in = wdq; out = wdqT; ld_in = 2048; ld_out = 512;
      cb = (rem & 63) * 32; rb = (rem >> 6) * 32;
    }
#pragma unroll
    for (int i = 0; i < 32; i += 8)
      tile[ty + i][tx] = in[(long)(rb + ty + i) * ld_in + cb + tx];
    __syncthreads();
#pragma unroll
    for (int i = 0; i < 32; i += 8)
      out[(long)(cb + ty + i) * ld_out + rb + tx] = f2bf(tile[tx][ty + i]);
  }
}

// ---------- transpose (R,Cc) -> (Cc,R), bf16 out (used for ckvT) ----------
template<typename TIN>
__global__ void __launch_bounds__(256) transpose_to_bf16(
    const TIN* __restrict__ in, uint16_t* __restrict__ out,
    int ld_in, int ld_out, long sIn, long sOut)
{
  __shared__ float tile[32][33];
  in += (long)blockIdx.z * sIn;
  out += (long)blockIdx.z * sOut;
  const int rb = blockIdx.y * 32, cb = blockIdx.x * 32;
#pragma unroll
  for (int i = 0; i < 32; i += 8)
    tile[threadIdx.y + i][threadIdx.x] =
        ld_as_float(in[(long)(rb + threadIdx.y + i) * ld_in + cb + threadIdx.x]);
  __syncthreads();
#pragma unroll
  for (int i = 0; i < 32; i += 8)
    out[(long)(cb + threadIdx.y + i) * ld_out + rb + threadIdx.x] =
        f2bf(tile[threadIdx.x][threadIdx.y + i]);
}

// ---------- fused norms: blocks 0..8191 cq-scale only; 8192..16383 ckv full ----------
__global__ void __launch_bounds__(256) norm_pair(
    const uint16_t* __restrict__ cqpre, float* __restrict__ sVec,
    const float* __restrict__ ckvpre, const float* __restrict__ g2,
    float* __restrict__ ckv_out, uint16_t* __restrict__ catk)
{
  __shared__ float sm[9];
  const int b = blockIdx.x;
  const int base = threadIdx.x * 2;
  float v0, v1;
  if (b < 8192) {
    ushort2 t = *(const ushort2*)&cqpre[(long)b * 512 + base];
    v0 = bf2f(t.x); v1 = bf2f(t.y);
  } else {
    float2 t = *(const float2*)&ckvpre[(long)(b - 8192) * 512 + base];
    v0 = t.x; v1 = t.y;
  }
  float ss = v0 * v0 + v1 * v1;
#pragma unroll
  for (int o = 32; o; o >>= 1) ss += __shfl_down(ss, o);
  if ((threadIdx.x & 63) == 0) sm[threadIdx.x >> 6] = ss;
  __syncthreads();
  if (threadIdx.x == 0)
    sm[8] = rsqrtf((sm[0] + sm[1] + sm[2] + sm[3]) * (1.0f / 512.0f) + 1.1920929e-7f);
  __syncthreads();
  const float sc = sm[8];
  if (b < 8192) {
    if (threadIdx.x == 0) sVec[b] = sc;
  } else {
    const long row = b - 8192;
    float y0 = v0 * sc * g2[base];
    float y1 = v1 * sc * g2[base + 1];
    *(float2*)&ckv_out[row * 512 + base] = make_float2(y0, y1);
    ushort2 o; o.x = f2bf(y0); o.y = f2bf(y1);
    *(ushort2*)&catk[row * 2560 + base] = o;
  }
}

// ---------- rmsnorm: one block per row; DIM = PT*256 (u-norm) ----------
template<int PT, typename TIN>
__global__ void __launch_bounds__(256) rmsnorm_k(
    const TIN* __restrict__ in, const float* __restrict__ g,
    float* __restrict__ out_f, uint16_t* __restrict__ out_b, int ld_b)
{
  constexpr int DIM = PT * 256;
  __shared__ float sm[9];
  const TIN* x = in + (long)blockIdx.x * DIM;
  const int base = threadIdx.x * PT;
  float v[PT];
  if constexpr (sizeof(TIN) == 2) {
#pragma unroll
    for (int i = 0; i < PT; i += 8) {
      u16x8 t = *(const u16x8*)&x[base + i];
#pragma unroll
      for (int q = 0; q < 8; q++) v[i + q] = bf2f(t[q]);
    }
  } else {
#pragma unroll
    for (int i = 0; i < PT; i += 4) {
      float4 t = *(const float4*)&x[base + i];
      v[i] = t.x; v[i + 1] = t.y; v[i + 2] = t.z; v[i + 3] = t.w;
    }
  }
  float ss = 0.f;
#pragma unroll
  for (int i = 0; i < PT; i++) ss += v[i] * v[i];
#pragma unroll
  for (int o = 32; o; o >>= 1) ss += __shfl_down(ss, o);
  if ((threadIdx.x & 63) == 0) sm[threadIdx.x >> 6] = ss;
  __syncthreads();
  if (threadIdx.x == 0)
    sm[8] = rsqrtf((sm[0] + sm[1] + sm[2] + sm[3]) * (1.0f / DIM) + 1.1920929e-7f);
  __syncthreads();
  const float sc = sm[8];
#pragma unroll
  for (int i = 0; i < PT; i++) {
    float y = v[i] * sc * g[base + i];
    if (out_f) out_f[(long)blockIdx.x * DIM + base + i] = y;
    if (out_b) out_b[(long)blockIdx.x * ld_b + base + i] = f2bf(y);
  }
}

// ---------- softmax over rows of 2048, bf16 in (pre-scaled), bf16 out ----------
__global__ void __launch_bounds__(256) softmax_k(const uint16_t* __restrict__ sc,
                                                 uint16_t* __restrict__ attn) {
  __shared__ float sm[9];
  const uint16_t* x = sc + ((long)blockIdx.x << 11);
  const int base = threadIdx.x * 8;
  float v[8];
  u16x8 t = *(const u16x8*)&x[base];
#pragma unroll
  for (int i = 0; i < 8; i++) v[i] = bf2f(t[i]);
  float m = -1e30f;
#pragma unroll
  for (int i = 0; i < 8; i++) m = fmaxf(m, v[i]);
#pragma unroll
  for (int o = 32; o; o >>= 1) m = fmaxf(m, __shfl_down(m, o));
  if ((threadIdx.x & 63) == 0) sm[threadIdx.x >> 6] = m;
  __syncthreads();
  if (threadIdx.x == 0)
    sm[8] = fmaxf(fmaxf(sm[0], sm[1]), fmaxf(sm[2], sm[3]));
  __syncthreads();
  m = sm[8];
  __syncthreads();
  float ss = 0.f;
#pragma unroll
  for (int i = 0; i < 8; i++) { v[i] = __expf(v[i] - m); ss += v[i]; }
#pragma unroll
  for (int o = 32; o; o >>= 1) ss += __shfl_down(ss, o);
  if ((threadIdx.x & 63) == 0) sm[threadIdx.x >> 6] = ss;
  __syncthreads();
  if (threadIdx.x == 0) sm[8] = 1.0f / (sm[0] + sm[1] + sm[2] + sm[3]);
  __syncthreads();
  const float r = sm[8];
  ushort4 o1, o2;
  o1.x = f2bf(v[0] * r); o1.y = f2bf(v[1] * r); o1.z = f2bf(v[2] * r); o1.w = f2bf(v[3] * r);
  o2.x = f2bf(v[4] * r); o2.y = f2bf(v[5] * r); o2.z = f2bf(v[6] * r); o2.w = f2bf(v[7] * r);
  uint16_t* dst = attn + ((long)blockIdx.x << 11) + base;
  *(ushort4*)dst = o1;
  *(ushort4*)(dst + 4) = o2;
}

// ---------- orchestration ----------
extern "C" void kernel_launch(void* const* d_in, const int* in_sizes, int n_in,
                              void* d_out, int out_size, void* d_ws, size_t ws_size,
                              hipStream_t stream) {
  (void)in_sizes; (void)n_in; (void)out_size; (void)ws_size;
  const float* h    = (const float*)d_in[0];
  const float* wdkv = (const float*)d_in[1];
  const float* wuk  = (const float*)d_in[2];
  const float* wuv  = (const float*)d_in[3];
  const float* wdq  = (const float*)d_in[4];
  const float* wuq  = (const float*)d_in[5];
  const float* wkr  = (const float*)d_in[6];
  const float* wqr  = (const float*)d_in[7];
  const float* wo   = (const float*)d_in[8];
  const float* g1   = (const float*)d_in[9];
  const float* g2   = (const float*)d_in[10];
  const float* g3   = (const float*)d_in[11];

  float* u_out   = (float*)d_out;                 // (4,2048,2048)
  float* ckv_out = u_out + 16777216L;             // (4,2048,512)
  float* kr_out  = ckv_out + 4194304L;            // (4,2048,2048)

  char* p = (char*)d_ws;
  auto alloc = [&](size_t bytes) -> void* {
    void* q = (void*)p; p += (bytes + 255) & ~(size_t)255; return q;
  };
  uint16_t* hb     = (uint16_t*)alloc(16777216ULL * 2);  // h bf16
  uint16_t* wcat   = (uint16_t*)alloc(3145728ULL * 2);   // (1536,2048) [wdq;wdkv;Bqt]
  uint16_t* wqr_b  = (uint16_t*)alloc(1048576ULL * 2);
  uint16_t* wkr_b  = (uint16_t*)alloc(4194304ULL * 2);
  uint16_t* wo_b   = (uint16_t*)alloc(4194304ULL * 2);
  uint16_t* wukT   = (uint16_t*)alloc(1048576ULL * 2);   // (512,2048)
  uint16_t* wuqT   = (uint16_t*)alloc(1048576ULL * 2);
  uint16_t* wuvT   = (uint16_t*)alloc(1048576ULL * 2);
  uint16_t* wdqT   = (uint16_t*)alloc(1048576ULL * 2);   // (2048,512)
  uint16_t* T1t    = (uint16_t*)alloc(262144ULL * 2);    // (512,512)
  uint16_t* awoT   = (uint16_t*)alloc(1048576ULL * 2);   // absorbed_w_o^T (2048,512)
  uint16_t* cqpre  = (uint16_t*)alloc(4194304ULL * 2);   // (8192,512) bf16 cq-pre
  float*    sVec   = (float*)alloc(8192ULL * 4);         // per-row rmsnorm scale for cq
  uint16_t* catq   = (uint16_t*)alloc(20971520ULL * 2);  // (8192,2560) [aq|qr]
  uint16_t* catk   = (uint16_t*)alloc(20971520ULL * 2);  // (8192,2560) [ckv|kr]
  uint16_t* ckvT   = (uint16_t*)alloc(4194304ULL * 2);   // 4 x (512,2048)
  uint16_t* o_b    = (uint16_t*)alloc(4194304ULL * 2);   // (8192,512)
  float2*   rtab   = (float2*)alloc(131072ULL * 8);      // 2048x64 (cos,sin)
  float*    tmpS2  = (float*)alloc(4194304ULL * 4);      // (8192,512) fp32 ckv-pre
  float*    tmpB   = (float*)alloc(16777216ULL * 4);     // (8192,2048) scratch
  float*    redT   = (float*)alloc(1048576ULL * 4);      // 4 x (512,512) partials
  float*    redW   = (float*)alloc(4194304ULL * 4);      // 4 x (2048,512) partials
  uint16_t* tmpBb  = (uint16_t*)tmpB;                    // alias: (8192,2048) bf16
  uint16_t* attn   = catq;  // alias: catq dead after scores GEMM

  uint16_t* wdq_b  = wcat;                  // rows 0-511
  uint16_t* wdkv_b = wcat + 1048576;        // rows 512-1023
  uint16_t* Bqt    = wcat + 2097152;        // rows 1024-1535 (absorbed_w_q^T)

  const dim3 b256(256);
  const dim3 b512(512);
  const dim3 tb(32, 8);

  // fused prep: converts (g1 folded into wqr_b) + rope table + weight transposes
  prep_all<<<dim3(32256), b256, 0, stream>>>(
      h, wdq, wdkv, wqr, wkr, wo, g1, wuk, wuq, wuv,
      hb, wdq_b, wdkv_b, wqr_b, wkr_b, wo_b, rtab, wukT, wuqT, wuvT, wdqT);

  // absorbed weights — merged split-K prep (T1t + awoT partials), merged reduce, Bqt
  gemm_prep<<<dim3(20, 4, 4), b256, 0, stream>>>(wukT, wuqT, wo_b, wuvT, redT, redW);
  reduce2<<<dim3(1280), b256, 0, stream>>>(redT, T1t, redW, awoT);
  gemm_bt<1><<<dim3(4, 16, 1), b256, 0, stream>>>(T1t, wdqT, Bqt, 512, 512, 512, 2048, 0, 0, 0);

  // fused: [cq-pre(bf16) | ckv-pre(fp32) | aq(bf16)] = h @ [wdq; wdkv; Bqt]^T
  gemm256v3<2><<<dim3(32, 6, 1), b512, 0, stream>>>(
      hb, wcat, cqpre, tmpS2, catq, 2048, 2048, 2048, 0, 0, 0, 0, 2);
  // fused norms: cq scale vector + full ckv rmsnorm
  norm_pair<<<dim3(16384), b256, 0, stream>>>(cqpre, sVec, tmpS2, g2, ckv_out, catk);
  // qr = rope(s * (cqpre @ (wqr*g1)^T)) fused in epilogue -> catq[:,512:]
  gemm256v3<4><<<dim3(32, 8, 1), b512, 0, stream>>>(
      cqpre, wqr_b, catq, rtab, sVec, 512, 512, 512, 2560, 0, 0, 0, 4);
  // ckvT: 4 x (512,2048) from catk cols 0..511
  transpose_to_bf16<uint16_t><<<dim3(16, 64, 4), tb, 0, stream>>>(
      catk, ckvT, 2560, 2048, 2048L * 2560, 512L * 2048);
  // kr = rope(h @ wkr^T) fused in epilogue -> catk[:,512:] + kr_out (fp32)
  gemm256v3<5><<<dim3(32, 8, 1), b512, 0, stream>>>(
      hb, wkr_b, catk, rtab, kr_out, 2048, 2048, 2048, 2560, 0, 0, 0, 4);
  // scores[b]/12 = (catq_b @ catk_b^T)/12 -> tmpBb bf16 (K=2560)
  gemm256v3<3><<<dim3(8, 8, 4), b512, 0, stream>>>(
      catq, catk, tmpBb, nullptr, nullptr, 2560, 2560, 2560, 2048,
      5242880L, 5242880L, 4194304L, 2);
  // softmax -> attn bf16 (aliases catq)
  softmax_k<<<dim3(8192), b256, 0, stream>>>(tmpBb, attn);
  // o[b] = attn_b @ ckv_b (via ckvT) -> o_b bf16
  gemm256<1><<<dim3(8, 4, 4), b512, 0, stream>>>(
      attn, ckvT, o_b, 2048, 2048, 2048, 512, 4194304L, 1048576L, 1048576L);
  // u = rmsnorm(o @ absorbed_w_o, g3) -> u_out
  gemm256v3<1><<<dim3(32, 8, 1), b512, 0, stream>>>(
      o_b, awoT, tmpBb, nullptr, nullptr, 512, 512, 512, 2048, 0, 0, 0, 4);
  rmsnorm_k<8, uint16_t><<<dim3(8192), b256, 0, stream>>>(tmpBb, g3, u_out, nullptr, 0);
}

// Round 15
// 450.880 us; speedup vs baseline: 1.2465x; 1.0015x over previous
//
#include <hip/hip_runtime.h>
#include <stdint.h>

// ---------- small helpers ----------
typedef __attribute__((ext_vector_type(8))) short bf16x8;
typedef __attribute__((ext_vector_type(8))) unsigned short u16x8;
typedef __attribute__((ext_vector_type(4))) float floatx4;

__device__ __forceinline__ uint16_t f2bf(float f) {
  union { float f; uint32_t u; } v; v.f = f;
  uint32_t r = v.u + 0x7fffu + ((v.u >> 16) & 1u);
  return (uint16_t)(r >> 16);
}
__device__ __forceinline__ float bf2f(uint16_t b) {
  union { uint32_t u; float f; } v; v.u = ((uint32_t)b) << 16;
  return v.f;
}
__device__ __forceinline__ float ld_as_float(float v) { return v; }
__device__ __forceinline__ float ld_as_float(uint16_t v) { return bf2f(v); }

__device__ __forceinline__ void mfma16(floatx4& d, bf16x8 a, bf16x8 b) {
  asm("v_mfma_f32_16x16x32_bf16 %0, %1, %2, %0" : "+v"(d) : "v"(a), "v"(b));
}

#define FENCE() asm volatile("" ::: "memory")
#define SCHED() __builtin_amdgcn_sched_barrier(0)
#define SBAR()                                  \
  do {                                          \
    FENCE();                                    \
    __builtin_amdgcn_sched_barrier(0);          \
    __builtin_amdgcn_s_barrier();               \
    __builtin_amdgcn_sched_barrier(0);          \
    FENCE();                                    \
  } while (0)

// ================= v5 GEMM: 256x256, BK=32, 4-slot ring, cross-tile reg prefetch =================
// C(M,N) = A(M,K) @ B(N,K)^T, bf16 in, fp32 acc. Requires K % 32 == 0, K >= 128.
// 512 threads = 8 waves (2M x 4N), per-wave 128x64 output (8x4 frags).
// LDS: 4 slots x (A 16KB + B 16KB) = 128 KB. Tile t in slot t%4, staging depth 3.
// Schedule (r11): every MFMA cluster consumes registers read >=1 phase earlier.
// Chunk-XOR swizzle (both sides, same involution; r7-verified conflicts=0).
// XCD mapping: 1D 8-way swizzle + swzG 2D supertile shaping (r10: -33% FETCH).
// MODE 0: fp32 C0; 1: bf16 C0; 2: routed (cols 0-511 bf16 C0 ld512 cq-pre,
//   512-1023 fp32 C1 ld512 ckv-pre, 1024-1535 bf16 C2 ld2560 aq);
// 3: bf16 C0 with fused *(1/12) scale;
// 4: RoPE epilogue -> bf16 C0[row*2560 + 512 + c]; C1v = rope table;
//    C2v = optional per-row fp32 scale vector s (rmsnorm fold, applied pre-rotation).
// 5: RoPE epilogue -> bf16 C0[row*2560 + 512 + c] AND fp32 C2v[row*2048 + c].
// 6: routed kr/qr (r15): z==0 -> kr: A/B/K as passed (hb, wkr_b, 2048), rope ->
//    catk(C0)+kr_out(C2); z==1 -> qr: A=A2(cqpre), B=B2(wqr_b), K=512, scaled
//    (S2=sVec) rope -> C3v(catq). sA=sB=sC=0 so batch offset is inert.
template<int MODE>
__global__ void __launch_bounds__(512, 1) gemm256v3(
    const uint16_t* __restrict__ A, const uint16_t* __restrict__ B,
    void* __restrict__ C0v, void* __restrict__ C1v, void* __restrict__ C2v,
    int K, int lda, int ldb, int ldc,
    long sA, long sB, long sC, int swzG,
    const uint16_t* __restrict__ A2, const uint16_t* __restrict__ B2,
    void* __restrict__ C3v, const float* __restrict__ S2)
{
  __shared__ __attribute__((aligned(16))) char lds[131072];
  const int tid = threadIdx.x;
  const int w = tid >> 6, l = tid & 63;
  const int wm = w >> 2, wn = w & 3;

  if constexpr (MODE == 6) {
    if (blockIdx.z != 0) { A = A2; B = B2; K = 512; lda = 512; ldb = 512; }
  }

  const int gx = gridDim.x;
  const int nwg = gx * gridDim.y;
  int id = blockIdx.y * gx + blockIdx.x;
  if ((nwg & 7) == 0) id = (id & 7) * (nwg >> 3) + (id >> 3);
  const int grp = gx * swzG;
  const int ing = id % grp;
  const long bm = (long)(ing / swzG) * 256;
  const long bn = ((long)(id / grp) * swzG + (ing % swzG)) * 256;
  A += (long)blockIdx.z * sA;
  B += (long)blockIdx.z * sB;

  const int scol = (((l & 3) ^ ((l >> 3) & 3)) << 3);  // pre-swizzled source chunk
  const uint16_t* gA = A + (bm + w * 16 + (l >> 2)) * (long)lda + scol;
  const uint16_t* gB = B + (bn + w * 16 + (l >> 2)) * (long)ldb + scol;
  const int ldsw = w * 1024;

#define STG_A3(slot, k0, r)                                                    \
  __builtin_amdgcn_global_load_lds(gA + (k0) + (long)(r) * 128 * lda,          \
      (uint16_t*)(lds + (slot) * 32768 + (r) * 8192 + ldsw), 16, 0, 0)
#define STG_B3(slot, k0, r)                                                    \
  __builtin_amdgcn_global_load_lds(gB + (k0) + (long)(r) * 128 * ldb,          \
      (uint16_t*)(lds + (slot) * 32768 + 16384 + (r) * 8192 + ldsw), 16, 0, 0)

  const int lr = l & 15;
  const int chunkx = (((l >> 4) ^ ((lr >> 1) & 3)) << 4);  // bytes
  const int aoff = (wm * 128 + lr) * 64 + chunkx;
  const int boff = 16384 + (wn * 64 + lr) * 64 + chunkx;

  floatx4 acc[8][4];
#pragma unroll
  for (int i = 0; i < 8; i++)
#pragma unroll
    for (int j = 0; j < 4; j++) acc[i][j] = (floatx4){0.f, 0.f, 0.f, 0.f};

  const int nt = K >> 5;  // assumes nt >= 4
#pragma unroll
  for (int tt = 0; tt < 3; tt++) {
    STG_A3(tt, tt * 32, 0); STG_A3(tt, tt * 32, 1);
    STG_B3(tt, tt * 32, 0); STG_B3(tt, tt * 32, 1);
  }
  asm volatile("s_waitcnt vmcnt(8)" ::: "memory");  // tile 0 landed
  SBAR();

  bf16x8 Bf[4], Bfn[4], Af0[4], Af1[4];
#pragma unroll
  for (int j = 0; j < 4; j++) Bf[j] = *(const bf16x8*)(lds + boff + j * 1024);
#pragma unroll
  for (int i = 0; i < 4; i++) Af0[i] = *(const bf16x8*)(lds + aoff + i * 1024);

  for (int t = 0; t < nt; t++) {
    const char* Ls = lds + (t & 3) * 32768;
    const char* Ln = lds + ((t + 1) & 3) * 32768;
    const long pk0 = (long)(t + 3) << 5;
    const int pslot = (t + 3) & 3;
    const bool pf = (t + 3 < nt);

    // ---- phase 1: read Af1(t), stage (t+3) A, MFMA on Af0(t) x Bf(t) ----
#pragma unroll
    for (int i = 0; i < 4; i++) Af1[i] = *(const bf16x8*)(Ls + aoff + (4 + i) * 1024);
    SCHED();
    if (pf) { STG_A3(pslot, pk0, 0); STG_A3(pslot, pk0, 1); }
    asm volatile("s_waitcnt lgkmcnt(4)" ::: "memory");
    SCHED();
    __builtin_amdgcn_s_setprio(1);
#pragma unroll
    for (int i = 0; i < 4; i++)
#pragma unroll
      for (int j = 0; j < 4; j++) mfma16(acc[i][j], Af0[i], Bf[j]);
    __builtin_amdgcn_s_setprio(0);
    SCHED();

    // ---- mid: retire t+1 staging (counted), drain Af1 reads, fence ----
    if (t + 3 < nt)      asm volatile("s_waitcnt vmcnt(6)" ::: "memory");
    else if (t + 2 < nt) asm volatile("s_waitcnt vmcnt(4)" ::: "memory");
    else if (t + 1 < nt) asm volatile("s_waitcnt vmcnt(0)" ::: "memory");
    asm volatile("s_waitcnt lgkmcnt(0)" ::: "memory");
    SBAR();

    // ---- phase 2: read Bf/Af0 of t+1, stage (t+3) B, MFMA Af1 x Bf ----
    if (t + 1 < nt) {
#pragma unroll
      for (int j = 0; j < 4; j++) Bfn[j] = *(const bf16x8*)(Ln + boff + j * 1024);
#pragma unroll
      for (int i = 0; i < 4; i++) Af0[i] = *(const bf16x8*)(Ln + aoff + i * 1024);
    }
    SCHED();
    if (pf) { STG_B3(pslot, pk0, 0); STG_B3(pslot, pk0, 1); }
    SCHED();
    __builtin_amdgcn_s_setprio(1);
#pragma unroll
    for (int i = 0; i < 4; i++)
#pragma unroll
      for (int j = 0; j < 4; j++) mfma16(acc[4 + i][j], Af1[i], Bf[j]);
    __builtin_amdgcn_s_setprio(0);
    SCHED();
#pragma unroll
    for (int j = 0; j < 4; j++) Bf[j] = Bfn[j];
  }
#undef STG_A3
#undef STG_B3

  const long crow = bm + wm * 128 + ((l >> 4) * 4);
  const long ccol = bn + wn * 64 + (l & 15);
  if constexpr (MODE == 0) {
    float* C = (float*)C0v + (long)blockIdx.z * sC;
#pragma unroll
    for (int i = 0; i < 8; i++)
#pragma unroll
      for (int r = 0; r < 4; r++) {
        long row = crow + i * 16 + r;
#pragma unroll
        for (int j = 0; j < 4; j++) C[row * (long)ldc + ccol + j * 16] = acc[i][j][r];
      }
  } else if constexpr (MODE == 1) {
    uint16_t* C = (uint16_t*)C0v + (long)blockIdx.z * sC;
#pragma unroll
    for (int i = 0; i < 8; i++)
#pragma unroll
      for (int r = 0; r < 4; r++) {
        long row = crow + i * 16 + r;
#pragma unroll
        for (int j = 0; j < 4; j++) C[row * (long)ldc + ccol + j * 16] = f2bf(acc[i][j][r]);
      }
  } else if constexpr (MODE == 3) {
    const float s = 1.0f / 12.0f;
    uint16_t* C = (uint16_t*)C0v + (long)blockIdx.z * sC;
#pragma unroll
    for (int i = 0; i < 8; i++)
#pragma unroll
      for (int r = 0; r < 4; r++) {
        long row = crow + i * 16 + r;
#pragma unroll
        for (int j = 0; j < 4; j++) C[row * (long)ldc + ccol + j * 16] = f2bf(acc[i][j][r] * s);
      }
  } else if constexpr (MODE == 4 || MODE == 5) {
    const float2* __restrict__ tab = (const float2*)C1v;
    uint16_t* Cb = (uint16_t*)C0v;
    const float* __restrict__ S = (MODE == 4) ? (const float*)C2v : nullptr;
    float* Cf = (MODE == 5) ? (float*)C2v : nullptr;
    const float sgn = (l & 1) ? 1.0f : -1.0f;
#pragma unroll
    for (int i = 0; i < 8; i++)
#pragma unroll
      for (int r = 0; r < 4; r++) {
        long row = crow + i * 16 + r;
        const float2* trow = tab + (((int)(row & 2047)) << 6);
        float srow = 1.0f;
        if constexpr (MODE == 4) srow = S ? S[row] : 1.0f;
#pragma unroll
        for (int j = 0; j < 4; j++) {
          long c = ccol + j * 16;
          float v = acc[i][j][r];
          if constexpr (MODE == 4) v *= srow;
          float pp = __shfl_xor(v, 1);
          float2 cs = trow[((int)(c & 127)) >> 1];
          float y = v * cs.x + sgn * pp * cs.y;
          Cb[row * 2560 + 512 + c] = f2bf(y);
          if constexpr (MODE == 5) Cf[row * 2048 + c] = y;
        }
      }
  } else if constexpr (MODE == 6) {
    const float2* __restrict__ tab = (const float2*)C1v;
    const float sgn = (l & 1) ? 1.0f : -1.0f;
    if (blockIdx.z == 0) {
      // kr: rope -> catk[:,512+c] bf16 + kr_out fp32
      uint16_t* Cb = (uint16_t*)C0v;
      float* Cf = (float*)C2v;
#pragma unroll
      for (int i = 0; i < 8; i++)
#pragma unroll
        for (int r = 0; r < 4; r++) {
          long row = crow + i * 16 + r;
          const float2* trow = tab + (((int)(row & 2047)) << 6);
#pragma unroll
          for (int j = 0; j < 4; j++) {
            long c = ccol + j * 16;
            float v = acc[i][j][r];
            float pp = __shfl_xor(v, 1);
            float2 cs = trow[((int)(c & 127)) >> 1];
            float y = v * cs.x + sgn * pp * cs.y;
            Cb[row * 2560 + 512 + c] = f2bf(y);
            Cf[row * 2048 + c] = y;
          }
        }
    } else {
      // qr: scaled rope -> catq[:,512+c] bf16
      uint16_t* Cb = (uint16_t*)C3v;
#pragma unroll
      for (int i = 0; i < 8; i++)
#pragma unroll
        for (int r = 0; r < 4; r++) {
          long row = crow + i * 16 + r;
          const float2* trow = tab + (((int)(row & 2047)) << 6);
          float srow = S2[row];
#pragma unroll
          for (int j = 0; j < 4; j++) {
            long c = ccol + j * 16;
            float v = acc[i][j][r] * srow;
            float pp = __shfl_xor(v, 1);
            float2 cs = trow[((int)(c & 127)) >> 1];
            float y = v * cs.x + sgn * pp * cs.y;
            Cb[row * 2560 + 512 + c] = f2bf(y);
          }
        }
    }
  } else {
    if (bn < 512) {
      uint16_t* C = (uint16_t*)C0v;
#pragma unroll
      for (int i = 0; i < 8; i++)
#pragma unroll
        for (int r = 0; r < 4; r++) {
          long row = crow + i * 16 + r;
#pragma unroll
          for (int j = 0; j < 4; j++) C[row * 512 + ccol + j * 16] = f2bf(acc[i][j][r]);
        }
    } else if (bn < 1024) {
      float* C = (float*)C1v;
      const long cc = ccol - 512;
#pragma unroll
      for (int i = 0; i < 8; i++)
#pragma unroll
        for (int r = 0; r < 4; r++) {
          long row = crow + i * 16 + r;
#pragma unroll
          for (int j = 0; j < 4; j++) C[row * 512 + cc + j * 16] = acc[i][j][r];
        }
    } else {
      uint16_t* C = (uint16_t*)C2v;
      const long cc = ccol - 1024;
#pragma unroll
      for (int i = 0; i < 8; i++)
#pragma unroll
        for (int r = 0; r < 4; r++) {
          long row = crow + i * 16 + r;
#pragma unroll
          for (int j = 0; j < 4; j++) C[row * 2560 + cc + j * 16] = f2bf(acc[i][j][r]);
        }
    }
  }
}

// ================= 256x128 pipelined GEMM (for the small-N o GEMM) =================
template<int OUTB>
__global__ void __launch_bounds__(512, 2) gemm256(
    const uint16_t* __restrict__ A, const uint16_t* __restrict__ B,
    void* __restrict__ Cv, int K, int lda, int ldb, int ldc,
    long sA, long sB, long sC)
{
  __shared__ __attribute__((aligned(16))) char lds[147456];
  const int tid = threadIdx.x;
  const int w = tid >> 6, l = tid & 63;
  const int wm = w >> 1, wn = w & 1;

  const int gx = gridDim.x;
  const int nwg = gx * gridDim.y;
  int id = blockIdx.y * gx + blockIdx.x;
  if ((nwg & 7) == 0) id = (id & 7) * (nwg >> 3) + (id >> 3);
  const long bm = (long)(id % gx) * 256;
  const long bn = (long)(id / gx) * 128;
  A += (long)blockIdx.z * sA;
  B += (long)blockIdx.z * sB;

  const int sr = l >> 3;
  const int sc = l & 7;
  const int scol = ((sc ^ sr) << 3);
  const uint16_t* gA = A + (bm + w * 8 + sr) * (long)lda + scol;
  const uint16_t* gB = B + (bn + w * 8 + sr) * (long)ldb + scol;
  const int ldsw = w * 1024;

#define STAGE_A(bufi, k0, r)                                                     \
  __builtin_amdgcn_global_load_lds(gA + (k0) + (long)(r) * 64 * lda,             \
      (uint16_t*)(lds + (bufi) * 49152 + (r) * 8192 + ldsw), 16, 0, 0)
#define STAGE_B(bufi, k0, r)                                                     \
  __builtin_amdgcn_global_load_lds(gB + (k0) + (long)(r) * 64 * ldb,             \
      (uint16_t*)(lds + (bufi) * 49152 + 32768 + (r) * 8192 + ldsw), 16, 0, 0)

  const int lr = l & 15;
  const int kk = (l >> 4) << 4;
  const int msk = (l & 7) << 4;
  const int ko0 = kk ^ msk;
  const int ko1 = (64 + kk) ^ msk;
  const int arow = (wm * 64 + lr) * 128;
  const int brow = (wn * 64 + lr) * 128;

  floatx4 acc[4][4];
#pragma unroll
  for (int i = 0; i < 4; i++)
#pragma unroll
    for (int j = 0; j < 4; j++) acc[i][j] = (floatx4){0.f, 0.f, 0.f, 0.f};

  const int nt = K >> 6;
#pragma unroll
  for (int r = 0; r < 4; r++) STAGE_A(0, 0, r);
#pragma unroll
  for (int r = 0; r < 2; r++) STAGE_B(0, 0, r);
#pragma unroll
  for (int r = 0; r < 4; r++) STAGE_A(1, 64, r);
#pragma unroll
  for (int r = 0; r < 2; r++) STAGE_B(1, 64, r);
  asm volatile("s_waitcnt vmcnt(6)" ::: "memory");
  SBAR();

  bf16x8 af0[4], bf0[4], af1[4], bf1[4];
  {
    const char* LA = lds + arow;
    const char* LB = lds + 32768 + brow;
#pragma unroll
    for (int i = 0; i < 4; i++) af0[i] = *(const bf16x8*)(LA + i * 2048 + ko0);
#pragma unroll
    for (int j = 0; j < 4; j++) bf0[j] = *(const bf16x8*)(LB + j * 2048 + ko0);
  }

  for (int t = 0; t < nt; t++) {
    const int buf = t % 3;
    const int pbuf = (t + 2) % 3;
    const long pk0 = (long)(t + 2) << 6;
    const char* LA = lds + buf * 49152 + arow;
    const char* LB = lds + buf * 49152 + 32768 + brow;
    const bool pf = (t + 2 < nt);

    if (pf) { STAGE_A(pbuf, pk0, 0); STAGE_A(pbuf, pk0, 1); STAGE_B(pbuf, pk0, 0); }
#pragma unroll
    for (int i = 0; i < 4; i++) af1[i] = *(const bf16x8*)(LA + i * 2048 + ko1);
#pragma unroll
    for (int j = 0; j < 4; j++) bf1[j] = *(const bf16x8*)(LB + j * 2048 + ko1);
    SCHED();
    __builtin_amdgcn_s_setprio(1);
#pragma unroll
    for (int i = 0; i < 4; i++)
#pragma unroll
      for (int j = 0; j < 4; j++) mfma16(acc[i][j], af0[i], bf0[j]);
    __builtin_amdgcn_s_setprio(0);
    SCHED();

    if (pf) { STAGE_A(pbuf, pk0, 2); STAGE_A(pbuf, pk0, 3); STAGE_B(pbuf, pk0, 1); }
    if (t < nt - 2) asm volatile("s_waitcnt vmcnt(6) lgkmcnt(0)" ::: "memory");
    else            asm volatile("s_waitcnt vmcnt(0) lgkmcnt(0)" ::: "memory");
    SBAR();
    if (t < nt - 1) {
      const char* LAn = lds + ((t + 1) % 3) * 49152 + arow;
      const char* LBn = lds + ((t + 1) % 3) * 49152 + 32768 + brow;
#pragma unroll
      for (int i = 0; i < 4; i++) af0[i] = *(const bf16x8*)(LAn + i * 2048 + ko0);
#pragma unroll
      for (int j = 0; j < 4; j++) bf0[j] = *(const bf16x8*)(LBn + j * 2048 + ko0);
    }
    SCHED();
    __builtin_amdgcn_s_setprio(1);
#pragma unroll
    for (int i = 0; i < 4; i++)
#pragma unroll
      for (int j = 0; j < 4; j++) mfma16(acc[i][j], af1[i], bf1[j]);
    __builtin_amdgcn_s_setprio(0);
    SCHED();
  }
#undef STAGE_A
#undef STAGE_B

  const long crow = bm + wm * 64 + ((l >> 4) * 4);
  const long ccol = bn + wn * 64 + (l & 15);
  if constexpr (OUTB == 0) {
    float* C = (float*)Cv + (long)blockIdx.z * sC;
#pragma unroll
    for (int i = 0; i < 4; i++)
#pragma unroll
      for (int r = 0; r < 4; r++) {
        long row = crow + i * 16 + r;
#pragma unroll
        for (int j = 0; j < 4; j++) C[row * (long)ldc + ccol + j * 16] = acc[i][j][r];
      }
  } else {
    uint16_t* C = (uint16_t*)Cv + (long)blockIdx.z * sC;
#pragma unroll
    for (int i = 0; i < 4; i++)
#pragma unroll
      for (int r = 0; r < 4; r++) {
        long row = crow + i * 16 + r;
#pragma unroll
        for (int j = 0; j < 4; j++) C[row * (long)ldc + ccol + j * 16] = f2bf(acc[i][j][r]);
      }
  }
}

// ================= routed prep GEMM: T1t partials (x<4) + awoT partials (x>=4) =================
__global__ void __launch_bounds__(256) gemm_prep(
    const uint16_t* __restrict__ wukT, const uint16_t* __restrict__ wuqT,
    const uint16_t* __restrict__ wo_b, const uint16_t* __restrict__ wuvT,
    float* __restrict__ redT, float* __restrict__ redW)
{
  __shared__ alignas(16) uint16_t As[4096];
  __shared__ alignas(16) uint16_t Bs[4096];
  const int tid = threadIdx.x;
  const int w = tid >> 6, l = tid & 63;
  const int wr = w >> 1, wc = w & 1;

  const bool isT1 = (blockIdx.x < 4);
  const long bm = (long)(isT1 ? blockIdx.x : (blockIdx.x - 4)) * 128;
  const long bn = (long)blockIdx.y * 128;
  const uint16_t* A = (isT1 ? wukT : wo_b) + (long)blockIdx.z * 512;
  const uint16_t* B = (isT1 ? wuqT : wuvT) + (long)blockIdx.z * 512;
  float* C = (isT1 ? redT : redW) + (long)blockIdx.z * (isT1 ? 262144L : 1048576L);
  const int lda = 2048, ldb = 2048, ldc = 512;

  const uint16_t* ga0 = A + (bm + w * 16 + (l >> 2)) * (long)lda + (l & 3) * 8;
  const uint16_t* ga1 = ga0 + 64L * lda;
  const uint16_t* gb0 = B + (bn + w * 16 + (l >> 2)) * (long)ldb + (l & 3) * 8;
  const uint16_t* gb1 = gb0 + 64L * ldb;
  uint16_t* la0 = &As[w * 512];
  uint16_t* la1 = &As[2048 + w * 512];
  uint16_t* lb0 = &Bs[w * 512];
  uint16_t* lb1 = &Bs[2048 + w * 512];

  floatx4 acc[4][4];
#pragma unroll
  for (int i = 0; i < 4; i++)
#pragma unroll
    for (int j = 0; j < 4; j++) acc[i][j] = (floatx4){0.f, 0.f, 0.f, 0.f};

  const int rA = (wr * 64 + (l & 15)) * 32 + (l >> 4) * 8;
  const int rB = (wc * 64 + (l & 15)) * 32 + (l >> 4) * 8;

  for (int k0 = 0; k0 < 512; k0 += 32) {
    __builtin_amdgcn_global_load_lds(ga0, la0, 16, 0, 0);
    __builtin_amdgcn_global_load_lds(ga1, la1, 16, 0, 0);
    __builtin_amdgcn_global_load_lds(gb0, lb0, 16, 0, 0);
    __builtin_amdgcn_global_load_lds(gb1, lb1, 16, 0, 0);
    ga0 += 32; ga1 += 32; gb0 += 32; gb1 += 32;
    __syncthreads();
    bf16x8 af[4], bfr[4];
#pragma unroll
    for (int i = 0; i < 4; i++) af[i] = *(const bf16x8*)&As[rA + i * 512];
#pragma unroll
    for (int j = 0; j < 4; j++) bfr[j] = *(const bf16x8*)&Bs[rB + j * 512];
#pragma unroll
    for (int i = 0; i < 4; i++)
#pragma unroll
      for (int j = 0; j < 4; j++) mfma16(acc[i][j], af[i], bfr[j]);
    __syncthreads();
  }

  const long crow = bm + wr * 64 + ((l >> 4) * 4);
  const long ccol = bn + wc * 64 + (l & 15);
#pragma unroll
  for (int i = 0; i < 4; i++)
#pragma unroll
    for (int r = 0; r < 4; r++) {
      long row = crow + i * 16 + r;
#pragma unroll
      for (int j = 0; j < 4; j++) C[row * (long)ldc + ccol + j * 16] = acc[i][j][r];
    }
}

// ================= legacy 128x128 GEMM (Bqt only) =================
template<int OUTB>
__global__ void __launch_bounds__(256) gemm_bt(
    const uint16_t* __restrict__ A, const uint16_t* __restrict__ B,
    void* __restrict__ Cv, int K, int lda, int ldb, int ldc,
    long sA, long sB, long sC)
{
  __shared__ alignas(16) uint16_t As[4096];
  __shared__ alignas(16) uint16_t Bs[4096];
  const int tid = threadIdx.x;
  const int w = tid >> 6, l = tid & 63;
  const int wr = w >> 1, wc = w & 1;
  const long bm = (long)blockIdx.x * 128, bn = (long)blockIdx.y * 128;
  A += (long)blockIdx.z * sA;
  B += (long)blockIdx.z * sB;

  const uint16_t* ga0 = A + (bm + w * 16 + (l >> 2)) * (long)lda + (l & 3) * 8;
  const uint16_t* ga1 = ga0 + 64L * lda;
  const uint16_t* gb0 = B + (bn + w * 16 + (l >> 2)) * (long)ldb + (l & 3) * 8;
  const uint16_t* gb1 = gb0 + 64L * ldb;
  uint16_t* la0 = &As[w * 512];
  uint16_t* la1 = &As[2048 + w * 512];
  uint16_t* lb0 = &Bs[w * 512];
  uint16_t* lb1 = &Bs[2048 + w * 512];

  floatx4 acc[4][4];
#pragma unroll
  for (int i = 0; i < 4; i++)
#pragma unroll
    for (int j = 0; j < 4; j++) acc[i][j] = (floatx4){0.f, 0.f, 0.f, 0.f};

  const int rA = (wr * 64 + (l & 15)) * 32 + (l >> 4) * 8;
  const int rB = (wc * 64 + (l & 15)) * 32 + (l >> 4) * 8;

  for (int k0 = 0; k0 < K; k0 += 32) {
    __builtin_amdgcn_global_load_lds(ga0, la0, 16, 0, 0);
    __builtin_amdgcn_global_load_lds(ga1, la1, 16, 0, 0);
    __builtin_amdgcn_global_load_lds(gb0, lb0, 16, 0, 0);
    __builtin_amdgcn_global_load_lds(gb1, lb1, 16, 0, 0);
    ga0 += 32; ga1 += 32; gb0 += 32; gb1 += 32;
    __syncthreads();
    bf16x8 af[4], bfr[4];
#pragma unroll
    for (int i = 0; i < 4; i++) af[i] = *(const bf16x8*)&As[rA + i * 512];
#pragma unroll
    for (int j = 0; j < 4; j++) bfr[j] = *(const bf16x8*)&Bs[rB + j * 512];
#pragma unroll
    for (int i = 0; i < 4; i++)
#pragma unroll
      for (int j = 0; j < 4; j++) mfma16(acc[i][j], af[i], bfr[j]);
    __syncthreads();
  }

  const long crow = bm + wr * 64 + ((l >> 4) * 4);
  const long ccol = bn + wc * 64 + (l & 15);
  if constexpr (OUTB == 0) {
    float* C = (float*)Cv + (long)blockIdx.z * sC;
#pragma unroll
    for (int i = 0; i < 4; i++)
#pragma unroll
      for (int r = 0; r < 4; r++) {
        long row = crow + i * 16 + r;
#pragma unroll
        for (int j = 0; j < 4; j++) C[row * (long)ldc + ccol + j * 16] = acc[i][j][r];
      }
  } else {
    uint16_t* C = (uint16_t*)Cv + (long)blockIdx.z * sC;
#pragma unroll
    for (int i = 0; i < 4; i++)
#pragma unroll
      for (int r = 0; r < 4; r++) {
        long row = crow + i * 16 + r;
#pragma unroll
        for (int j = 0; j < 4; j++) C[row * (long)ldc + ccol + j * 16] = f2bf(acc[i][j][r]);
      }
  }
}

// ---------- merged split-K reduce: blocks 0..255 -> T1t; 256..1279 -> awoT ----------
__global__ void __launch_bounds__(256) reduce2(
    const float* __restrict__ redT, uint16_t* __restrict__ T1t,
    const float* __restrict__ redW, uint16_t* __restrict__ awoT)
{
  const int b = blockIdx.x;
  const float* in; uint16_t* out; long i, stride;
  if (b < 256) { in = redT; out = T1t; i = ((long)b * 256 + threadIdx.x) * 4; stride = 262144L; }
  else         { in = redW; out = awoT; i = ((long)(b - 256) * 256 + threadIdx.x) * 4; stride = 1048576L; }
  float4 s = *(const float4*)(in + i);
  for (int k = 1; k < 4; k++) {
    float4 t = *(const float4*)(in + k * stride + i);
    s.x += t.x; s.y += t.y; s.z += t.z; s.w += t.w;
  }
  ushort4 o; o.x = f2bf(s.x); o.y = f2bf(s.y); o.z = f2bf(s.z); o.w = f2bf(s.w);
  *(ushort4*)(out + i) = o;
}

// ---------- fused prep: h/weight converts + g1-folded wqr + rope table + transposes ----------
__global__ void __launch_bounds__(256) prep_all(
    const float* __restrict__ h,
    const float* __restrict__ wdq, const float* __restrict__ wdkv,
    const float* __restrict__ wqr, const float* __restrict__ wkr,
    const float* __restrict__ wo, const float* __restrict__ g1,
    const float* __restrict__ wuk, const float* __restrict__ wuq,
    const float* __restrict__ wuv,
    uint16_t* __restrict__ hb,
    uint16_t* __restrict__ wdq_b, uint16_t* __restrict__ wdkv_b,
    uint16_t* __restrict__ wqr_b, uint16_t* __restrict__ wkr_b,
    uint16_t* __restrict__ wo_b, float2* __restrict__ rtab,
    uint16_t* __restrict__ wukT, uint16_t* __restrict__ wuqT,
    uint16_t* __restrict__ wuvT, uint16_t* __restrict__ wdqT)
{
  const int b = blockIdx.x;
  if (b < 27648) {
    if (b >= 18432 && b < 19456) {  // wqr with g1 fold
      long i = ((long)(b - 18432) * 256 + threadIdx.x) * 4;
      float4 v = *(const float4*)(wqr + i);
      int c = (int)(i & 511);
      float4 g = *(const float4*)(g1 + c);
      ushort4 o;
      o.x = f2bf(v.x * g.x); o.y = f2bf(v.y * g.y);
      o.z = f2bf(v.z * g.z); o.w = f2bf(v.w * g.w);
      *(ushort4*)(wqr_b + i) = o;
      return;
    }
    const float* src; uint16_t* dst; long off;
    if (b < 16384)      { src = h;    dst = hb;     off = b; }
    else if (b < 17408) { src = wdq;  dst = wdq_b;  off = b - 16384; }
    else if (b < 18432) { src = wdkv; dst = wdkv_b; off = b - 17408; }
    else if (b < 23552) { src = wkr;  dst = wkr_b;  off = b - 19456; }
    else                { src = wo;   dst = wo_b;   off = b - 23552; }
    long i = (off * 256 + threadIdx.x) * 4;
    float4 v = *(const float4*)(src + i);
    ushort4 o; o.x = f2bf(v.x); o.y = f2bf(v.y); o.z = f2bf(v.z); o.w = f2bf(v.w);
    *(ushort4*)(dst + i) = o;
  } else if (b < 28160) {
    int idx = (b - 27648) * 256 + threadIdx.x;
    int s = idx >> 6, fi = idx & 63;
    float f = powf(10000.0f, -(float)fi * (1.0f / 64.0f));
    float ang = (float)s * f;
    rtab[idx] = make_float2(cosf(ang), sinf(ang));
  } else {
    __shared__ float tile[32][33];
    const int bt = b - 28160;
    const int tx = threadIdx.x & 31, ty = threadIdx.x >> 5;
    const float* in; uint16_t* out; int ld_in, ld_out, rb, cb;
    if (bt < 3072) {
      const int op = bt >> 10, rem = bt & 1023;
      in = (op == 0) ? wuk : (op == 1) ? wuq : wuv;
      out = (op == 0) ? wukT : (op == 1) ? wuqT : wuvT;
      ld_in = 512; ld_out = 2048;
      cb = (rem & 15) * 32; rb = (rem >> 4) * 32;
    } else {
      const int rem = bt - 3072;
      in = wdq; out = wdqT; ld_in = 2048; ld_out = 512;
      cb = (rem & 63) * 32; rb = (rem >> 6) * 32;
    }
#pragma unroll
    for (int i = 0; i < 32; i += 8)
      tile[ty + i][tx] = in[(long)(rb + ty + i) * ld_in + cb + tx];
    __syncthreads();
#pragma unroll
    for (int i = 0; i < 32; i += 8)
      out[(long)(cb + ty + i) * ld_out + rb + tx] = f2bf(tile[tx][ty + i]);
  }
}

// ---------- transpose (R,Cc) -> (Cc,R), bf16 out (used for ckvT) ----------
template<typename TIN>
__global__ void __launch_bounds__(256) transpose_to_bf16(
    const TIN* __restrict__ in, uint16_t* __restrict__ out,
    int ld_in, int ld_out, long sIn, long sOut)
{
  __shared__ float tile[32][33];
  in += (long)blockIdx.z * sIn;
  out += (long)blockIdx.z * sOut;
  const int rb = blockIdx.y * 32, cb = blockIdx.x * 32;
#pragma unroll
  for (int i = 0; i < 32; i += 8)
    tile[threadIdx.y + i][threadIdx.x] =
        ld_as_float(in[(long)(rb + threadIdx.y + i) * ld_in + cb + threadIdx.x]);
  __syncthreads();
#pragma unroll
  for (int i = 0; i < 32; i += 8)
    out[(long)(cb + threadIdx.y + i) * ld_out + rb + threadIdx.x] =
        f2bf(tile[threadIdx.x][threadIdx.y + i]);
}

// ---------- fused norms: blocks 0..8191 cq-scale only; 8192..16383 ckv full ----------
__global__ void __launch_bounds__(256) norm_pair(
    const uint16_t* __restrict__ cqpre, float* __restrict__ sVec,
    const float* __restrict__ ckvpre, const float* __restrict__ g2,
    float* __restrict__ ckv_out, uint16_t* __restrict__ catk)
{
  __shared__ float sm[9];
  const int b = blockIdx.x;
  const int base = threadIdx.x * 2;
  float v0, v1;
  if (b < 8192) {
    ushort2 t = *(const ushort2*)&cqpre[(long)b * 512 + base];
    v0 = bf2f(t.x); v1 = bf2f(t.y);
  } else {
    float2 t = *(const float2*)&ckvpre[(long)(b - 8192) * 512 + base];
    v0 = t.x; v1 = t.y;
  }
  float ss = v0 * v0 + v1 * v1;
#pragma unroll
  for (int o = 32; o; o >>= 1) ss += __shfl_down(ss, o);
  if ((threadIdx.x & 63) == 0) sm[threadIdx.x >> 6] = ss;
  __syncthreads();
  if (threadIdx.x == 0)
    sm[8] = rsqrtf((sm[0] + sm[1] + sm[2] + sm[3]) * (1.0f / 512.0f) + 1.1920929e-7f);
  __syncthreads();
  const float sc = sm[8];
  if (b < 8192) {
    if (threadIdx.x == 0) sVec[b] = sc;
  } else {
    const long row = b - 8192;
    float y0 = v0 * sc * g2[base];
    float y1 = v1 * sc * g2[base + 1];
    *(float2*)&ckv_out[row * 512 + base] = make_float2(y0, y1);
    ushort2 o; o.x = f2bf(y0); o.y = f2bf(y1);
    *(ushort2*)&catk[row * 2560 + base] = o;
  }
}

// ---------- rmsnorm: one block per row; DIM = PT*256 (u-norm) ----------
template<int PT, typename TIN>
__global__ void __launch_bounds__(256) rmsnorm_k(
    const TIN* __restrict__ in, const float* __restrict__ g,
    float* __restrict__ out_f, uint16_t* __restrict__ out_b, int ld_b)
{
  constexpr int DIM = PT * 256;
  __shared__ float sm[9];
  const TIN* x = in + (long)blockIdx.x * DIM;
  const int base = threadIdx.x * PT;
  float v[PT];
  if constexpr (sizeof(TIN) == 2) {
#pragma unroll
    for (int i = 0; i < PT; i += 8) {
      u16x8 t = *(const u16x8*)&x[base + i];
#pragma unroll
      for (int q = 0; q < 8; q++) v[i + q] = bf2f(t[q]);
    }
  } else {
#pragma unroll
    for (int i = 0; i < PT; i += 4) {
      float4 t = *(const float4*)&x[base + i];
      v[i] = t.x; v[i + 1] = t.y; v[i + 2] = t.z; v[i + 3] = t.w;
    }
  }
  float ss = 0.f;
#pragma unroll
  for (int i = 0; i < PT; i++) ss += v[i] * v[i];
#pragma unroll
  for (int o = 32; o; o >>= 1) ss += __shfl_down(ss, o);
  if ((threadIdx.x & 63) == 0) sm[threadIdx.x >> 6] = ss;
  __syncthreads();
  if (threadIdx.x == 0)
    sm[8] = rsqrtf((sm[0] + sm[1] + sm[2] + sm[3]) * (1.0f / DIM) + 1.1920929e-7f);
  __syncthreads();
  const float sc = sm[8];
#pragma unroll
  for (int i = 0; i < PT; i++) {
    float y = v[i] * sc * g[base + i];
    if (out_f) out_f[(long)blockIdx.x * DIM + base + i] = y;
    if (out_b) out_b[(long)blockIdx.x * ld_b + base + i] = f2bf(y);
  }
}

// ---------- softmax over rows of 2048, bf16 in (pre-scaled), bf16 out ----------
__global__ void __launch_bounds__(256) softmax_k(const uint16_t* __restrict__ sc,
                                                 uint16_t* __restrict__ attn) {
  __shared__ float sm[9];
  const uint16_t* x = sc + ((long)blockIdx.x << 11);
  const int base = threadIdx.x * 8;
  float v[8];
  u16x8 t = *(const u16x8*)&x[base];
#pragma unroll
  for (int i = 0; i < 8; i++) v[i] = bf2f(t[i]);
  float m = -1e30f;
#pragma unroll
  for (int i = 0; i < 8; i++) m = fmaxf(m, v[i]);
#pragma unroll
  for (int o = 32; o; o >>= 1) m = fmaxf(m, __shfl_down(m, o));
  if ((threadIdx.x & 63) == 0) sm[threadIdx.x >> 6] = m;
  __syncthreads();
  if (threadIdx.x == 0)
    sm[8] = fmaxf(fmaxf(sm[0], sm[1]), fmaxf(sm[2], sm[3]));
  __syncthreads();
  m = sm[8];
  __syncthreads();
  float ss = 0.f;
#pragma unroll
  for (int i = 0; i < 8; i++) { v[i] = __expf(v[i] - m); ss += v[i]; }
#pragma unroll
  for (int o = 32; o; o >>= 1) ss += __shfl_down(ss, o);
  if ((threadIdx.x & 63) == 0) sm[threadIdx.x >> 6] = ss;
  __syncthreads();
  if (threadIdx.x == 0) sm[8] = 1.0f / (sm[0] + sm[1] + sm[2] + sm[3]);
  __syncthreads();
  const float r = sm[8];
  ushort4 o1, o2;
  o1.x = f2bf(v[0] * r); o1.y = f2bf(v[1] * r); o1.z = f2bf(v[2] * r); o1.w = f2bf(v[3] * r);
  o2.x = f2bf(v[4] * r); o2.y = f2bf(v[5] * r); o2.z = f2bf(v[6] * r); o2.w = f2bf(v[7] * r);
  uint16_t* dst = attn + ((long)blockIdx.x << 11) + base;
  *(ushort4*)dst = o1;
  *(ushort4*)(dst + 4) = o2;
}

// ---------- orchestration ----------
extern "C" void kernel_launch(void* const* d_in, const int* in_sizes, int n_in,
                              void* d_out, int out_size, void* d_ws, size_t ws_size,
                              hipStream_t stream) {
  (void)in_sizes; (void)n_in; (void)out_size; (void)ws_size;
  const float* h    = (const float*)d_in[0];
  const float* wdkv = (const float*)d_in[1];
  const float* wuk  = (const float*)d_in[2];
  const float* wuv  = (const float*)d_in[3];
  const float* wdq  = (const float*)d_in[4];
  const float* wuq  = (const float*)d_in[5];
  const float* wkr  = (const float*)d_in[6];
  const float* wqr  = (const float*)d_in[7];
  const float* wo   = (const float*)d_in[8];
  const float* g1   = (const float*)d_in[9];
  const float* g2   = (const float*)d_in[10];
  const float* g3   = (const float*)d_in[11];

  float* u_out   = (float*)d_out;                 // (4,2048,2048)
  float* ckv_out = u_out + 16777216L;             // (4,2048,512)
  float* kr_out  = ckv_out + 4194304L;            // (4,2048,2048)

  char* p = (char*)d_ws;
  auto alloc = [&](size_t bytes) -> void* {
    void* q = (void*)p; p += (bytes + 255) & ~(size_t)255; return q;
  };
  uint16_t* hb     = (uint16_t*)alloc(16777216ULL * 2);  // h bf16
  uint16_t* wcat   = (uint16_t*)alloc(3145728ULL * 2);   // (1536,2048) [wdq;wdkv;Bqt]
  uint16_t* wqr_b  = (uint16_t*)alloc(1048576ULL * 2);
  uint16_t* wkr_b  = (uint16_t*)alloc(4194304ULL * 2);
  uint16_t* wo_b   = (uint16_t*)alloc(4194304ULL * 2);
  uint16_t* wukT   = (uint16_t*)alloc(1048576ULL * 2);   // (512,2048)
  uint16_t* wuqT   = (uint16_t*)alloc(1048576ULL * 2);
  uint16_t* wuvT   = (uint16_t*)alloc(1048576ULL * 2);
  uint16_t* wdqT   = (uint16_t*)alloc(1048576ULL * 2);   // (2048,512)
  uint16_t* T1t    = (uint16_t*)alloc(262144ULL * 2);    // (512,512)
  uint16_t* awoT   = (uint16_t*)alloc(1048576ULL * 2);   // absorbed_w_o^T (2048,512)
  uint16_t* cqpre  = (uint16_t*)alloc(4194304ULL * 2);   // (8192,512) bf16 cq-pre
  float*    sVec   = (float*)alloc(8192ULL * 4);         // per-row rmsnorm scale for cq
  uint16_t* catq   = (uint16_t*)alloc(20971520ULL * 2);  // (8192,2560) [aq|qr]
  uint16_t* catk   = (uint16_t*)alloc(20971520ULL * 2);  // (8192,2560) [ckv|kr]
  uint16_t* ckvT   = (uint16_t*)alloc(4194304ULL * 2);   // 4 x (512,2048)
  uint16_t* o_b    = (uint16_t*)alloc(4194304ULL * 2);   // (8192,512)
  float2*   rtab   = (float2*)alloc(131072ULL * 8);      // 2048x64 (cos,sin)
  float*    tmpS2  = (float*)alloc(4194304ULL * 4);      // (8192,512) fp32 ckv-pre
  float*    tmpB   = (float*)alloc(16777216ULL * 4);     // (8192,2048) scratch
  float*    redT   = (float*)alloc(1048576ULL * 4);      // 4 x (512,512) partials
  float*    redW   = (float*)alloc(4194304ULL * 4);      // 4 x (2048,512) partials
  uint16_t* tmpBb  = (uint16_t*)tmpB;                    // alias: (8192,2048) bf16
  uint16_t* attn   = catq;  // alias: catq dead after scores GEMM

  uint16_t* wdq_b  = wcat;                  // rows 0-511
  uint16_t* wdkv_b = wcat + 1048576;        // rows 512-1023
  uint16_t* Bqt    = wcat + 2097152;        // rows 1024-1535 (absorbed_w_q^T)

  const dim3 b256(256);
  const dim3 b512(512);
  const dim3 tb(32, 8);

  // fused prep: converts (g1 folded into wqr_b) + rope table + weight transposes
  prep_all<<<dim3(32256), b256, 0, stream>>>(
      h, wdq, wdkv, wqr, wkr, wo, g1, wuk, wuq, wuv,
      hb, wdq_b, wdkv_b, wqr_b, wkr_b, wo_b, rtab, wukT, wuqT, wuvT, wdqT);

  // absorbed weights — merged split-K prep (T1t + awoT partials), merged reduce, Bqt
  gemm_prep<<<dim3(20, 4, 4), b256, 0, stream>>>(wukT, wuqT, wo_b, wuvT, redT, redW);
  reduce2<<<dim3(1280), b256, 0, stream>>>(redT, T1t, redW, awoT);
  gemm_bt<1><<<dim3(4, 16, 1), b256, 0, stream>>>(T1t, wdqT, Bqt, 512, 512, 512, 2048, 0, 0, 0);

  // fused: [cq-pre(bf16) | ckv-pre(fp32) | aq(bf16)] = h @ [wdq; wdkv; Bqt]^T
  gemm256v3<2><<<dim3(32, 6, 1), b512, 0, stream>>>(
      hb, wcat, cqpre, tmpS2, catq, 2048, 2048, 2048, 0, 0, 0, 0, 2,
      nullptr, nullptr, nullptr, nullptr);
  // fused norms: cq scale vector + full ckv rmsnorm
  norm_pair<<<dim3(16384), b256, 0, stream>>>(cqpre, sVec, tmpS2, g2, ckv_out, catk);
  // merged kr + qr (routed on z): z=0 kr (rope -> catk + kr_out),
  // z=1 qr (scaled rope -> catq)
  gemm256v3<6><<<dim3(32, 8, 2), b512, 0, stream>>>(
      hb, wkr_b, catk, rtab, kr_out, 2048, 2048, 2048, 2560, 0, 0, 0, 4,
      cqpre, wqr_b, catq, sVec);
  // ckvT: 4 x (512,2048) from catk cols 0..511
  transpose_to_bf16<uint16_t><<<dim3(16, 64, 4), tb, 0, stream>>>(
      catk, ckvT, 2560, 2048, 2048L * 2560, 512L * 2048);
  // scores[b]/12 = (catq_b @ catk_b^T)/12 -> tmpBb bf16 (K=2560)
  gemm256v3<3><<<dim3(8, 8, 4), b512, 0, stream>>>(
      catq, catk, tmpBb, nullptr, nullptr, 2560, 2560, 2560, 2048,
      5242880L, 5242880L, 4194304L, 2, nullptr, nullptr, nullptr, nullptr);
  // softmax -> attn bf16 (aliases catq)
  softmax_k<<<dim3(8192), b256, 0, stream>>>(tmpBb, attn);
  // o[b] = attn_b @ ckv_b (via ckvT) -> o_b bf16
  gemm256<1><<<dim3(8, 4, 4), b512, 0, stream>>>(
      attn, ckvT, o_b, 2048, 2048, 2048, 512, 4194304L, 1048576L, 1048576L);
  // u = rmsnorm(o @ absorbed_w_o, g3) -> u_out
  gemm256v3<1><<<dim3(32, 8, 1), b512, 0, stream>>>(
      o_b, awoT, tmpBb, nullptr, nullptr, 512, 512, 512, 2048, 0, 0, 0, 4,
      nullptr, nullptr, nullptr, nullptr);
  rmsnorm_k<8, uint16_t><<<dim3(8192), b256, 0, stream>>>(tmpBb, g3, u_out, nullptr, 0);
}